// Round 12
// baseline (277.188 us; speedup 1.0000x reference)
//
#include <hip/hip_runtime.h>
#include <hip/hip_bf16.h>

// Problem constants (fixed by the reference)
#define B_ 8
#define C_ 256
#define E_ 512
#define T_ 8192
#define K_ 512
#define CT_ (C_*T_)
#define CAP_ 32768          // compacted candidate capacity per batch
#define BCAP_ 512           // per-block LDS candidate capacity
#define OCAP_ 1024          // per-batch overflow capacity
#define NBLK_ 2048          // k_gemm128 grid
#define SUBS_ 64            // t-subsample stride
#define SCOLS_ (T_/SUBS_)   // 128
#define SUBN_ (E_*SCOLS_)   // 65536 subsample points per batch
#define RANK_ 64            // subsample rank -> expected full count ~4096
#define NB1_ 4096           // subsample histogram bins over [-1,1)
#define NB2_ 4096           // selection histogram bins over [0,0.5)
#define TAUP_ 8             // histogram partial blocks per batch
#define TAUM_ 0.004f        // bf16-m error margin (~40 sigma) for collection

typedef __attribute__((ext_vector_type(8))) short bf16x8;
typedef __attribute__((ext_vector_type(4))) float f32x4;

__device__ __forceinline__ ushort f2bf(float f) {
    __hip_bfloat16 h = __float2bfloat16(f);
    return *reinterpret_cast<ushort*>(&h);
}
__device__ __forceinline__ float bf2f(ushort u) {
    __hip_bfloat16 h = *reinterpret_cast<__hip_bfloat16*>(&u);
    return __bfloat162float(h);
}

// async global->LDS, 16B per lane; LDS dest = wave-uniform base + lane*16
__device__ __forceinline__ void gl16(const void* g, void* l) {
    __builtin_amdgcn_global_load_lds(
        (const __attribute__((address_space(1))) void*)g,
        (__attribute__((address_space(3))) void*)l, 16, 0, 0);
}

// Tiled operand layout (ushort units):
//   W tiles:  [etile(8)][cc(4)][cb(8)][erow(64)][8]   (16384 per etile)
//   X tiles:  [b*128+ttile][cc(4)][cb(8)][trow(64)][8] (16384 per ttile)

// rn/nrm; block 0 inits ovc
__global__ void k_rn(const float* __restrict__ x, float* __restrict__ rn,
                     float* __restrict__ nrm, int* __restrict__ ovc) {
    if (blockIdx.x == 0 && threadIdx.x < B_) ovc[threadIdx.x] = 0;
    int gid = blockIdx.x * 256 + threadIdx.x;   // B*T threads
    int b = gid / T_, t = gid % T_;
    const float* xp = x + (size_t)b * CT_ + t;
    float s0 = 0.f, s1 = 0.f, s2 = 0.f, s3 = 0.f;
    for (int c = 0; c < C_; c += 4) {
        float a0 = xp[(size_t)c * T_];
        float a1 = xp[(size_t)(c + 1) * T_];
        float a2 = xp[(size_t)(c + 2) * T_];
        float a3 = xp[(size_t)(c + 3) * T_];
        s0 += a0 * a0; s1 += a1 * a1; s2 += a2 * a2; s3 += a3 * a3;
    }
    float s = (s0 + s1) + (s2 + s3);
    float n = sqrtf(s) + 1e-8f;
    nrm[gid] = n;
    rn[gid] = 1.0f / n;
}

// split mask_w into bf16 hi/lo, TILED layout (coalesced 16B writes)
__global__ void k_split_w(const float* __restrict__ mw, ushort* __restrict__ mwh,
                          ushort* __restrict__ mwl) {
    int idx = blockIdx.x * 256 + threadIdx.x;   // E*C/8 = 16384 threads
    int erow = idx & 63;
    int cb = (idx >> 6) & 7;
    int cc = (idx >> 9) & 3;
    int etile = idx >> 11;
    int e = etile * 64 + erow;
    int c0 = cc * 64 + cb * 8;
    const float* src = mw + (size_t)e * C_ + c0;
    ushort4 h0, l0, h1, l1;
    float v;
    v = src[0]; h0.x = f2bf(v); l0.x = f2bf(v - bf2f(h0.x));
    v = src[1]; h0.y = f2bf(v); l0.y = f2bf(v - bf2f(h0.y));
    v = src[2]; h0.z = f2bf(v); l0.z = f2bf(v - bf2f(h0.z));
    v = src[3]; h0.w = f2bf(v); l0.w = f2bf(v - bf2f(h0.w));
    v = src[4]; h1.x = f2bf(v); l1.x = f2bf(v - bf2f(h1.x));
    v = src[5]; h1.y = f2bf(v); l1.y = f2bf(v - bf2f(h1.y));
    v = src[6]; h1.z = f2bf(v); l1.z = f2bf(v - bf2f(h1.z));
    v = src[7]; h1.w = f2bf(v); l1.w = f2bf(v - bf2f(h1.w));
    *(ushort4*)(mwh + (size_t)idx * 8) = h0;
    *(ushort4*)(mwh + (size_t)idx * 8 + 4) = h1;
    *(ushort4*)(mwl + (size_t)idx * 8) = l0;
    *(ushort4*)(mwl + (size_t)idx * 8 + 4) = l1;
}

// transpose + rn-scale + split into TILED layout
__launch_bounds__(256)
__global__ void k_split_x(const float* __restrict__ x, const float* __restrict__ rn,
                          ushort* __restrict__ xh, ushort* __restrict__ xl) {
    __shared__ float tile[64][76];
    __shared__ float rnv[64];
    int tid = threadIdx.x;
    int ttile = blockIdx.x, cc = blockIdx.y, b = blockIdx.z;
    int t0 = ttile * 64, c0 = cc * 64;
    if (tid < 64) rnv[tid] = rn[b * T_ + t0 + tid];
    const float* xb = x + (size_t)b * CT_;
#pragma unroll
    for (int q = 0; q < 4; ++q) {
        int idx = tid + q * 256;
        int cr = idx >> 4, t4 = (idx & 15) * 4;
        float4 v = *(const float4*)(xb + (size_t)(c0 + cr) * T_ + t0 + t4);
        *(float4*)&tile[cr][t4] = v;
    }
    __syncthreads();
    size_t obase = (((size_t)b * 128 + ttile) * 4 + cc) * 4096;
#pragma unroll
    for (int q = 0; q < 4; ++q) {
        int idx = tid + q * 256;
        int tr = idx >> 4, c4 = (idx & 15) * 4;
        float s = rnv[tr];
        float v0 = tile[c4 + 0][tr] * s;
        float v1 = tile[c4 + 1][tr] * s;
        float v2 = tile[c4 + 2][tr] * s;
        float v3 = tile[c4 + 3][tr] * s;
        ushort4 h, l;
        h.x = f2bf(v0); l.x = f2bf(v0 - bf2f(h.x));
        h.y = f2bf(v1); l.y = f2bf(v1 - bf2f(h.y));
        h.z = f2bf(v2); l.z = f2bf(v2 - bf2f(h.z));
        h.w = f2bf(v3); l.w = f2bf(v3 - bf2f(h.w));
        int cb = c4 >> 3, half = (c4 >> 2) & 1;
        size_t ro = obase + (size_t)cb * 512 + tr * 8 + half * 4;
        *(ushort4*)(xh + ro) = h;
        *(ushort4*)(xl + ro) = l;
    }
}

// gather subsampled, rn-scaled x; first 32K threads also zero gh
__global__ void k_gather(const float* __restrict__ x, const float* __restrict__ rn,
                         float* __restrict__ xs, int* __restrict__ gh) {
    int gid = blockIdx.x * 256 + threadIdx.x;   // B*C*SCOLS threads = 262144
    if (gid < B_ * NB1_) gh[gid] = 0;
    int s = gid & (SCOLS_ - 1);
    int c = (gid >> 7) & (C_ - 1);
    int b = gid >> 15;
    int t = s * SUBS_;
    xs[gid] = x[(size_t)b * CT_ + (size_t)c * T_ + t] * rn[b * T_ + t];
}

// tiled f32 GEMM on compact gathered buffer (small: ~270 MFLOP)
__launch_bounds__(256)
__global__ void k_msub2(const float* __restrict__ xs, const float* __restrict__ mw,
                        const float* __restrict__ mb, float* __restrict__ msub) {
    __shared__ float As[64][68];
    __shared__ float Bs[64][68];
    int tid = threadIdx.x;
    int tx = tid & 15, ty = tid >> 4;
    int s0 = blockIdx.x * 64, e0 = blockIdx.y * 64, b = blockIdx.z;
    const float* xb = xs + (size_t)b * C_ * SCOLS_;
    float acc[4][4] = {};
    for (int c0 = 0; c0 < C_; c0 += 64) {
#pragma unroll
        for (int r = 0; r < 4; ++r) {
            int i = (tid >> 4) + r * 16;
            int kq = (tid & 15) * 4;
            float4 av = *(const float4*)(mw + (size_t)(e0 + i) * C_ + c0 + kq);
            As[kq + 0][i] = av.x; As[kq + 1][i] = av.y;
            As[kq + 2][i] = av.z; As[kq + 3][i] = av.w;
        }
#pragma unroll
        for (int r = 0; r < 4; ++r) {
            int k = (tid >> 4) + r * 16;
            int jq = (tid & 15) * 4;
            *(float4*)(&Bs[k][jq]) =
                *(const float4*)(xb + (size_t)(c0 + k) * SCOLS_ + s0 + jq);
        }
        __syncthreads();
#pragma unroll
        for (int k = 0; k < 64; ++k) {
            float4 a = *(const float4*)(&As[k][ty * 4]);
            float4 bq = *(const float4*)(&Bs[k][tx * 4]);
            float av[4] = {a.x, a.y, a.z, a.w};
            float bv[4] = {bq.x, bq.y, bq.z, bq.w};
#pragma unroll
            for (int ii = 0; ii < 4; ++ii)
#pragma unroll
                for (int jj = 0; jj < 4; ++jj)
                    acc[ii][jj] += av[ii] * bv[jj];
        }
        __syncthreads();
    }
#pragma unroll
    for (int ii = 0; ii < 4; ++ii) {
        float mbv = mb[e0 + ty * 4 + ii];
#pragma unroll
        for (int jj = 0; jj < 4; ++jj) {
            int e = e0 + ty * 4 + ii, s = s0 + tx * 4 + jj;
            msub[(size_t)b * SUBN_ + e * SCOLS_ + s] = acc[ii][jj] + mbv;
        }
    }
}

// parallel histogram of msub: 64 blocks (8 per batch) -> global gh[b][NB1]
__launch_bounds__(256)
__global__ void k_tau_hist(const float* __restrict__ msub, int* __restrict__ gh) {
    __shared__ int h[NB1_];
    int tid = threadIdx.x;
    int b = blockIdx.x >> 3, part = blockIdx.x & (TAUP_ - 1);
    for (int i = tid; i < NB1_; i += 256) h[i] = 0;
    __syncthreads();
    const float* mp = msub + (size_t)b * SUBN_ + part * (SUBN_ / TAUP_);
    for (int j = tid; j < SUBN_ / TAUP_; j += 256) {
        float v = mp[j];
        int bin = (int)((v + 1.0f) * ((float)NB1_ * 0.5f));
        bin = bin < 0 ? 0 : (bin > NB1_ - 1 ? NB1_ - 1 : bin);
        atomicAdd(&h[bin], 1);
    }
    __syncthreads();
    int* ghb = gh + b * NB1_;
    for (int i = tid; i < NB1_; i += 256)
        if (h[i]) atomicAdd(&ghb[i], h[i]);   // fire-and-forget, low contention
}

// per-batch conservative threshold tau0 from global histogram rank-64
__global__ void k_tau2(const int* __restrict__ gh, float* __restrict__ tau0) {
    __shared__ int part[256];
    int b = blockIdx.x, tid = threadIdx.x;
    const int* h = gh + b * NB1_;
    int ps = 0;
    for (int j = 0; j < 16; ++j) ps += h[tid * 16 + j];
    part[tid] = ps;
    __syncthreads();
    if (tid == 0) {
        int cum = 0, bf = 0;
        for (int i = 255; i >= 0; --i) {
            if (cum + part[i] >= RANK_) {
                int cum2 = cum;
                for (int j = 15; j >= 0; --j) {
                    cum2 += h[i * 16 + j];
                    if (cum2 >= RANK_) { bf = i * 16 + j; break; }
                }
                break;
            }
            cum += part[i];
        }
        tau0[b] = (float)bf * (2.0f / (float)NB1_) - 1.0f;  // bin lower edge
    }
}

// ---------------- fast main GEMM: plain bf16, half staging, 1/3 MFMA --------
// Bulk m computed in plain bf16 (input-rounding error |dm| <~ 6e-4); collect
// with lowered threshold tau0-TAUM (no true candidate missed); Z from bf16 m
// (bias ~5e-9 relative). Exact values restored by k_exact for candidates only.
__launch_bounds__(256)
__global__ void k_gemm128(const ushort* __restrict__ mwh, const ushort* __restrict__ xh,
                          const float* __restrict__ mb, const float* __restrict__ tau0,
                          float* __restrict__ zpart, int* __restrict__ cntB,
                          float* __restrict__ cvalB, int* __restrict__ cidxB,
                          int* __restrict__ ovc, float* __restrict__ ovv,
                          int* __restrict__ ovi) {
    __shared__ ushort S[4][4096];   // Wh0,Wh1,Xh0,Xh1 (8KB each)
    __shared__ float red[4];
    __shared__ float sval[BCAP_];
    __shared__ int sidx[BCAP_];
    __shared__ int scnt;
    int tid = threadIdx.x, lane = tid & 63, w = tid >> 6;
    int f = blockIdx.x;
    int xcd = f & 7, slot = f >> 3;          // XCD grouping: b == xcd
    int eblk = slot & 3, xt = slot >> 2;     // 4 e-blocks adjacent per x-tile
    int xtile = xcd * 64 + xt;               // 0..511 = b*64 + tt
    int b = xtile >> 6, tt = xtile & 63;
    int e0 = eblk * 128, t0 = tt * 128;
    if (tid == 0) scnt = 0;

    // wave w stages segment w (8 gl16 per K=64 chunk)
    const ushort* base;
    if (w < 2) base = mwh + (size_t)(eblk * 2 + (w & 1)) * 16384;
    else       base = xh + ((size_t)b * 128 + tt * 2 + (w & 1)) * 16384;
    const ushort* gsrc = base + lane * 8;

    f32x4 acc[4][4];
#pragma unroll
    for (int m = 0; m < 4; ++m)
#pragma unroll
        for (int n = 0; n < 4; ++n)
            acc[m][n] = (f32x4){0.f, 0.f, 0.f, 0.f};

    int a15 = lane & 15;
    int khalf = lane >> 4;                   // 0..3
    int wr = w >> 1, wc = w & 1;             // wave's 64x64 quadrant

    for (int cc = 0; cc < 4; ++cc) {
#pragma unroll
        for (int i = 0; i < 8; ++i)
            gl16(gsrc + cc * 4096 + i * 512, &S[w][0] + i * 512);
        __syncthreads();
#pragma unroll
        for (int ks = 0; ks < 2; ++ks) {
            int cb16 = ks * 4 + khalf;
            bf16x8 ah[4], bh[4];
#pragma unroll
            for (int m = 0; m < 4; ++m) {
                int aoff = (cb16 * 64 + m * 16 + a15) * 16;
                ah[m] = *(const bf16x8*)((const char*)&S[wr][0] + aoff);
            }
#pragma unroll
            for (int n = 0; n < 4; ++n) {
                int boff = (cb16 * 64 + n * 16 + a15) * 16;
                bh[n] = *(const bf16x8*)((const char*)&S[2 + wc][0] + boff);
            }
#pragma unroll
            for (int m = 0; m < 4; ++m)
#pragma unroll
                for (int n = 0; n < 4; ++n)
                    acc[m][n] = __builtin_amdgcn_mfma_f32_16x16x32_bf16(ah[m], bh[n], acc[m][n], 0, 0, 0);
        }
        __syncthreads();
    }

    // epilogue: C/D layout col(t)=lane&15, row(e)=(lane>>4)*4+reg
    float tau = tau0[b] - TAUM_;
    float zs = 0.f;
    int erow0 = e0 + wr * 64 + (lane >> 4) * 4;
#pragma unroll
    for (int m = 0; m < 4; ++m)
#pragma unroll
        for (int r = 0; r < 4; ++r) {
            int e = erow0 + m * 16 + r;
            float mbe = mb[e];
#pragma unroll
            for (int n = 0; n < 4; ++n) {
                int t = t0 + wc * 64 + n * 16 + a15;
                float v = acc[m][n][r] + mbe;
                zs += __expf(v);
                if (v >= tau) {
                    int pos = atomicAdd(&scnt, 1);       // LDS atomic (fast)
                    if (pos < BCAP_) {
                        sval[pos] = v;
                        sidx[pos] = e * T_ + t;
                    } else {                             // rare overflow spill
                        int q2 = atomicAdd(&ovc[b], 1);
                        if (q2 < OCAP_) {
                            ovv[b * OCAP_ + q2] = v;
                            ovi[b * OCAP_ + q2] = e * T_ + t;
                        }
                    }
                }
            }
        }
#pragma unroll
    for (int off = 32; off; off >>= 1) zs += __shfl_xor(zs, off, 64);
    if (lane == 0) red[w] = zs;
    __syncthreads();
    // flush: plain stores only
    int nc = scnt < BCAP_ ? scnt : BCAP_;
    for (int j = tid; j < nc; j += 256) {
        cvalB[(size_t)f * BCAP_ + j] = sval[j];
        cidxB[(size_t)f * BCAP_ + j] = sidx[j];
    }
    if (tid == 0) {
        cntB[f] = nc;
        zpart[f] = (red[0] + red[1]) + (red[2] + red[3]);
    }
}

// recompute exact m (f32, split pairs) for every collected candidate
__launch_bounds__(256)
__global__ void k_exact(const ushort* __restrict__ mwh, const ushort* __restrict__ mwl,
                        const ushort* __restrict__ xh, const ushort* __restrict__ xl,
                        const float* __restrict__ mb, const int* __restrict__ cntB,
                        const int* __restrict__ cidxB, float* __restrict__ cvalB,
                        const int* __restrict__ ovc, const int* __restrict__ ovi,
                        float* __restrict__ ovv) {
    int f = blockIdx.x;
    int wv = threadIdx.x >> 6, lane = threadIdx.x & 63;
    int cc = lane >> 4, cb = (lane >> 1) & 7, half = lane & 1;
    int n, b;
    const int* ip;
    float* vp;
    if (f < NBLK_) {
        b = f & 7;
        n = cntB[f]; if (n > BCAP_) n = BCAP_;
        ip = cidxB + (size_t)f * BCAP_;
        vp = cvalB + (size_t)f * BCAP_;
    } else {
        b = f - NBLK_;
        n = ovc[b]; if (n > OCAP_) n = OCAP_;
        ip = ovi + (size_t)b * OCAP_;
        vp = ovv + (size_t)b * OCAP_;
    }
    for (int j = wv; j < n; j += 4) {
        int idx = ip[j];
        int e = idx >> 13, t = idx & (T_ - 1);
        size_t xro = ((((size_t)b * 128 + (t >> 6)) * 4 + cc) * 8 + cb) * 512
                   + (size_t)(t & 63) * 8 + half * 4;
        size_t wro = (((size_t)(e >> 6) * 4 + cc) * 8 + cb) * 512
                   + (size_t)(e & 63) * 8 + half * 4;
        ushort4 hx = *(const ushort4*)(xh + xro);
        ushort4 lx = *(const ushort4*)(xl + xro);
        ushort4 hw = *(const ushort4*)(mwh + wro);
        ushort4 lw = *(const ushort4*)(mwl + wro);
        float a = (bf2f(hw.x) + bf2f(lw.x)) * (bf2f(hx.x) + bf2f(lx.x))
                + (bf2f(hw.y) + bf2f(lw.y)) * (bf2f(hx.y) + bf2f(lx.y))
                + (bf2f(hw.z) + bf2f(lw.z)) * (bf2f(hx.z) + bf2f(lx.z))
                + (bf2f(hw.w) + bf2f(lw.w)) * (bf2f(hx.w) + bf2f(lx.w));
#pragma unroll
        for (int off = 32; off; off >>= 1) a += __shfl_xor(a, off, 64);
        if (lane == 0) vp[j] = a + mb[e];
    }
}

// fused compact + exact top-K selection (one block per batch)
__launch_bounds__(256)
__global__ void k_selectc(const float* __restrict__ zpart, const int* __restrict__ cntB,
                          const float* __restrict__ cvalB, const int* __restrict__ cidxB,
                          const int* __restrict__ ovc, const float* __restrict__ ovv,
                          const int* __restrict__ ovi, float* __restrict__ cval,
                          int* __restrict__ cidx, int* __restrict__ sel_e,
                          int* __restrict__ sel_t, float* __restrict__ sel_sp) {
    __shared__ int pre[256];
    __shared__ float zsh[256];
    __shared__ int h[NB2_];
    __shared__ int part[256];
    __shared__ float bl_v[1024];
    __shared__ int bl_i[1024];
    __shared__ int nb, bstar, nabove, outcnt, ntot;
    int b = blockIdx.x, tid = threadIdx.x;
    // ---- compact phase ----
    int f = b + 8 * tid;                     // region id (b == f&7 decode)
    int c = cntB[f];
    pre[tid] = c;
    zsh[tid] = zpart[f];
    __syncthreads();
    for (int d = 1; d < 256; d <<= 1) {      // inclusive scan
        int v = (tid >= d) ? pre[tid - d] : 0;
        __syncthreads();
        pre[tid] += v;
        __syncthreads();
    }
    int start = pre[tid] - c;
    int total = pre[255];
    for (int j = 0; j < c; ++j) {
        int d = start + j;
        if (d < CAP_) {
            cval[b * CAP_ + d] = cvalB[(size_t)f * BCAP_ + j];
            cidx[b * CAP_ + d] = cidxB[(size_t)f * BCAP_ + j];
        }
    }
    __syncthreads();
    for (int d = 128; d; d >>= 1) {          // Z reduction
        if (tid < d) zsh[tid] += zsh[tid + d];
        __syncthreads();
    }
    int no = ovc[b]; if (no > OCAP_) no = OCAP_;
    for (int j = tid; j < no; j += 256) {
        int d = total + j;
        if (d < CAP_) {
            cval[b * CAP_ + d] = ovv[b * OCAP_ + j];
            cidx[b * CAP_ + d] = ovi[b * OCAP_ + j];
        }
    }
    if (tid == 0) {
        int tot = total + no;
        ntot = tot < CAP_ ? tot : CAP_;
        nb = 0; outcnt = 0;
    }
    for (int i = tid; i < NB2_; i += 256) h[i] = 0;
    __syncthreads();                          // drains global writes
    // ---- select phase ----
    int n = ntot;
    float Zb = zsh[0];
    const float* vp = cval + b * CAP_;
    const int* ip = cidx + b * CAP_;
    for (int j = tid; j < n; j += 256) {
        int bin = (int)(vp[j] * ((float)NB2_ * 2.0f));   // [0,0.5) range
        bin = bin < 0 ? 0 : (bin > NB2_ - 1 ? NB2_ - 1 : bin);
        atomicAdd(&h[bin], 1);
    }
    __syncthreads();
    int ps = 0;
    for (int j = 0; j < 16; ++j) ps += h[tid * 16 + j];
    part[tid] = ps;
    __syncthreads();
    if (tid == 0) {
        int cum = 0, bs = 0, na = 0;
        for (int i = 255; i >= 0; --i) {
            if (cum + part[i] >= K_) {
                int cum2 = cum;
                for (int j = 15; j >= 0; --j) {
                    cum2 += h[i * 16 + j];
                    if (cum2 >= K_) { bs = i * 16 + j; na = cum2 - h[i * 16 + j]; break; }
                }
                break;
            }
            cum += part[i];
        }
        bstar = bs; nabove = na;
    }
    __syncthreads();
    int bs = bstar;
    for (int j = tid; j < n; j += 256) {
        float v = vp[j];
        int bin = (int)(v * ((float)NB2_ * 2.0f));
        bin = bin < 0 ? 0 : (bin > NB2_ - 1 ? NB2_ - 1 : bin);
        if (bin == bs) {
            int q = atomicAdd(&nb, 1);
            if (q < 1024) { bl_v[q] = v; bl_i[q] = ip[j]; }
        }
    }
    __syncthreads();
    float rZ = 1.0f / Zb;
    for (int j = tid; j < n; j += 256) {
        float v = vp[j];
        int bin = (int)(v * ((float)NB2_ * 2.0f));
        bin = bin < 0 ? 0 : (bin > NB2_ - 1 ? NB2_ - 1 : bin);
        if (bin > bs) {
            int q = atomicAdd(&outcnt, 1);
            int idx = ip[j];
            sel_e[b * K_ + q] = idx / T_;
            sel_t[b * K_ + q] = idx % T_;
            sel_sp[b * K_ + q] = __expf(v) * rZ;
        }
    }
    __syncthreads();
    if (tid == 0) {
        int m = nb; if (m > 1024) m = 1024;
        for (int i = 1; i < m; ++i) {          // insertion sort: val desc, idx asc
            float v = bl_v[i]; int id = bl_i[i]; int j = i - 1;
            while (j >= 0 && (bl_v[j] < v || (bl_v[j] == v && bl_i[j] > id))) {
                bl_v[j + 1] = bl_v[j]; bl_i[j + 1] = bl_i[j]; --j;
            }
            bl_v[j + 1] = v; bl_i[j + 1] = id;
        }
        int need = K_ - nabove;
        for (int q = 0; q < need; ++q) {
            int slot = nabove + q;
            if (q < m) {
                int idx = bl_i[q];
                sel_e[b * K_ + slot] = idx / T_;
                sel_t[b * K_ + slot] = idx % T_;
                sel_sp[b * K_ + slot] = __expf(bl_v[q]) * rZ;
            } else {  // pathological fallback: harmless zero entries
                sel_e[b * K_ + slot] = 0; sel_t[b * K_ + slot] = 0;
                sel_sp[b * K_ + slot] = 0.f;
            }
        }
    }
}

// up at selected positions via tiled split-x
__global__ void k_upg2(const ushort* __restrict__ xh, const ushort* __restrict__ xl,
                       const float* __restrict__ nrm, const float* __restrict__ uw,
                       const float* __restrict__ ub, const int* __restrict__ sel_e,
                       const int* __restrict__ sel_t, const float* __restrict__ sel_sp,
                       float* __restrict__ gval) {
    int gid = blockIdx.x * 256 + threadIdx.x;   // B*K waves
    int w = gid >> 6, lane = gid & 63;
    int b = w >> 9, i = w & (K_ - 1);
    int e = sel_e[b * K_ + i], t = sel_t[b * K_ + i];
    int ttile = t >> 6, trow = t & 63;
    int cc = lane >> 4, cb = (lane >> 1) & 7, half = lane & 1;
    size_t ro = ((((size_t)b * 128 + ttile) * 4 + cc) * 8 + cb) * 512
              + (size_t)trow * 8 + half * 4;          // c = lane*4 .. +4
    ushort4 h = *(const ushort4*)(xh + ro);
    ushort4 l = *(const ushort4*)(xl + ro);
    float4 wv = *(const float4*)(uw + (size_t)e * C_ + lane * 4);
    float acc = (bf2f(h.x) + bf2f(l.x)) * wv.x + (bf2f(h.y) + bf2f(l.y)) * wv.y
              + (bf2f(h.z) + bf2f(l.z)) * wv.z + (bf2f(h.w) + bf2f(l.w)) * wv.w;
#pragma unroll
    for (int off = 32; off; off >>= 1) acc += __shfl_down(acc, off, 64);
    if (lane == 0)
        gval[b * K_ + i] = sel_sp[b * K_ + i] * (acc * nrm[b * T_ + t] + ub[e]);
}

// fused base/S1/Q + BN stats: one block per channel c, 8 batches inside
__launch_bounds__(256)
__global__ void k_bsqbn(const float* __restrict__ sw, const float* __restrict__ sb,
                        const float* __restrict__ db, const float* __restrict__ dw,
                        const int* __restrict__ sel_e, const float* __restrict__ gval,
                        const float* __restrict__ bnw, const float* __restrict__ bnb,
                        float* __restrict__ scalec, float* __restrict__ obase) {
    __shared__ float barr[8], s1arr[8], qarr[8];
    int c = blockIdx.x;
    int w = threadIdx.x >> 6, lane = threadIdx.x & 63;
#pragma unroll
    for (int rep = 0; rep < 2; ++rep) {
        int b = w + rep * 4;
        float p = 0.f, s = 0.f, q = 0.f;
        for (int i = lane; i < K_; i += 64) {
            int e = sel_e[b * K_ + i];
            float g = gval[b * K_ + i];
            p += g * sw[(size_t)c * E_ + e];
            float wv = dw[(size_t)c * E_ + e] * g;
            s += wv; q += wv * wv;
        }
#pragma unroll
        for (int off = 32; off; off >>= 1) {
            p += __shfl_xor(p, off, 64);
            s += __shfl_xor(s, off, 64);
            q += __shfl_xor(q, off, 64);
        }
        if (lane == 0) {
            barr[b] = p + sb[c] + db[c];
            s1arr[b] = s; qarr[b] = q;
        }
    }
    __syncthreads();
    if (threadIdx.x == 0) {
        float msum = 0.f;
        for (int b = 0; b < B_; ++b) msum += (float)T_ * barr[b] + s1arr[b];
        float mean = msum / (float)(B_ * T_);
        float vs = 0.f;
        for (int b = 0; b < B_; ++b) {
            float d = barr[b] - mean;
            vs += (float)T_ * d * d + 2.0f * d * s1arr[b] + qarr[b];
        }
        float var = vs / (float)(B_ * T_);
        float sc = bnw[c] * rsqrtf(var + 1e-5f);
        scalec[c] = sc;
        for (int b = 0; b < B_; ++b)
            obase[b * C_ + c] = (barr[b] - mean) * sc + bnb[c];
    }
}

// fill output with column-constant base
__global__ void k_fill(const float* __restrict__ obase, float* __restrict__ out) {
    size_t gid = (size_t)blockIdx.x * 256 + threadIdx.x;
    size_t flat = gid * 4;
    int b = (int)(flat / CT_);
    int c = (int)(flat / T_) & (C_ - 1);
    float v = obase[b * C_ + c];
    float4 o = {v, v, v, v};
    *(float4*)(out + flat) = o;
}

// add spikes
__global__ void k_spikes(const float* __restrict__ dw, const float* __restrict__ scalec,
                         const int* __restrict__ sel_e, const int* __restrict__ sel_t,
                         const float* __restrict__ gval, float* __restrict__ out) {
    int gid = blockIdx.x * 256 + threadIdx.x;   // B*K*64 threads
    int s = gid >> 6, cq = (gid & 63) * 4;
    int b = s >> 9, i = s & (K_ - 1);
    int e = sel_e[b * K_ + i], t = sel_t[b * K_ + i];
    float g = gval[b * K_ + i];
#pragma unroll
    for (int q = 0; q < 4; ++q) {
        int c = cq + q;
        atomicAdd(out + (size_t)b * CT_ + (size_t)c * T_ + t,
                  scalec[c] * dw[(size_t)c * E_ + e] * g);
    }
}

extern "C" void kernel_launch(void* const* d_in, const int* in_sizes, int n_in,
                              void* d_out, int out_size, void* d_ws, size_t ws_size,
                              hipStream_t stream) {
    const float* x = (const float*)d_in[0];
    const float* up_w = (const float*)d_in[1];
    const float* up_b = (const float*)d_in[2];
    const float* mask_w = (const float*)d_in[3];
    const float* mask_b = (const float*)d_in[4];
    const float* sum_w = (const float*)d_in[5];
    const float* sum_b = (const float*)d_in[6];
    const float* down_w = (const float*)d_in[7];
    const float* down_b = (const float*)d_in[8];
    const float* bn_w = (const float*)d_in[9];
    const float* bn_b = (const float*)d_in[10];
    float* out = (float*)d_out;

    // workspace layout (float units)
    float* ws = (float*)d_ws;
    size_t o = 0;
    float* rn = ws + o;   o += (size_t)B_ * T_;
    float* nrm = ws + o;  o += (size_t)B_ * T_;
    float* xs = ws + o;   o += (size_t)B_ * C_ * SCOLS_;
    float* msub = ws + o; o += (size_t)B_ * SUBN_;
    float* tau0 = ws + o; o += B_;
    int* gh = (int*)(ws + o);    o += (size_t)B_ * NB1_;
    float* cval = ws + o; o += (size_t)B_ * CAP_;
    int* cidx = (int*)(ws + o);  o += (size_t)B_ * CAP_;
    int* sel_e = (int*)(ws + o); o += (size_t)B_ * K_;
    int* sel_t = (int*)(ws + o); o += (size_t)B_ * K_;
    float* sel_sp = ws + o; o += (size_t)B_ * K_;
    float* gval = ws + o;   o += (size_t)B_ * K_;
    float* scalec = ws + o; o += C_;
    float* obase = ws + o;  o += (size_t)B_ * C_ + 8;
    // no-atomic collection buffers
    float* zpart = ws + o;  o += NBLK_;
    int* cntB = (int*)(ws + o); o += NBLK_;
    float* cvalB = ws + o;  o += (size_t)NBLK_ * BCAP_;
    int* cidxB = (int*)(ws + o); o += (size_t)NBLK_ * BCAP_;
    int* ovc = (int*)(ws + o); o += B_;
    float* ovv = ws + o;    o += (size_t)B_ * OCAP_;
    int* ovi = (int*)(ws + o); o += (size_t)B_ * OCAP_;
    // big split buffers last
    ushort* mwh = (ushort*)(ws + o); o += (size_t)E_ * C_ / 2;
    ushort* mwl = (ushort*)(ws + o); o += (size_t)E_ * C_ / 2;
    ushort* xh = (ushort*)(ws + o);  o += (size_t)B_ * T_ * C_ / 2;
    ushort* xl = (ushort*)(ws + o);  o += (size_t)B_ * T_ * C_ / 2;
    (void)ws_size;

    k_rn<<<(B_ * T_) / 256, 256, 0, stream>>>(x, rn, nrm, ovc);
    k_gather<<<(B_ * C_ * SCOLS_) / 256, 256, 0, stream>>>(x, rn, xs, gh);
    k_msub2<<<dim3(SCOLS_ / 64, E_ / 64, B_), 256, 0, stream>>>(xs, mask_w, mask_b, msub);
    k_tau_hist<<<B_ * TAUP_, 256, 0, stream>>>(msub, gh);
    k_tau2<<<B_, 256, 0, stream>>>(gh, tau0);
    k_split_w<<<(E_ * C_ / 8) / 256, 256, 0, stream>>>(mask_w, mwh, mwl);
    k_split_x<<<dim3(T_ / 64, C_ / 64, B_), 256, 0, stream>>>(x, rn, xh, xl);
    k_gemm128<<<NBLK_, 256, 0, stream>>>(mwh, xh, mask_b, tau0,
                                         zpart, cntB, cvalB, cidxB,
                                         ovc, ovv, ovi);
    k_exact<<<NBLK_ + B_, 256, 0, stream>>>(mwh, mwl, xh, xl, mask_b,
                                            cntB, cidxB, cvalB, ovc, ovi, ovv);
    k_selectc<<<B_, 256, 0, stream>>>(zpart, cntB, cvalB, cidxB,
                                      ovc, ovv, ovi, cval, cidx,
                                      sel_e, sel_t, sel_sp);
    k_upg2<<<(B_ * K_ * 64) / 256, 256, 0, stream>>>(xh, xl, nrm, up_w, up_b,
                                                     sel_e, sel_t, sel_sp, gval);
    k_bsqbn<<<C_, 256, 0, stream>>>(sum_w, sum_b, down_b, down_w, sel_e, gval,
                                    bn_w, bn_b, scalec, obase);
    k_fill<<<(B_ * CT_ / 4) / 256, 256, 0, stream>>>(obase, out);
    k_spikes<<<(B_ * K_ * 64) / 256, 256, 0, stream>>>(down_w, scalec, sel_e, sel_t,
                                                       gval, out);
}

// Round 13
// 252.093 us; speedup vs baseline: 1.0995x; 1.0995x over previous
//
#include <hip/hip_runtime.h>
#include <hip/hip_bf16.h>

// Problem constants (fixed by the reference)
#define B_ 8
#define C_ 256
#define E_ 512
#define T_ 8192
#define K_ 512
#define CT_ (C_*T_)
#define CAP_ 32768          // compacted candidate capacity per batch
#define BCAP_ 512           // per-block LDS candidate capacity
#define OCAP_ 1024          // per-batch overflow capacity
#define NBLK_ 2048          // k_gemm128 grid
#define SUBS_ 64            // t-subsample stride
#define SCOLS_ (T_/SUBS_)   // 128
#define SUBN_ (E_*SCOLS_)   // 65536 subsample points per batch
#define RANK_ 64            // subsample rank -> expected full count ~4096
#define NB1_ 4096           // subsample histogram bins over [-1,1)
#define NB2_ 4096           // selection histogram bins over [0,0.5)
#define TAUP_ 8             // histogram partial blocks per batch
#define TAUM_ 0.004f        // bf16-m error margin (~40 sigma) for collection

typedef __attribute__((ext_vector_type(8))) short bf16x8;
typedef __attribute__((ext_vector_type(4))) float f32x4;

__device__ __forceinline__ ushort f2bf(float f) {
    __hip_bfloat16 h = __float2bfloat16(f);
    return *reinterpret_cast<ushort*>(&h);
}
__device__ __forceinline__ float bf2f(ushort u) {
    __hip_bfloat16 h = *reinterpret_cast<__hip_bfloat16*>(&u);
    return __bfloat162float(h);
}

// async global->LDS, 16B per lane; LDS dest = wave-uniform base + lane*16
__device__ __forceinline__ void gl16(const void* g, void* l) {
    __builtin_amdgcn_global_load_lds(
        (const __attribute__((address_space(1))) void*)g,
        (__attribute__((address_space(3))) void*)l, 16, 0, 0);
}

// Tiled operand layout (ushort units):
//   W tiles:  [etile(8)][cc(4)][cb(8)][erow(64)][8]   (16384 per etile)
//   X tiles:  [b*128+ttile][cc(4)][cb(8)][trow(64)][8] (16384 per ttile)

// rn/nrm; inits ovc, spike map (-1), spk accumulator (0)
__global__ void k_rn(const float* __restrict__ x, float* __restrict__ rn,
                     float* __restrict__ nrm, int* __restrict__ ovc,
                     int* __restrict__ map, float* __restrict__ spk) {
    int gid = blockIdx.x * 256 + threadIdx.x;   // exactly B*T threads
    if (blockIdx.x == 0 && threadIdx.x < B_) ovc[threadIdx.x] = 0;
    map[gid] = -1;
    float4* sp4 = (float4*)spk;                 // B*K*C floats = 262144 float4
#pragma unroll
    for (int j = 0; j < 4; ++j)
        sp4[gid + j * (B_ * T_)] = (float4){0.f, 0.f, 0.f, 0.f};
    int b = gid / T_, t = gid % T_;
    const float* xp = x + (size_t)b * CT_ + t;
    float s0 = 0.f, s1 = 0.f, s2 = 0.f, s3 = 0.f;
    for (int c = 0; c < C_; c += 4) {
        float a0 = xp[(size_t)c * T_];
        float a1 = xp[(size_t)(c + 1) * T_];
        float a2 = xp[(size_t)(c + 2) * T_];
        float a3 = xp[(size_t)(c + 3) * T_];
        s0 += a0 * a0; s1 += a1 * a1; s2 += a2 * a2; s3 += a3 * a3;
    }
    float s = (s0 + s1) + (s2 + s3);
    float n = sqrtf(s) + 1e-8f;
    nrm[gid] = n;
    rn[gid] = 1.0f / n;
}

// split mask_w into bf16 hi/lo, TILED layout (coalesced 16B writes)
__global__ void k_split_w(const float* __restrict__ mw, ushort* __restrict__ mwh,
                          ushort* __restrict__ mwl) {
    int idx = blockIdx.x * 256 + threadIdx.x;   // E*C/8 = 16384 threads
    int erow = idx & 63;
    int cb = (idx >> 6) & 7;
    int cc = (idx >> 9) & 3;
    int etile = idx >> 11;
    int e = etile * 64 + erow;
    int c0 = cc * 64 + cb * 8;
    const float* src = mw + (size_t)e * C_ + c0;
    ushort4 h0, l0, h1, l1;
    float v;
    v = src[0]; h0.x = f2bf(v); l0.x = f2bf(v - bf2f(h0.x));
    v = src[1]; h0.y = f2bf(v); l0.y = f2bf(v - bf2f(h0.y));
    v = src[2]; h0.z = f2bf(v); l0.z = f2bf(v - bf2f(h0.z));
    v = src[3]; h0.w = f2bf(v); l0.w = f2bf(v - bf2f(h0.w));
    v = src[4]; h1.x = f2bf(v); l1.x = f2bf(v - bf2f(h1.x));
    v = src[5]; h1.y = f2bf(v); l1.y = f2bf(v - bf2f(h1.y));
    v = src[6]; h1.z = f2bf(v); l1.z = f2bf(v - bf2f(h1.z));
    v = src[7]; h1.w = f2bf(v); l1.w = f2bf(v - bf2f(h1.w));
    *(ushort4*)(mwh + (size_t)idx * 8) = h0;
    *(ushort4*)(mwh + (size_t)idx * 8 + 4) = h1;
    *(ushort4*)(mwl + (size_t)idx * 8) = l0;
    *(ushort4*)(mwl + (size_t)idx * 8 + 4) = l1;
}

// transpose + rn-scale + split into TILED layout
__launch_bounds__(256)
__global__ void k_split_x(const float* __restrict__ x, const float* __restrict__ rn,
                          ushort* __restrict__ xh, ushort* __restrict__ xl) {
    __shared__ float tile[64][76];
    __shared__ float rnv[64];
    int tid = threadIdx.x;
    int ttile = blockIdx.x, cc = blockIdx.y, b = blockIdx.z;
    int t0 = ttile * 64, c0 = cc * 64;
    if (tid < 64) rnv[tid] = rn[b * T_ + t0 + tid];
    const float* xb = x + (size_t)b * CT_;
#pragma unroll
    for (int q = 0; q < 4; ++q) {
        int idx = tid + q * 256;
        int cr = idx >> 4, t4 = (idx & 15) * 4;
        float4 v = *(const float4*)(xb + (size_t)(c0 + cr) * T_ + t0 + t4);
        *(float4*)&tile[cr][t4] = v;
    }
    __syncthreads();
    size_t obase = (((size_t)b * 128 + ttile) * 4 + cc) * 4096;
#pragma unroll
    for (int q = 0; q < 4; ++q) {
        int idx = tid + q * 256;
        int tr = idx >> 4, c4 = (idx & 15) * 4;
        float s = rnv[tr];
        float v0 = tile[c4 + 0][tr] * s;
        float v1 = tile[c4 + 1][tr] * s;
        float v2 = tile[c4 + 2][tr] * s;
        float v3 = tile[c4 + 3][tr] * s;
        ushort4 h, l;
        h.x = f2bf(v0); l.x = f2bf(v0 - bf2f(h.x));
        h.y = f2bf(v1); l.y = f2bf(v1 - bf2f(h.y));
        h.z = f2bf(v2); l.z = f2bf(v2 - bf2f(h.z));
        h.w = f2bf(v3); l.w = f2bf(v3 - bf2f(h.w));
        int cb = c4 >> 3, half = (c4 >> 2) & 1;
        size_t ro = obase + (size_t)cb * 512 + tr * 8 + half * 4;
        *(ushort4*)(xh + ro) = h;
        *(ushort4*)(xl + ro) = l;
    }
}

// gather subsampled, rn-scaled x; first 32K threads also zero gh
__global__ void k_gather(const float* __restrict__ x, const float* __restrict__ rn,
                         float* __restrict__ xs, int* __restrict__ gh) {
    int gid = blockIdx.x * 256 + threadIdx.x;   // B*C*SCOLS threads = 262144
    if (gid < B_ * NB1_) gh[gid] = 0;
    int s = gid & (SCOLS_ - 1);
    int c = (gid >> 7) & (C_ - 1);
    int b = gid >> 15;
    int t = s * SUBS_;
    xs[gid] = x[(size_t)b * CT_ + (size_t)c * T_ + t] * rn[b * T_ + t];
}

// tiled f32 GEMM on compact gathered buffer (small: ~270 MFLOP)
__launch_bounds__(256)
__global__ void k_msub2(const float* __restrict__ xs, const float* __restrict__ mw,
                        const float* __restrict__ mb, float* __restrict__ msub) {
    __shared__ float As[64][68];
    __shared__ float Bs[64][68];
    int tid = threadIdx.x;
    int tx = tid & 15, ty = tid >> 4;
    int s0 = blockIdx.x * 64, e0 = blockIdx.y * 64, b = blockIdx.z;
    const float* xb = xs + (size_t)b * C_ * SCOLS_;
    float acc[4][4] = {};
    for (int c0 = 0; c0 < C_; c0 += 64) {
#pragma unroll
        for (int r = 0; r < 4; ++r) {
            int i = (tid >> 4) + r * 16;
            int kq = (tid & 15) * 4;
            float4 av = *(const float4*)(mw + (size_t)(e0 + i) * C_ + c0 + kq);
            As[kq + 0][i] = av.x; As[kq + 1][i] = av.y;
            As[kq + 2][i] = av.z; As[kq + 3][i] = av.w;
        }
#pragma unroll
        for (int r = 0; r < 4; ++r) {
            int k = (tid >> 4) + r * 16;
            int jq = (tid & 15) * 4;
            *(float4*)(&Bs[k][jq]) =
                *(const float4*)(xb + (size_t)(c0 + k) * SCOLS_ + s0 + jq);
        }
        __syncthreads();
#pragma unroll
        for (int k = 0; k < 64; ++k) {
            float4 a = *(const float4*)(&As[k][ty * 4]);
            float4 bq = *(const float4*)(&Bs[k][tx * 4]);
            float av[4] = {a.x, a.y, a.z, a.w};
            float bv[4] = {bq.x, bq.y, bq.z, bq.w};
#pragma unroll
            for (int ii = 0; ii < 4; ++ii)
#pragma unroll
                for (int jj = 0; jj < 4; ++jj)
                    acc[ii][jj] += av[ii] * bv[jj];
        }
        __syncthreads();
    }
#pragma unroll
    for (int ii = 0; ii < 4; ++ii) {
        float mbv = mb[e0 + ty * 4 + ii];
#pragma unroll
        for (int jj = 0; jj < 4; ++jj) {
            int e = e0 + ty * 4 + ii, s = s0 + tx * 4 + jj;
            msub[(size_t)b * SUBN_ + e * SCOLS_ + s] = acc[ii][jj] + mbv;
        }
    }
}

// parallel histogram of msub: 64 blocks (8 per batch) -> global gh[b][NB1]
__launch_bounds__(256)
__global__ void k_tau_hist(const float* __restrict__ msub, int* __restrict__ gh) {
    __shared__ int h[NB1_];
    int tid = threadIdx.x;
    int b = blockIdx.x >> 3, part = blockIdx.x & (TAUP_ - 1);
    for (int i = tid; i < NB1_; i += 256) h[i] = 0;
    __syncthreads();
    const float* mp = msub + (size_t)b * SUBN_ + part * (SUBN_ / TAUP_);
    for (int j = tid; j < SUBN_ / TAUP_; j += 256) {
        float v = mp[j];
        int bin = (int)((v + 1.0f) * ((float)NB1_ * 0.5f));
        bin = bin < 0 ? 0 : (bin > NB1_ - 1 ? NB1_ - 1 : bin);
        atomicAdd(&h[bin], 1);
    }
    __syncthreads();
    int* ghb = gh + b * NB1_;
    for (int i = tid; i < NB1_; i += 256)
        if (h[i]) atomicAdd(&ghb[i], h[i]);   // fire-and-forget, low contention
}

// per-batch conservative threshold tau0 from global histogram rank-64
__global__ void k_tau2(const int* __restrict__ gh, float* __restrict__ tau0) {
    __shared__ int part[256];
    int b = blockIdx.x, tid = threadIdx.x;
    const int* h = gh + b * NB1_;
    int ps = 0;
    for (int j = 0; j < 16; ++j) ps += h[tid * 16 + j];
    part[tid] = ps;
    __syncthreads();
    if (tid == 0) {
        int cum = 0, bf = 0;
        for (int i = 255; i >= 0; --i) {
            if (cum + part[i] >= RANK_) {
                int cum2 = cum;
                for (int j = 15; j >= 0; --j) {
                    cum2 += h[i * 16 + j];
                    if (cum2 >= RANK_) { bf = i * 16 + j; break; }
                }
                break;
            }
            cum += part[i];
        }
        tau0[b] = (float)bf * (2.0f / (float)NB1_) - 1.0f;  // bin lower edge
    }
}

// ---------------- fast main GEMM: plain bf16, half staging, 1/3 MFMA --------
__launch_bounds__(256)
__global__ void k_gemm128(const ushort* __restrict__ mwh, const ushort* __restrict__ xh,
                          const float* __restrict__ mb, const float* __restrict__ tau0,
                          float* __restrict__ zpart, int* __restrict__ cntB,
                          float* __restrict__ cvalB, int* __restrict__ cidxB,
                          int* __restrict__ ovc, float* __restrict__ ovv,
                          int* __restrict__ ovi) {
    __shared__ ushort S[4][4096];   // Wh0,Wh1,Xh0,Xh1 (8KB each)
    __shared__ float red[4];
    __shared__ float sval[BCAP_];
    __shared__ int sidx[BCAP_];
    __shared__ int scnt;
    int tid = threadIdx.x, lane = tid & 63, w = tid >> 6;
    int f = blockIdx.x;
    int xcd = f & 7, slot = f >> 3;          // XCD grouping: b == xcd
    int eblk = slot & 3, xt = slot >> 2;     // 4 e-blocks adjacent per x-tile
    int xtile = xcd * 64 + xt;               // 0..511 = b*64 + tt
    int b = xtile >> 6, tt = xtile & 63;
    int e0 = eblk * 128, t0 = tt * 128;
    if (tid == 0) scnt = 0;

    const ushort* base;
    if (w < 2) base = mwh + (size_t)(eblk * 2 + (w & 1)) * 16384;
    else       base = xh + ((size_t)b * 128 + tt * 2 + (w & 1)) * 16384;
    const ushort* gsrc = base + lane * 8;

    f32x4 acc[4][4];
#pragma unroll
    for (int m = 0; m < 4; ++m)
#pragma unroll
        for (int n = 0; n < 4; ++n)
            acc[m][n] = (f32x4){0.f, 0.f, 0.f, 0.f};

    int a15 = lane & 15;
    int khalf = lane >> 4;                   // 0..3
    int wr = w >> 1, wc = w & 1;             // wave's 64x64 quadrant

    for (int cc = 0; cc < 4; ++cc) {
#pragma unroll
        for (int i = 0; i < 8; ++i)
            gl16(gsrc + cc * 4096 + i * 512, &S[w][0] + i * 512);
        __syncthreads();
#pragma unroll
        for (int ks = 0; ks < 2; ++ks) {
            int cb16 = ks * 4 + khalf;
            bf16x8 ah[4], bh[4];
#pragma unroll
            for (int m = 0; m < 4; ++m) {
                int aoff = (cb16 * 64 + m * 16 + a15) * 16;
                ah[m] = *(const bf16x8*)((const char*)&S[wr][0] + aoff);
            }
#pragma unroll
            for (int n = 0; n < 4; ++n) {
                int boff = (cb16 * 64 + n * 16 + a15) * 16;
                bh[n] = *(const bf16x8*)((const char*)&S[2 + wc][0] + boff);
            }
#pragma unroll
            for (int m = 0; m < 4; ++m)
#pragma unroll
                for (int n = 0; n < 4; ++n)
                    acc[m][n] = __builtin_amdgcn_mfma_f32_16x16x32_bf16(ah[m], bh[n], acc[m][n], 0, 0, 0);
        }
        __syncthreads();
    }

    // epilogue: C/D layout col(t)=lane&15, row(e)=(lane>>4)*4+reg
    float tau = tau0[b] - TAUM_;
    float zs = 0.f;
    int erow0 = e0 + wr * 64 + (lane >> 4) * 4;
#pragma unroll
    for (int m = 0; m < 4; ++m)
#pragma unroll
        for (int r = 0; r < 4; ++r) {
            int e = erow0 + m * 16 + r;
            float mbe = mb[e];
#pragma unroll
            for (int n = 0; n < 4; ++n) {
                int t = t0 + wc * 64 + n * 16 + a15;
                float v = acc[m][n][r] + mbe;
                zs += __expf(v);
                if (v >= tau) {
                    int pos = atomicAdd(&scnt, 1);       // LDS atomic (fast)
                    if (pos < BCAP_) {
                        sval[pos] = v;
                        sidx[pos] = e * T_ + t;
                    } else {                             // rare overflow spill
                        int q2 = atomicAdd(&ovc[b], 1);
                        if (q2 < OCAP_) {
                            ovv[b * OCAP_ + q2] = v;
                            ovi[b * OCAP_ + q2] = e * T_ + t;
                        }
                    }
                }
            }
        }
#pragma unroll
    for (int off = 32; off; off >>= 1) zs += __shfl_xor(zs, off, 64);
    if (lane == 0) red[w] = zs;
    __syncthreads();
    // flush: plain stores only
    int nc = scnt < BCAP_ ? scnt : BCAP_;
    for (int j = tid; j < nc; j += 256) {
        cvalB[(size_t)f * BCAP_ + j] = sval[j];
        cidxB[(size_t)f * BCAP_ + j] = sidx[j];
    }
    if (tid == 0) {
        cntB[f] = nc;
        zpart[f] = (red[0] + red[1]) + (red[2] + red[3]);
    }
}

// recompute exact m (f32, split pairs) for every collected candidate
__launch_bounds__(256)
__global__ void k_exact(const ushort* __restrict__ mwh, const ushort* __restrict__ mwl,
                        const ushort* __restrict__ xh, const ushort* __restrict__ xl,
                        const float* __restrict__ mb, const int* __restrict__ cntB,
                        const int* __restrict__ cidxB, float* __restrict__ cvalB,
                        const int* __restrict__ ovc, const int* __restrict__ ovi,
                        float* __restrict__ ovv) {
    int f = blockIdx.x;
    int wv = threadIdx.x >> 6, lane = threadIdx.x & 63;
    int cc = lane >> 4, cb = (lane >> 1) & 7, half = lane & 1;
    int n, b;
    const int* ip;
    float* vp;
    if (f < NBLK_) {
        b = f & 7;
        n = cntB[f]; if (n > BCAP_) n = BCAP_;
        ip = cidxB + (size_t)f * BCAP_;
        vp = cvalB + (size_t)f * BCAP_;
    } else {
        b = f - NBLK_;
        n = ovc[b]; if (n > OCAP_) n = OCAP_;
        ip = ovi + (size_t)b * OCAP_;
        vp = ovv + (size_t)b * OCAP_;
    }
    for (int j = wv; j < n; j += 4) {
        int idx = ip[j];
        int e = idx >> 13, t = idx & (T_ - 1);
        size_t xro = ((((size_t)b * 128 + (t >> 6)) * 4 + cc) * 8 + cb) * 512
                   + (size_t)(t & 63) * 8 + half * 4;
        size_t wro = (((size_t)(e >> 6) * 4 + cc) * 8 + cb) * 512
                   + (size_t)(e & 63) * 8 + half * 4;
        ushort4 hx = *(const ushort4*)(xh + xro);
        ushort4 lx = *(const ushort4*)(xl + xro);
        ushort4 hw = *(const ushort4*)(mwh + wro);
        ushort4 lw = *(const ushort4*)(mwl + wro);
        float a = (bf2f(hw.x) + bf2f(lw.x)) * (bf2f(hx.x) + bf2f(lx.x))
                + (bf2f(hw.y) + bf2f(lw.y)) * (bf2f(hx.y) + bf2f(lx.y))
                + (bf2f(hw.z) + bf2f(lw.z)) * (bf2f(hx.z) + bf2f(lx.z))
                + (bf2f(hw.w) + bf2f(lw.w)) * (bf2f(hx.w) + bf2f(lx.w));
#pragma unroll
        for (int off = 32; off; off >>= 1) a += __shfl_xor(a, off, 64);
        if (lane == 0) vp[j] = a + mb[e];
    }
}

// fused compact + exact top-K selection (one block per batch)
__launch_bounds__(256)
__global__ void k_selectc(const float* __restrict__ zpart, const int* __restrict__ cntB,
                          const float* __restrict__ cvalB, const int* __restrict__ cidxB,
                          const int* __restrict__ ovc, const float* __restrict__ ovv,
                          const int* __restrict__ ovi, float* __restrict__ cval,
                          int* __restrict__ cidx, int* __restrict__ sel_e,
                          int* __restrict__ sel_t, float* __restrict__ sel_sp) {
    __shared__ int pre[256];
    __shared__ float zsh[256];
    __shared__ int h[NB2_];
    __shared__ int part[256];
    __shared__ float bl_v[1024];
    __shared__ int bl_i[1024];
    __shared__ int nb, bstar, nabove, outcnt, ntot;
    int b = blockIdx.x, tid = threadIdx.x;
    // ---- compact phase ----
    int f = b + 8 * tid;                     // region id (b == f&7 decode)
    int c = cntB[f];
    pre[tid] = c;
    zsh[tid] = zpart[f];
    __syncthreads();
    for (int d = 1; d < 256; d <<= 1) {      // inclusive scan
        int v = (tid >= d) ? pre[tid - d] : 0;
        __syncthreads();
        pre[tid] += v;
        __syncthreads();
    }
    int start = pre[tid] - c;
    int total = pre[255];
    for (int j = 0; j < c; ++j) {
        int d = start + j;
        if (d < CAP_) {
            cval[b * CAP_ + d] = cvalB[(size_t)f * BCAP_ + j];
            cidx[b * CAP_ + d] = cidxB[(size_t)f * BCAP_ + j];
        }
    }
    __syncthreads();
    for (int d = 128; d; d >>= 1) {          // Z reduction
        if (tid < d) zsh[tid] += zsh[tid + d];
        __syncthreads();
    }
    int no = ovc[b]; if (no > OCAP_) no = OCAP_;
    for (int j = tid; j < no; j += 256) {
        int d = total + j;
        if (d < CAP_) {
            cval[b * CAP_ + d] = ovv[b * OCAP_ + j];
            cidx[b * CAP_ + d] = ovi[b * OCAP_ + j];
        }
    }
    if (tid == 0) {
        int tot = total + no;
        ntot = tot < CAP_ ? tot : CAP_;
        nb = 0; outcnt = 0;
    }
    for (int i = tid; i < NB2_; i += 256) h[i] = 0;
    __syncthreads();                          // drains global writes
    // ---- select phase ----
    int n = ntot;
    float Zb = zsh[0];
    const float* vp = cval + b * CAP_;
    const int* ip = cidx + b * CAP_;
    for (int j = tid; j < n; j += 256) {
        int bin = (int)(vp[j] * ((float)NB2_ * 2.0f));   // [0,0.5) range
        bin = bin < 0 ? 0 : (bin > NB2_ - 1 ? NB2_ - 1 : bin);
        atomicAdd(&h[bin], 1);
    }
    __syncthreads();
    int ps = 0;
    for (int j = 0; j < 16; ++j) ps += h[tid * 16 + j];
    part[tid] = ps;
    __syncthreads();
    if (tid == 0) {
        int cum = 0, bs = 0, na = 0;
        for (int i = 255; i >= 0; --i) {
            if (cum + part[i] >= K_) {
                int cum2 = cum;
                for (int j = 15; j >= 0; --j) {
                    cum2 += h[i * 16 + j];
                    if (cum2 >= K_) { bs = i * 16 + j; na = cum2 - h[i * 16 + j]; break; }
                }
                break;
            }
            cum += part[i];
        }
        bstar = bs; nabove = na;
    }
    __syncthreads();
    int bs = bstar;
    for (int j = tid; j < n; j += 256) {
        float v = vp[j];
        int bin = (int)(v * ((float)NB2_ * 2.0f));
        bin = bin < 0 ? 0 : (bin > NB2_ - 1 ? NB2_ - 1 : bin);
        if (bin == bs) {
            int q = atomicAdd(&nb, 1);
            if (q < 1024) { bl_v[q] = v; bl_i[q] = ip[j]; }
        }
    }
    __syncthreads();
    float rZ = 1.0f / Zb;
    for (int j = tid; j < n; j += 256) {
        float v = vp[j];
        int bin = (int)(v * ((float)NB2_ * 2.0f));
        bin = bin < 0 ? 0 : (bin > NB2_ - 1 ? NB2_ - 1 : bin);
        if (bin > bs) {
            int q = atomicAdd(&outcnt, 1);
            int idx = ip[j];
            sel_e[b * K_ + q] = idx / T_;
            sel_t[b * K_ + q] = idx % T_;
            sel_sp[b * K_ + q] = __expf(v) * rZ;
        }
    }
    __syncthreads();
    if (tid == 0) {
        int m = nb; if (m > 1024) m = 1024;
        for (int i = 1; i < m; ++i) {          // insertion sort: val desc, idx asc
            float v = bl_v[i]; int id = bl_i[i]; int j = i - 1;
            while (j >= 0 && (bl_v[j] < v || (bl_v[j] == v && bl_i[j] > id))) {
                bl_v[j + 1] = bl_v[j]; bl_i[j + 1] = bl_i[j]; --j;
            }
            bl_v[j + 1] = v; bl_i[j + 1] = id;
        }
        int need = K_ - nabove;
        for (int q = 0; q < need; ++q) {
            int slot = nabove + q;
            if (q < m) {
                int idx = bl_i[q];
                sel_e[b * K_ + slot] = idx / T_;
                sel_t[b * K_ + slot] = idx % T_;
                sel_sp[b * K_ + slot] = __expf(bl_v[q]) * rZ;
            } else {  // pathological fallback: harmless zero entries
                sel_e[b * K_ + slot] = 0; sel_t[b * K_ + slot] = 0;
                sel_sp[b * K_ + slot] = 0.f;
            }
        }
    }
}

// up at selected positions via tiled split-x
__global__ void k_upg2(const ushort* __restrict__ xh, const ushort* __restrict__ xl,
                       const float* __restrict__ nrm, const float* __restrict__ uw,
                       const float* __restrict__ ub, const int* __restrict__ sel_e,
                       const int* __restrict__ sel_t, const float* __restrict__ sel_sp,
                       float* __restrict__ gval) {
    int gid = blockIdx.x * 256 + threadIdx.x;   // B*K waves
    int w = gid >> 6, lane = gid & 63;
    int b = w >> 9, i = w & (K_ - 1);
    int e = sel_e[b * K_ + i], t = sel_t[b * K_ + i];
    int ttile = t >> 6, trow = t & 63;
    int cc = lane >> 4, cb = (lane >> 1) & 7, half = lane & 1;
    size_t ro = ((((size_t)b * 128 + ttile) * 4 + cc) * 8 + cb) * 512
              + (size_t)trow * 8 + half * 4;          // c = lane*4 .. +4
    ushort4 h = *(const ushort4*)(xh + ro);
    ushort4 l = *(const ushort4*)(xl + ro);
    float4 wv = *(const float4*)(uw + (size_t)e * C_ + lane * 4);
    float acc = (bf2f(h.x) + bf2f(l.x)) * wv.x + (bf2f(h.y) + bf2f(l.y)) * wv.y
              + (bf2f(h.z) + bf2f(l.z)) * wv.z + (bf2f(h.w) + bf2f(l.w)) * wv.w;
#pragma unroll
    for (int off = 32; off; off >>= 1) acc += __shfl_down(acc, off, 64);
    if (lane == 0)
        gval[b * K_ + i] = sel_sp[b * K_ + i] * (acc * nrm[b * T_ + t] + ub[e]);
}

// fused base/S1/Q + BN stats: one block per channel c, 8 batches inside
__launch_bounds__(256)
__global__ void k_bsqbn(const float* __restrict__ sw, const float* __restrict__ sb,
                        const float* __restrict__ db, const float* __restrict__ dw,
                        const int* __restrict__ sel_e, const float* __restrict__ gval,
                        const float* __restrict__ bnw, const float* __restrict__ bnb,
                        float* __restrict__ scalec, float* __restrict__ obase) {
    __shared__ float barr[8], s1arr[8], qarr[8];
    int c = blockIdx.x;
    int w = threadIdx.x >> 6, lane = threadIdx.x & 63;
#pragma unroll
    for (int rep = 0; rep < 2; ++rep) {
        int b = w + rep * 4;
        float p = 0.f, s = 0.f, q = 0.f;
        for (int i = lane; i < K_; i += 64) {
            int e = sel_e[b * K_ + i];
            float g = gval[b * K_ + i];
            p += g * sw[(size_t)c * E_ + e];
            float wv = dw[(size_t)c * E_ + e] * g;
            s += wv; q += wv * wv;
        }
#pragma unroll
        for (int off = 32; off; off >>= 1) {
            p += __shfl_xor(p, off, 64);
            s += __shfl_xor(s, off, 64);
            q += __shfl_xor(q, off, 64);
        }
        if (lane == 0) {
            barr[b] = p + sb[c] + db[c];
            s1arr[b] = s; qarr[b] = q;
        }
    }
    __syncthreads();
    if (threadIdx.x == 0) {
        float msum = 0.f;
        for (int b = 0; b < B_; ++b) msum += (float)T_ * barr[b] + s1arr[b];
        float mean = msum / (float)(B_ * T_);
        float vs = 0.f;
        for (int b = 0; b < B_; ++b) {
            float d = barr[b] - mean;
            vs += (float)T_ * d * d + 2.0f * d * s1arr[b] + qarr[b];
        }
        float var = vs / (float)(B_ * T_);
        float sc = bnw[c] * rsqrtf(var + 1e-5f);
        scalec[c] = sc;
        for (int b = 0; b < B_; ++b)
            obase[b * C_ + c] = (barr[b] - mean) * sc + bnb[c];
    }
}

// spike slot assignment: one slot per distinct (b,t); duplicates share winner
__global__ void k_spk1(const int* __restrict__ sel_t, int* __restrict__ map,
                       int* __restrict__ pri) {
    int gid = blockIdx.x * 256 + threadIdx.x;   // B*K threads
    int b = gid >> 9;
    int t = sel_t[gid];
    int old = atomicCAS(&map[b * T_ + t], -1, gid & (K_ - 1));
    pri[gid] = (old == -1) ? (gid & (K_ - 1)) : old;
}

// spike accumulation into compact L2-resident spk[b][slot][c]
__global__ void k_spk2(const float* __restrict__ dw, const float* __restrict__ scalec,
                       const int* __restrict__ sel_e, const int* __restrict__ pri,
                       const float* __restrict__ gval, float* __restrict__ spk) {
    int gid = blockIdx.x * 256 + threadIdx.x;   // B*K*64 threads
    int s = gid >> 6, cq = (gid & 63) * 4;
    int b = s >> 9;
    int e = sel_e[s];
    float g = gval[s];
    int p = pri[s];
    float* dst = spk + ((size_t)(b * K_ + p)) * C_ + cq;
#pragma unroll
    for (int q = 0; q < 4; ++q) {
        int c = cq + q;
        atomicAdd(dst + q, scalec[c] * dw[(size_t)c * E_ + e] * g);
    }
}

// fill output: column-constant base + spike columns from compact spk
__global__ void k_fill2(const float* __restrict__ obase, const int* __restrict__ map,
                        const float* __restrict__ spk, float* __restrict__ out) {
    size_t gid = (size_t)blockIdx.x * 256 + threadIdx.x;
    size_t flat = gid * 4;
    int b = (int)(flat / CT_);
    int c = (int)(flat / T_) & (C_ - 1);
    int t0 = (int)(flat & (T_ - 1));
    float v = obase[b * C_ + c];
    float4 o = {v, v, v, v};
    int4 mp = *(const int4*)(map + b * T_ + t0);
    if (mp.x >= 0) o.x += spk[((size_t)(b * K_ + mp.x)) * C_ + c];
    if (mp.y >= 0) o.y += spk[((size_t)(b * K_ + mp.y)) * C_ + c];
    if (mp.z >= 0) o.z += spk[((size_t)(b * K_ + mp.z)) * C_ + c];
    if (mp.w >= 0) o.w += spk[((size_t)(b * K_ + mp.w)) * C_ + c];
    *(float4*)(out + flat) = o;
}

extern "C" void kernel_launch(void* const* d_in, const int* in_sizes, int n_in,
                              void* d_out, int out_size, void* d_ws, size_t ws_size,
                              hipStream_t stream) {
    const float* x = (const float*)d_in[0];
    const float* up_w = (const float*)d_in[1];
    const float* up_b = (const float*)d_in[2];
    const float* mask_w = (const float*)d_in[3];
    const float* mask_b = (const float*)d_in[4];
    const float* sum_w = (const float*)d_in[5];
    const float* sum_b = (const float*)d_in[6];
    const float* down_w = (const float*)d_in[7];
    const float* down_b = (const float*)d_in[8];
    const float* bn_w = (const float*)d_in[9];
    const float* bn_b = (const float*)d_in[10];
    float* out = (float*)d_out;

    // workspace layout (float units)
    float* ws = (float*)d_ws;
    size_t o = 0;
    float* rn = ws + o;   o += (size_t)B_ * T_;
    float* nrm = ws + o;  o += (size_t)B_ * T_;
    float* xs = ws + o;   o += (size_t)B_ * C_ * SCOLS_;
    float* msub = ws + o; o += (size_t)B_ * SUBN_;
    float* tau0 = ws + o; o += B_;
    int* gh = (int*)(ws + o);    o += (size_t)B_ * NB1_;
    float* cval = ws + o; o += (size_t)B_ * CAP_;
    int* cidx = (int*)(ws + o);  o += (size_t)B_ * CAP_;
    int* sel_e = (int*)(ws + o); o += (size_t)B_ * K_;
    int* sel_t = (int*)(ws + o); o += (size_t)B_ * K_;
    float* sel_sp = ws + o; o += (size_t)B_ * K_;
    float* gval = ws + o;   o += (size_t)B_ * K_;
    float* scalec = ws + o; o += C_;
    float* obase = ws + o;  o += (size_t)B_ * C_ + 8;
    // no-atomic collection buffers
    float* zpart = ws + o;  o += NBLK_;
    int* cntB = (int*)(ws + o); o += NBLK_;
    float* cvalB = ws + o;  o += (size_t)NBLK_ * BCAP_;
    int* cidxB = (int*)(ws + o); o += (size_t)NBLK_ * BCAP_;
    int* ovc = (int*)(ws + o); o += B_;
    float* ovv = ws + o;    o += (size_t)B_ * OCAP_;
    int* ovi = (int*)(ws + o); o += (size_t)B_ * OCAP_;
    // spike buffers
    int* map = (int*)(ws + o);  o += (size_t)B_ * T_;
    int* pri = (int*)(ws + o);  o += (size_t)B_ * K_;
    float* spk = ws + o;        o += (size_t)B_ * K_ * C_;
    // big split buffers last
    ushort* mwh = (ushort*)(ws + o); o += (size_t)E_ * C_ / 2;
    ushort* mwl = (ushort*)(ws + o); o += (size_t)E_ * C_ / 2;
    ushort* xh = (ushort*)(ws + o);  o += (size_t)B_ * T_ * C_ / 2;
    ushort* xl = (ushort*)(ws + o);  o += (size_t)B_ * T_ * C_ / 2;
    (void)ws_size;

    k_rn<<<(B_ * T_) / 256, 256, 0, stream>>>(x, rn, nrm, ovc, map, spk);
    k_gather<<<(B_ * C_ * SCOLS_) / 256, 256, 0, stream>>>(x, rn, xs, gh);
    k_msub2<<<dim3(SCOLS_ / 64, E_ / 64, B_), 256, 0, stream>>>(xs, mask_w, mask_b, msub);
    k_tau_hist<<<B_ * TAUP_, 256, 0, stream>>>(msub, gh);
    k_tau2<<<B_, 256, 0, stream>>>(gh, tau0);
    k_split_w<<<(E_ * C_ / 8) / 256, 256, 0, stream>>>(mask_w, mwh, mwl);
    k_split_x<<<dim3(T_ / 64, C_ / 64, B_), 256, 0, stream>>>(x, rn, xh, xl);
    k_gemm128<<<NBLK_, 256, 0, stream>>>(mwh, xh, mask_b, tau0,
                                         zpart, cntB, cvalB, cidxB,
                                         ovc, ovv, ovi);
    k_exact<<<NBLK_ + B_, 256, 0, stream>>>(mwh, mwl, xh, xl, mask_b,
                                            cntB, cidxB, cvalB, ovc, ovi, ovv);
    k_selectc<<<B_, 256, 0, stream>>>(zpart, cntB, cvalB, cidxB,
                                      ovc, ovv, ovi, cval, cidx,
                                      sel_e, sel_t, sel_sp);
    k_spk1<<<(B_ * K_) / 256, 256, 0, stream>>>(sel_t, map, pri);
    k_upg2<<<(B_ * K_ * 64) / 256, 256, 0, stream>>>(xh, xl, nrm, up_w, up_b,
                                                     sel_e, sel_t, sel_sp, gval);
    k_bsqbn<<<C_, 256, 0, stream>>>(sum_w, sum_b, down_b, down_w, sel_e, gval,
                                    bn_w, bn_b, scalec, obase);
    k_spk2<<<(B_ * K_ * 64) / 256, 256, 0, stream>>>(down_w, scalec, sel_e, pri,
                                                     gval, spk);
    k_fill2<<<(B_ * CT_ / 4) / 256, 256, 0, stream>>>(obase, map, spk, out);
}

// Round 14
// 242.086 us; speedup vs baseline: 1.1450x; 1.0413x over previous
//
#include <hip/hip_runtime.h>
#include <hip/hip_bf16.h>

// Problem constants (fixed by the reference)
#define B_ 8
#define C_ 256
#define E_ 512
#define T_ 8192
#define K_ 512
#define CT_ (C_*T_)
#define CAP_ 32768          // compacted candidate capacity per batch
#define BCAP_ 512           // per-block LDS candidate capacity
#define OCAP_ 1024          // per-batch overflow capacity
#define NBLK_ 2048          // k_gemm128 grid
#define SUBS_ 64            // t-subsample stride
#define SCOLS_ (T_/SUBS_)   // 128
#define SUBN_ (E_*SCOLS_)   // 65536 subsample points per batch
#define RANK_ 64            // subsample rank -> expected full count ~4096
#define NB1_ 4096           // subsample histogram bins over [-1,1)
#define NB2_ 4096           // selection histogram bins over [0,0.5)
#define TAUP_ 8             // histogram partial blocks per batch
#define TAUM_ 0.004f        // bf16-m error margin (~40 sigma) for collection

typedef __attribute__((ext_vector_type(8))) short bf16x8;
typedef __attribute__((ext_vector_type(4))) float f32x4;

__device__ __forceinline__ ushort f2bf(float f) {
    __hip_bfloat16 h = __float2bfloat16(f);
    return *reinterpret_cast<ushort*>(&h);
}
__device__ __forceinline__ float bf2f(ushort u) {
    __hip_bfloat16 h = *reinterpret_cast<__hip_bfloat16*>(&u);
    return __bfloat162float(h);
}

// async global->LDS, 16B per lane; LDS dest = wave-uniform base + lane*16
__device__ __forceinline__ void gl16(const void* g, void* l) {
    __builtin_amdgcn_global_load_lds(
        (const __attribute__((address_space(1))) void*)g,
        (__attribute__((address_space(3))) void*)l, 16, 0, 0);
}

// Tiled operand layout (ushort units):
//   W tiles:  [etile(8)][cc(4)][cb(8)][erow(64)][8]   (16384 per etile)
//   X tiles:  [b*128+ttile][cc(4)][cb(8)][trow(64)][8] (16384 per ttile)

// rn/nrm; inits ovc, spike map (-1), spk accumulator (0)
__global__ void k_rn(const float* __restrict__ x, float* __restrict__ rn,
                     float* __restrict__ nrm, int* __restrict__ ovc,
                     int* __restrict__ map, float* __restrict__ spk) {
    int gid = blockIdx.x * 256 + threadIdx.x;   // exactly B*T threads
    if (blockIdx.x == 0 && threadIdx.x < B_) ovc[threadIdx.x] = 0;
    map[gid] = -1;
    float4* sp4 = (float4*)spk;                 // B*K*C floats = 262144 float4
#pragma unroll
    for (int j = 0; j < 4; ++j)
        sp4[gid + j * (B_ * T_)] = (float4){0.f, 0.f, 0.f, 0.f};
    int b = gid / T_, t = gid % T_;
    const float* xp = x + (size_t)b * CT_ + t;
    float s0 = 0.f, s1 = 0.f, s2 = 0.f, s3 = 0.f;
    for (int c = 0; c < C_; c += 4) {
        float a0 = xp[(size_t)c * T_];
        float a1 = xp[(size_t)(c + 1) * T_];
        float a2 = xp[(size_t)(c + 2) * T_];
        float a3 = xp[(size_t)(c + 3) * T_];
        s0 += a0 * a0; s1 += a1 * a1; s2 += a2 * a2; s3 += a3 * a3;
    }
    float s = (s0 + s1) + (s2 + s3);
    float n = sqrtf(s) + 1e-8f;
    nrm[gid] = n;
    rn[gid] = 1.0f / n;
}

// split mask_w into bf16 hi/lo, TILED layout (coalesced 16B writes)
__global__ void k_split_w(const float* __restrict__ mw, ushort* __restrict__ mwh,
                          ushort* __restrict__ mwl) {
    int idx = blockIdx.x * 256 + threadIdx.x;   // E*C/8 = 16384 threads
    int erow = idx & 63;
    int cb = (idx >> 6) & 7;
    int cc = (idx >> 9) & 3;
    int etile = idx >> 11;
    int e = etile * 64 + erow;
    int c0 = cc * 64 + cb * 8;
    const float* src = mw + (size_t)e * C_ + c0;
    ushort4 h0, l0, h1, l1;
    float v;
    v = src[0]; h0.x = f2bf(v); l0.x = f2bf(v - bf2f(h0.x));
    v = src[1]; h0.y = f2bf(v); l0.y = f2bf(v - bf2f(h0.y));
    v = src[2]; h0.z = f2bf(v); l0.z = f2bf(v - bf2f(h0.z));
    v = src[3]; h0.w = f2bf(v); l0.w = f2bf(v - bf2f(h0.w));
    v = src[4]; h1.x = f2bf(v); l1.x = f2bf(v - bf2f(h1.x));
    v = src[5]; h1.y = f2bf(v); l1.y = f2bf(v - bf2f(h1.y));
    v = src[6]; h1.z = f2bf(v); l1.z = f2bf(v - bf2f(h1.z));
    v = src[7]; h1.w = f2bf(v); l1.w = f2bf(v - bf2f(h1.w));
    *(ushort4*)(mwh + (size_t)idx * 8) = h0;
    *(ushort4*)(mwh + (size_t)idx * 8 + 4) = h1;
    *(ushort4*)(mwl + (size_t)idx * 8) = l0;
    *(ushort4*)(mwl + (size_t)idx * 8 + 4) = l1;
}

// transpose + rn-scale + split into TILED layout
__launch_bounds__(256)
__global__ void k_split_x(const float* __restrict__ x, const float* __restrict__ rn,
                          ushort* __restrict__ xh, ushort* __restrict__ xl) {
    __shared__ float tile[64][76];
    __shared__ float rnv[64];
    int tid = threadIdx.x;
    int ttile = blockIdx.x, cc = blockIdx.y, b = blockIdx.z;
    int t0 = ttile * 64, c0 = cc * 64;
    if (tid < 64) rnv[tid] = rn[b * T_ + t0 + tid];
    const float* xb = x + (size_t)b * CT_;
#pragma unroll
    for (int q = 0; q < 4; ++q) {
        int idx = tid + q * 256;
        int cr = idx >> 4, t4 = (idx & 15) * 4;
        float4 v = *(const float4*)(xb + (size_t)(c0 + cr) * T_ + t0 + t4);
        *(float4*)&tile[cr][t4] = v;
    }
    __syncthreads();
    size_t obase = (((size_t)b * 128 + ttile) * 4 + cc) * 4096;
#pragma unroll
    for (int q = 0; q < 4; ++q) {
        int idx = tid + q * 256;
        int tr = idx >> 4, c4 = (idx & 15) * 4;
        float s = rnv[tr];
        float v0 = tile[c4 + 0][tr] * s;
        float v1 = tile[c4 + 1][tr] * s;
        float v2 = tile[c4 + 2][tr] * s;
        float v3 = tile[c4 + 3][tr] * s;
        ushort4 h, l;
        h.x = f2bf(v0); l.x = f2bf(v0 - bf2f(h.x));
        h.y = f2bf(v1); l.y = f2bf(v1 - bf2f(h.y));
        h.z = f2bf(v2); l.z = f2bf(v2 - bf2f(h.z));
        h.w = f2bf(v3); l.w = f2bf(v3 - bf2f(h.w));
        int cb = c4 >> 3, half = (c4 >> 2) & 1;
        size_t ro = obase + (size_t)cb * 512 + tr * 8 + half * 4;
        *(ushort4*)(xh + ro) = h;
        *(ushort4*)(xl + ro) = l;
    }
}

// gather subsampled, rn-scaled x; first 32K threads also zero gh
__global__ void k_gather(const float* __restrict__ x, const float* __restrict__ rn,
                         float* __restrict__ xs, int* __restrict__ gh) {
    int gid = blockIdx.x * 256 + threadIdx.x;   // B*C*SCOLS threads = 262144
    if (gid < B_ * NB1_) gh[gid] = 0;
    int s = gid & (SCOLS_ - 1);
    int c = (gid >> 7) & (C_ - 1);
    int b = gid >> 15;
    int t = s * SUBS_;
    xs[gid] = x[(size_t)b * CT_ + (size_t)c * T_ + t] * rn[b * T_ + t];
}

// tiled f32 GEMM on compact gathered buffer (small: ~270 MFLOP)
__launch_bounds__(256)
__global__ void k_msub2(const float* __restrict__ xs, const float* __restrict__ mw,
                        const float* __restrict__ mb, float* __restrict__ msub) {
    __shared__ float As[64][68];
    __shared__ float Bs[64][68];
    int tid = threadIdx.x;
    int tx = tid & 15, ty = tid >> 4;
    int s0 = blockIdx.x * 64, e0 = blockIdx.y * 64, b = blockIdx.z;
    const float* xb = xs + (size_t)b * C_ * SCOLS_;
    float acc[4][4] = {};
    for (int c0 = 0; c0 < C_; c0 += 64) {
#pragma unroll
        for (int r = 0; r < 4; ++r) {
            int i = (tid >> 4) + r * 16;
            int kq = (tid & 15) * 4;
            float4 av = *(const float4*)(mw + (size_t)(e0 + i) * C_ + c0 + kq);
            As[kq + 0][i] = av.x; As[kq + 1][i] = av.y;
            As[kq + 2][i] = av.z; As[kq + 3][i] = av.w;
        }
#pragma unroll
        for (int r = 0; r < 4; ++r) {
            int k = (tid >> 4) + r * 16;
            int jq = (tid & 15) * 4;
            *(float4*)(&Bs[k][jq]) =
                *(const float4*)(xb + (size_t)(c0 + k) * SCOLS_ + s0 + jq);
        }
        __syncthreads();
#pragma unroll
        for (int k = 0; k < 64; ++k) {
            float4 a = *(const float4*)(&As[k][ty * 4]);
            float4 bq = *(const float4*)(&Bs[k][tx * 4]);
            float av[4] = {a.x, a.y, a.z, a.w};
            float bv[4] = {bq.x, bq.y, bq.z, bq.w};
#pragma unroll
            for (int ii = 0; ii < 4; ++ii)
#pragma unroll
                for (int jj = 0; jj < 4; ++jj)
                    acc[ii][jj] += av[ii] * bv[jj];
        }
        __syncthreads();
    }
#pragma unroll
    for (int ii = 0; ii < 4; ++ii) {
        float mbv = mb[e0 + ty * 4 + ii];
#pragma unroll
        for (int jj = 0; jj < 4; ++jj) {
            int e = e0 + ty * 4 + ii, s = s0 + tx * 4 + jj;
            msub[(size_t)b * SUBN_ + e * SCOLS_ + s] = acc[ii][jj] + mbv;
        }
    }
}

// parallel histogram of msub: 64 blocks (8 per batch) -> global gh[b][NB1]
__launch_bounds__(256)
__global__ void k_tau_hist(const float* __restrict__ msub, int* __restrict__ gh) {
    __shared__ int h[NB1_];
    int tid = threadIdx.x;
    int b = blockIdx.x >> 3, part = blockIdx.x & (TAUP_ - 1);
    for (int i = tid; i < NB1_; i += 256) h[i] = 0;
    __syncthreads();
    const float* mp = msub + (size_t)b * SUBN_ + part * (SUBN_ / TAUP_);
    for (int j = tid; j < SUBN_ / TAUP_; j += 256) {
        float v = mp[j];
        int bin = (int)((v + 1.0f) * ((float)NB1_ * 0.5f));
        bin = bin < 0 ? 0 : (bin > NB1_ - 1 ? NB1_ - 1 : bin);
        atomicAdd(&h[bin], 1);
    }
    __syncthreads();
    int* ghb = gh + b * NB1_;
    for (int i = tid; i < NB1_; i += 256)
        if (h[i]) atomicAdd(&ghb[i], h[i]);   // fire-and-forget, low contention
}

// per-batch conservative threshold tau0 from global histogram rank-64
__global__ void k_tau2(const int* __restrict__ gh, float* __restrict__ tau0) {
    __shared__ int part[256];
    int b = blockIdx.x, tid = threadIdx.x;
    const int* h = gh + b * NB1_;
    int ps = 0;
    for (int j = 0; j < 16; ++j) ps += h[tid * 16 + j];
    part[tid] = ps;
    __syncthreads();
    if (tid == 0) {
        int cum = 0, bf = 0;
        for (int i = 255; i >= 0; --i) {
            if (cum + part[i] >= RANK_) {
                int cum2 = cum;
                for (int j = 15; j >= 0; --j) {
                    cum2 += h[i * 16 + j];
                    if (cum2 >= RANK_) { bf = i * 16 + j; break; }
                }
                break;
            }
            cum += part[i];
        }
        tau0[b] = (float)bf * (2.0f / (float)NB1_) - 1.0f;  // bin lower edge
    }
}

// ---------------- fast main GEMM: plain bf16, half staging, 1/3 MFMA --------
__launch_bounds__(256)
__global__ void k_gemm128(const ushort* __restrict__ mwh, const ushort* __restrict__ xh,
                          const float* __restrict__ mb, const float* __restrict__ tau0,
                          float* __restrict__ zpart, int* __restrict__ cntB,
                          float* __restrict__ cvalB, int* __restrict__ cidxB,
                          int* __restrict__ ovc, float* __restrict__ ovv,
                          int* __restrict__ ovi) {
    __shared__ ushort S[4][4096];   // Wh0,Wh1,Xh0,Xh1 (8KB each)
    __shared__ float red[4];
    __shared__ float sval[BCAP_];
    __shared__ int sidx[BCAP_];
    __shared__ int scnt;
    int tid = threadIdx.x, lane = tid & 63, w = tid >> 6;
    int f = blockIdx.x;
    int xcd = f & 7, slot = f >> 3;          // XCD grouping: b == xcd
    int eblk = slot & 3, xt = slot >> 2;     // 4 e-blocks adjacent per x-tile
    int xtile = xcd * 64 + xt;               // 0..511 = b*64 + tt
    int b = xtile >> 6, tt = xtile & 63;
    int e0 = eblk * 128, t0 = tt * 128;
    if (tid == 0) scnt = 0;

    const ushort* base;
    if (w < 2) base = mwh + (size_t)(eblk * 2 + (w & 1)) * 16384;
    else       base = xh + ((size_t)b * 128 + tt * 2 + (w & 1)) * 16384;
    const ushort* gsrc = base + lane * 8;

    f32x4 acc[4][4];
#pragma unroll
    for (int m = 0; m < 4; ++m)
#pragma unroll
        for (int n = 0; n < 4; ++n)
            acc[m][n] = (f32x4){0.f, 0.f, 0.f, 0.f};

    int a15 = lane & 15;
    int khalf = lane >> 4;                   // 0..3
    int wr = w >> 1, wc = w & 1;             // wave's 64x64 quadrant

    for (int cc = 0; cc < 4; ++cc) {
#pragma unroll
        for (int i = 0; i < 8; ++i)
            gl16(gsrc + cc * 4096 + i * 512, &S[w][0] + i * 512);
        __syncthreads();
#pragma unroll
        for (int ks = 0; ks < 2; ++ks) {
            int cb16 = ks * 4 + khalf;
            bf16x8 ah[4], bh[4];
#pragma unroll
            for (int m = 0; m < 4; ++m) {
                int aoff = (cb16 * 64 + m * 16 + a15) * 16;
                ah[m] = *(const bf16x8*)((const char*)&S[wr][0] + aoff);
            }
#pragma unroll
            for (int n = 0; n < 4; ++n) {
                int boff = (cb16 * 64 + n * 16 + a15) * 16;
                bh[n] = *(const bf16x8*)((const char*)&S[2 + wc][0] + boff);
            }
#pragma unroll
            for (int m = 0; m < 4; ++m)
#pragma unroll
                for (int n = 0; n < 4; ++n)
                    acc[m][n] = __builtin_amdgcn_mfma_f32_16x16x32_bf16(ah[m], bh[n], acc[m][n], 0, 0, 0);
        }
        __syncthreads();
    }

    // epilogue: C/D layout col(t)=lane&15, row(e)=(lane>>4)*4+reg
    float tau = tau0[b] - TAUM_;
    float zs = 0.f;
    int erow0 = e0 + wr * 64 + (lane >> 4) * 4;
#pragma unroll
    for (int m = 0; m < 4; ++m)
#pragma unroll
        for (int r = 0; r < 4; ++r) {
            int e = erow0 + m * 16 + r;
            float mbe = mb[e];
#pragma unroll
            for (int n = 0; n < 4; ++n) {
                int t = t0 + wc * 64 + n * 16 + a15;
                float v = acc[m][n][r] + mbe;
                zs += __expf(v);
                if (v >= tau) {
                    int pos = atomicAdd(&scnt, 1);       // LDS atomic (fast)
                    if (pos < BCAP_) {
                        sval[pos] = v;
                        sidx[pos] = e * T_ + t;
                    } else {                             // rare overflow spill
                        int q2 = atomicAdd(&ovc[b], 1);
                        if (q2 < OCAP_) {
                            ovv[b * OCAP_ + q2] = v;
                            ovi[b * OCAP_ + q2] = e * T_ + t;
                        }
                    }
                }
            }
        }
#pragma unroll
    for (int off = 32; off; off >>= 1) zs += __shfl_xor(zs, off, 64);
    if (lane == 0) red[w] = zs;
    __syncthreads();
    // flush: plain stores only
    int nc = scnt < BCAP_ ? scnt : BCAP_;
    for (int j = tid; j < nc; j += 256) {
        cvalB[(size_t)f * BCAP_ + j] = sval[j];
        cidxB[(size_t)f * BCAP_ + j] = sidx[j];
    }
    if (tid == 0) {
        cntB[f] = nc;
        zpart[f] = (red[0] + red[1]) + (red[2] + red[3]);
    }
}

// recompute exact m (f32, split pairs) for every collected candidate
__launch_bounds__(256)
__global__ void k_exact(const ushort* __restrict__ mwh, const ushort* __restrict__ mwl,
                        const ushort* __restrict__ xh, const ushort* __restrict__ xl,
                        const float* __restrict__ mb, const int* __restrict__ cntB,
                        const int* __restrict__ cidxB, float* __restrict__ cvalB,
                        const int* __restrict__ ovc, const int* __restrict__ ovi,
                        float* __restrict__ ovv) {
    int f = blockIdx.x;
    int wv = threadIdx.x >> 6, lane = threadIdx.x & 63;
    int cc = lane >> 4, cb = (lane >> 1) & 7, half = lane & 1;
    int n, b;
    const int* ip;
    float* vp;
    if (f < NBLK_) {
        b = f & 7;
        n = cntB[f]; if (n > BCAP_) n = BCAP_;
        ip = cidxB + (size_t)f * BCAP_;
        vp = cvalB + (size_t)f * BCAP_;
    } else {
        b = f - NBLK_;
        n = ovc[b]; if (n > OCAP_) n = OCAP_;
        ip = ovi + (size_t)b * OCAP_;
        vp = ovv + (size_t)b * OCAP_;
    }
    for (int j = wv; j < n; j += 4) {
        int idx = ip[j];
        int e = idx >> 13, t = idx & (T_ - 1);
        size_t xro = ((((size_t)b * 128 + (t >> 6)) * 4 + cc) * 8 + cb) * 512
                   + (size_t)(t & 63) * 8 + half * 4;
        size_t wro = (((size_t)(e >> 6) * 4 + cc) * 8 + cb) * 512
                   + (size_t)(e & 63) * 8 + half * 4;
        ushort4 hx = *(const ushort4*)(xh + xro);
        ushort4 lx = *(const ushort4*)(xl + xro);
        ushort4 hw = *(const ushort4*)(mwh + wro);
        ushort4 lw = *(const ushort4*)(mwl + wro);
        float a = (bf2f(hw.x) + bf2f(lw.x)) * (bf2f(hx.x) + bf2f(lx.x))
                + (bf2f(hw.y) + bf2f(lw.y)) * (bf2f(hx.y) + bf2f(lx.y))
                + (bf2f(hw.z) + bf2f(lw.z)) * (bf2f(hx.z) + bf2f(lx.z))
                + (bf2f(hw.w) + bf2f(lw.w)) * (bf2f(hx.w) + bf2f(lx.w));
#pragma unroll
        for (int off = 32; off; off >>= 1) a += __shfl_xor(a, off, 64);
        if (lane == 0) vp[j] = a + mb[e];
    }
}

// fused compact + exact top-K selection (one block per batch).
// De-serialized: histogram fused into compact copy; single combined pass for
// boundary-collect + above-write; suffix-scan boundary search; parallel-rank
// selection replacing the serial insertion sort (same val-desc/idx-asc order).
__launch_bounds__(256)
__global__ void k_selectc(const float* __restrict__ zpart, const int* __restrict__ cntB,
                          const float* __restrict__ cvalB, const int* __restrict__ cidxB,
                          const int* __restrict__ ovc, const float* __restrict__ ovv,
                          const int* __restrict__ ovi, float* __restrict__ cval,
                          int* __restrict__ cidx, int* __restrict__ sel_e,
                          int* __restrict__ sel_t, float* __restrict__ sel_sp) {
    __shared__ int pre[256];
    __shared__ float zsh[256];
    __shared__ int h[NB2_];
    __shared__ int part[256];
    __shared__ float bl_v[1024];
    __shared__ int bl_i[1024];
    __shared__ int nb, bstar, nabove, outcnt, ntot;
    int b = blockIdx.x, tid = threadIdx.x;
    // ---- compact + histogram phase ----
    int f = b + 8 * tid;                     // region id (b == f&7 decode)
    int c = cntB[f];
    pre[tid] = c;
    zsh[tid] = zpart[f];
    for (int i = tid; i < NB2_; i += 256) h[i] = 0;
    if (tid == 0) { nb = 0; outcnt = 0; bstar = 0; nabove = 0; }
    __syncthreads();
    for (int d = 1; d < 256; d <<= 1) {      // inclusive prefix scan
        int v = (tid >= d) ? pre[tid - d] : 0;
        __syncthreads();
        pre[tid] += v;
        __syncthreads();
    }
    int start = pre[tid] - c;
    int total = pre[255];
    for (int j = 0; j < c; ++j) {
        int d = start + j;
        if (d < CAP_) {
            float v = cvalB[(size_t)f * BCAP_ + j];
            cval[b * CAP_ + d] = v;
            cidx[b * CAP_ + d] = cidxB[(size_t)f * BCAP_ + j];
            int bin = (int)(v * ((float)NB2_ * 2.0f));
            bin = bin < 0 ? 0 : (bin > NB2_ - 1 ? NB2_ - 1 : bin);
            atomicAdd(&h[bin], 1);
        }
    }
    __syncthreads();
    for (int d = 128; d; d >>= 1) {          // Z reduction
        if (tid < d) zsh[tid] += zsh[tid + d];
        __syncthreads();
    }
    int no = ovc[b]; if (no > OCAP_) no = OCAP_;
    for (int j = tid; j < no; j += 256) {
        int d = total + j;
        if (d < CAP_) {
            float v = ovv[b * OCAP_ + j];
            cval[b * CAP_ + d] = v;
            cidx[b * CAP_ + d] = ovi[b * OCAP_ + j];
            int bin = (int)(v * ((float)NB2_ * 2.0f));
            bin = bin < 0 ? 0 : (bin > NB2_ - 1 ? NB2_ - 1 : bin);
            atomicAdd(&h[bin], 1);
        }
    }
    if (tid == 0) {
        int tot = total + no;
        ntot = tot < CAP_ ? tot : CAP_;
    }
    __syncthreads();
    // ---- boundary-bin search: suffix scan over 16-bin group sums ----
    int ps = 0;
#pragma unroll
    for (int j = 0; j < 16; ++j) ps += h[tid * 16 + j];
    part[tid] = ps;
    __syncthreads();
    for (int d = 1; d < 256; d <<= 1) {      // inclusive suffix scan
        int v = (tid + d < 256) ? part[tid + d] : 0;
        __syncthreads();
        part[tid] += v;
        __syncthreads();
    }
    if (part[tid] >= K_ && (tid == 255 || part[tid + 1] < K_)) {
        int cum2 = (tid == 255) ? 0 : part[tid + 1];
        for (int j = 15; j >= 0; --j) {
            cum2 += h[tid * 16 + j];
            if (cum2 >= K_) { bstar = tid * 16 + j; nabove = cum2 - h[tid * 16 + j]; break; }
        }
    }
    __syncthreads();
    // ---- combined pass: write >bs outputs, collect boundary bin ----
    int n = ntot;
    int bs = bstar;
    float rZ = 1.0f / zsh[0];
    const float* vp = cval + b * CAP_;
    const int* ip = cidx + b * CAP_;
    for (int j = tid; j < n; j += 256) {
        float v = vp[j];
        int bin = (int)(v * ((float)NB2_ * 2.0f));
        bin = bin < 0 ? 0 : (bin > NB2_ - 1 ? NB2_ - 1 : bin);
        if (bin > bs) {
            int q = atomicAdd(&outcnt, 1);
            int idx = ip[j];
            sel_e[b * K_ + q] = idx / T_;
            sel_t[b * K_ + q] = idx % T_;
            sel_sp[b * K_ + q] = __expf(v) * rZ;
        } else if (bin == bs) {
            int q = atomicAdd(&nb, 1);
            if (q < 1024) { bl_v[q] = v; bl_i[q] = ip[j]; }
        }
    }
    __syncthreads();
    // ---- parallel rank selection within the boundary bin ----
    int m = nb; if (m > 1024) m = 1024;
    int need = K_ - nabove;
    for (int j = tid; j < m; j += 256) {
        float v = bl_v[j]; int id = bl_i[j];
        int r = 0;
        for (int i = 0; i < m; ++i) {
            float vi = bl_v[i]; int ii = bl_i[i];
            r += (vi > v || (vi == v && ii < id)) ? 1 : 0;
        }
        if (r < need) {
            int slot = nabove + r;
            sel_e[b * K_ + slot] = id / T_;
            sel_t[b * K_ + slot] = id % T_;
            sel_sp[b * K_ + slot] = __expf(v) * rZ;
        }
    }
    // pathological fallback: fewer boundary items than needed -> zero entries
    for (int q = m + tid; q < need; q += 256) {
        int slot = nabove + q;
        sel_e[b * K_ + slot] = 0; sel_t[b * K_ + slot] = 0;
        sel_sp[b * K_ + slot] = 0.f;
    }
}

// up at selected positions via tiled split-x
__global__ void k_upg2(const ushort* __restrict__ xh, const ushort* __restrict__ xl,
                       const float* __restrict__ nrm, const float* __restrict__ uw,
                       const float* __restrict__ ub, const int* __restrict__ sel_e,
                       const int* __restrict__ sel_t, const float* __restrict__ sel_sp,
                       float* __restrict__ gval) {
    int gid = blockIdx.x * 256 + threadIdx.x;   // B*K waves
    int w = gid >> 6, lane = gid & 63;
    int b = w >> 9, i = w & (K_ - 1);
    int e = sel_e[b * K_ + i], t = sel_t[b * K_ + i];
    int ttile = t >> 6, trow = t & 63;
    int cc = lane >> 4, cb = (lane >> 1) & 7, half = lane & 1;
    size_t ro = ((((size_t)b * 128 + ttile) * 4 + cc) * 8 + cb) * 512
              + (size_t)trow * 8 + half * 4;          // c = lane*4 .. +4
    ushort4 h = *(const ushort4*)(xh + ro);
    ushort4 l = *(const ushort4*)(xl + ro);
    float4 wv = *(const float4*)(uw + (size_t)e * C_ + lane * 4);
    float acc = (bf2f(h.x) + bf2f(l.x)) * wv.x + (bf2f(h.y) + bf2f(l.y)) * wv.y
              + (bf2f(h.z) + bf2f(l.z)) * wv.z + (bf2f(h.w) + bf2f(l.w)) * wv.w;
#pragma unroll
    for (int off = 32; off; off >>= 1) acc += __shfl_down(acc, off, 64);
    if (lane == 0)
        gval[b * K_ + i] = sel_sp[b * K_ + i] * (acc * nrm[b * T_ + t] + ub[e]);
}

// fused base/S1/Q + BN stats: one block per channel c, 8 batches inside
__launch_bounds__(256)
__global__ void k_bsqbn(const float* __restrict__ sw, const float* __restrict__ sb,
                        const float* __restrict__ db, const float* __restrict__ dw,
                        const int* __restrict__ sel_e, const float* __restrict__ gval,
                        const float* __restrict__ bnw, const float* __restrict__ bnb,
                        float* __restrict__ scalec, float* __restrict__ obase) {
    __shared__ float barr[8], s1arr[8], qarr[8];
    int c = blockIdx.x;
    int w = threadIdx.x >> 6, lane = threadIdx.x & 63;
#pragma unroll
    for (int rep = 0; rep < 2; ++rep) {
        int b = w + rep * 4;
        float p = 0.f, s = 0.f, q = 0.f;
        for (int i = lane; i < K_; i += 64) {
            int e = sel_e[b * K_ + i];
            float g = gval[b * K_ + i];
            p += g * sw[(size_t)c * E_ + e];
            float wv = dw[(size_t)c * E_ + e] * g;
            s += wv; q += wv * wv;
        }
#pragma unroll
        for (int off = 32; off; off >>= 1) {
            p += __shfl_xor(p, off, 64);
            s += __shfl_xor(s, off, 64);
            q += __shfl_xor(q, off, 64);
        }
        if (lane == 0) {
            barr[b] = p + sb[c] + db[c];
            s1arr[b] = s; qarr[b] = q;
        }
    }
    __syncthreads();
    if (threadIdx.x == 0) {
        float msum = 0.f;
        for (int b = 0; b < B_; ++b) msum += (float)T_ * barr[b] + s1arr[b];
        float mean = msum / (float)(B_ * T_);
        float vs = 0.f;
        for (int b = 0; b < B_; ++b) {
            float d = barr[b] - mean;
            vs += (float)T_ * d * d + 2.0f * d * s1arr[b] + qarr[b];
        }
        float var = vs / (float)(B_ * T_);
        float sc = bnw[c] * rsqrtf(var + 1e-5f);
        scalec[c] = sc;
        for (int b = 0; b < B_; ++b)
            obase[b * C_ + c] = (barr[b] - mean) * sc + bnb[c];
    }
}

// spike slot assignment: one slot per distinct (b,t); duplicates share winner
__global__ void k_spk1(const int* __restrict__ sel_t, int* __restrict__ map,
                       int* __restrict__ pri) {
    int gid = blockIdx.x * 256 + threadIdx.x;   // B*K threads
    int b = gid >> 9;
    int t = sel_t[gid];
    int old = atomicCAS(&map[b * T_ + t], -1, gid & (K_ - 1));
    pri[gid] = (old == -1) ? (gid & (K_ - 1)) : old;
}

// spike accumulation into compact L2-resident spk[b][slot][c]
__global__ void k_spk2(const float* __restrict__ dw, const float* __restrict__ scalec,
                       const int* __restrict__ sel_e, const int* __restrict__ pri,
                       const float* __restrict__ gval, float* __restrict__ spk) {
    int gid = blockIdx.x * 256 + threadIdx.x;   // B*K*64 threads
    int s = gid >> 6, cq = (gid & 63) * 4;
    int b = s >> 9;
    int e = sel_e[s];
    float g = gval[s];
    int p = pri[s];
    float* dst = spk + ((size_t)(b * K_ + p)) * C_ + cq;
#pragma unroll
    for (int q = 0; q < 4; ++q) {
        int c = cq + q;
        atomicAdd(dst + q, scalec[c] * dw[(size_t)c * E_ + e] * g);
    }
}

// fill output: column-constant base + spike columns from compact spk
__global__ void k_fill2(const float* __restrict__ obase, const int* __restrict__ map,
                        const float* __restrict__ spk, float* __restrict__ out) {
    size_t gid = (size_t)blockIdx.x * 256 + threadIdx.x;
    size_t flat = gid * 4;
    int b = (int)(flat / CT_);
    int c = (int)(flat / T_) & (C_ - 1);
    int t0 = (int)(flat & (T_ - 1));
    float v = obase[b * C_ + c];
    float4 o = {v, v, v, v};
    int4 mp = *(const int4*)(map + b * T_ + t0);
    if (mp.x >= 0) o.x += spk[((size_t)(b * K_ + mp.x)) * C_ + c];
    if (mp.y >= 0) o.y += spk[((size_t)(b * K_ + mp.y)) * C_ + c];
    if (mp.z >= 0) o.z += spk[((size_t)(b * K_ + mp.z)) * C_ + c];
    if (mp.w >= 0) o.w += spk[((size_t)(b * K_ + mp.w)) * C_ + c];
    *(float4*)(out + flat) = o;
}

extern "C" void kernel_launch(void* const* d_in, const int* in_sizes, int n_in,
                              void* d_out, int out_size, void* d_ws, size_t ws_size,
                              hipStream_t stream) {
    const float* x = (const float*)d_in[0];
    const float* up_w = (const float*)d_in[1];
    const float* up_b = (const float*)d_in[2];
    const float* mask_w = (const float*)d_in[3];
    const float* mask_b = (const float*)d_in[4];
    const float* sum_w = (const float*)d_in[5];
    const float* sum_b = (const float*)d_in[6];
    const float* down_w = (const float*)d_in[7];
    const float* down_b = (const float*)d_in[8];
    const float* bn_w = (const float*)d_in[9];
    const float* bn_b = (const float*)d_in[10];
    float* out = (float*)d_out;

    // workspace layout (float units)
    float* ws = (float*)d_ws;
    size_t o = 0;
    float* rn = ws + o;   o += (size_t)B_ * T_;
    float* nrm = ws + o;  o += (size_t)B_ * T_;
    float* xs = ws + o;   o += (size_t)B_ * C_ * SCOLS_;
    float* msub = ws + o; o += (size_t)B_ * SUBN_;
    float* tau0 = ws + o; o += B_;
    int* gh = (int*)(ws + o);    o += (size_t)B_ * NB1_;
    float* cval = ws + o; o += (size_t)B_ * CAP_;
    int* cidx = (int*)(ws + o);  o += (size_t)B_ * CAP_;
    int* sel_e = (int*)(ws + o); o += (size_t)B_ * K_;
    int* sel_t = (int*)(ws + o); o += (size_t)B_ * K_;
    float* sel_sp = ws + o; o += (size_t)B_ * K_;
    float* gval = ws + o;   o += (size_t)B_ * K_;
    float* scalec = ws + o; o += C_;
    float* obase = ws + o;  o += (size_t)B_ * C_ + 8;
    // no-atomic collection buffers
    float* zpart = ws + o;  o += NBLK_;
    int* cntB = (int*)(ws + o); o += NBLK_;
    float* cvalB = ws + o;  o += (size_t)NBLK_ * BCAP_;
    int* cidxB = (int*)(ws + o); o += (size_t)NBLK_ * BCAP_;
    int* ovc = (int*)(ws + o); o += B_;
    float* ovv = ws + o;    o += (size_t)B_ * OCAP_;
    int* ovi = (int*)(ws + o); o += (size_t)B_ * OCAP_;
    // spike buffers
    int* map = (int*)(ws + o);  o += (size_t)B_ * T_;
    int* pri = (int*)(ws + o);  o += (size_t)B_ * K_;
    float* spk = ws + o;        o += (size_t)B_ * K_ * C_;
    // big split buffers last
    ushort* mwh = (ushort*)(ws + o); o += (size_t)E_ * C_ / 2;
    ushort* mwl = (ushort*)(ws + o); o += (size_t)E_ * C_ / 2;
    ushort* xh = (ushort*)(ws + o);  o += (size_t)B_ * T_ * C_ / 2;
    ushort* xl = (ushort*)(ws + o);  o += (size_t)B_ * T_ * C_ / 2;
    (void)ws_size;

    k_rn<<<(B_ * T_) / 256, 256, 0, stream>>>(x, rn, nrm, ovc, map, spk);
    k_gather<<<(B_ * C_ * SCOLS_) / 256, 256, 0, stream>>>(x, rn, xs, gh);
    k_msub2<<<dim3(SCOLS_ / 64, E_ / 64, B_), 256, 0, stream>>>(xs, mask_w, mask_b, msub);
    k_tau_hist<<<B_ * TAUP_, 256, 0, stream>>>(msub, gh);
    k_tau2<<<B_, 256, 0, stream>>>(gh, tau0);
    k_split_w<<<(E_ * C_ / 8) / 256, 256, 0, stream>>>(mask_w, mwh, mwl);
    k_split_x<<<dim3(T_ / 64, C_ / 64, B_), 256, 0, stream>>>(x, rn, xh, xl);
    k_gemm128<<<NBLK_, 256, 0, stream>>>(mwh, xh, mask_b, tau0,
                                         zpart, cntB, cvalB, cidxB,
                                         ovc, ovv, ovi);
    k_exact<<<NBLK_ + B_, 256, 0, stream>>>(mwh, mwl, xh, xl, mask_b,
                                            cntB, cidxB, cvalB, ovc, ovi, ovv);
    k_selectc<<<B_, 256, 0, stream>>>(zpart, cntB, cvalB, cidxB,
                                      ovc, ovv, ovi, cval, cidx,
                                      sel_e, sel_t, sel_sp);
    k_spk1<<<(B_ * K_) / 256, 256, 0, stream>>>(sel_t, map, pri);
    k_upg2<<<(B_ * K_ * 64) / 256, 256, 0, stream>>>(xh, xl, nrm, up_w, up_b,
                                                     sel_e, sel_t, sel_sp, gval);
    k_bsqbn<<<C_, 256, 0, stream>>>(sum_w, sum_b, down_b, down_w, sel_e, gval,
                                    bn_w, bn_b, scalec, obase);
    k_spk2<<<(B_ * K_ * 64) / 256, 256, 0, stream>>>(down_w, scalec, sel_e, pri,
                                                     gval, spk);
    k_fill2<<<(B_ * CT_ / 4) / 256, 256, 0, stream>>>(obase, map, spk, out);
}

// Round 15
// 233.727 us; speedup vs baseline: 1.1859x; 1.0358x over previous
//
#include <hip/hip_runtime.h>
#include <hip/hip_bf16.h>

// Problem constants (fixed by the reference)
#define B_ 8
#define C_ 256
#define E_ 512
#define T_ 8192
#define K_ 512
#define CT_ (C_*T_)
#define CAP_ 32768          // compacted candidate capacity per batch
#define BCAP_ 512           // per-block LDS candidate capacity
#define OCAP_ 1024          // per-batch overflow capacity
#define NBLK_ 2048          // k_gemm128 grid
#define SUBS_ 64            // t-subsample stride
#define SCOLS_ (T_/SUBS_)   // 128
#define SUBN_ (E_*SCOLS_)   // 65536 subsample points per batch
#define RANK_ 64            // subsample rank -> expected full count ~4096
#define NB1_ 4096           // subsample histogram bins over [-1,1)
#define NB2_ 4096           // selection histogram bins over [0,0.5)
#define TAUP_ 8             // histogram partial blocks per batch
#define TAUM_ 0.004f        // bf16-m error margin (~40 sigma) for collection

typedef __attribute__((ext_vector_type(8))) short bf16x8;
typedef __attribute__((ext_vector_type(4))) float f32x4;

__device__ __forceinline__ ushort f2bf(float f) {
    __hip_bfloat16 h = __float2bfloat16(f);
    return *reinterpret_cast<ushort*>(&h);
}
__device__ __forceinline__ float bf2f(ushort u) {
    __hip_bfloat16 h = *reinterpret_cast<__hip_bfloat16*>(&u);
    return __bfloat162float(h);
}

// async global->LDS, 16B per lane; LDS dest = wave-uniform base + lane*16
__device__ __forceinline__ void gl16(const void* g, void* l) {
    __builtin_amdgcn_global_load_lds(
        (const __attribute__((address_space(1))) void*)g,
        (__attribute__((address_space(3))) void*)l, 16, 0, 0);
}

// Tiled operand layout (ushort units):
//   W tiles:  [etile(8)][cc(4)][cb(8)][erow(64)][8]   (16384 per etile)
//   X tiles:  [b*128+ttile][cc(4)][cb(8)][trow(64)][8] (16384 per ttile)

// rn/nrm, 4x wave-parallel over channels; also inits ovc/map/spk
// grid: B*T/64 = 1024 blocks x 256 threads
__launch_bounds__(256)
__global__ void k_rn(const float* __restrict__ x, float* __restrict__ rn,
                     float* __restrict__ nrm, int* __restrict__ ovc,
                     int* __restrict__ map, float* __restrict__ spk) {
    __shared__ float partial[4][64];
    int tid = threadIdx.x, lane = tid & 63, w = tid >> 6;
    int bid = blockIdx.x;
    int gid = bid * 256 + tid;                  // 0 .. 262143
    if (gid < B_) ovc[gid] = 0;
    if (gid < B_ * T_) map[gid] = -1;
    ((float4*)spk)[gid] = (float4){0.f, 0.f, 0.f, 0.f};  // B*K*C/4 = 262144
    int b = bid >> 7;
    int t = (bid & 127) * 64 + lane;
    const float* xp = x + (size_t)b * CT_ + (size_t)(w * 64) * T_ + t;
    float s0 = 0.f, s1 = 0.f, s2 = 0.f, s3 = 0.f;
#pragma unroll 4
    for (int c = 0; c < 64; c += 4) {
        float a0 = xp[(size_t)c * T_];
        float a1 = xp[(size_t)(c + 1) * T_];
        float a2 = xp[(size_t)(c + 2) * T_];
        float a3 = xp[(size_t)(c + 3) * T_];
        s0 += a0 * a0; s1 += a1 * a1; s2 += a2 * a2; s3 += a3 * a3;
    }
    partial[w][lane] = (s0 + s1) + (s2 + s3);
    __syncthreads();
    if (w == 0) {
        float s = (partial[0][lane] + partial[1][lane])
                + (partial[2][lane] + partial[3][lane]);
        float n = sqrtf(s) + 1e-8f;
        nrm[b * T_ + t] = n;
        rn[b * T_ + t] = 1.0f / n;
    }
}

// split mask_w into bf16 hi/lo, TILED layout (coalesced 16B writes)
__global__ void k_split_w(const float* __restrict__ mw, ushort* __restrict__ mwh,
                          ushort* __restrict__ mwl) {
    int idx = blockIdx.x * 256 + threadIdx.x;   // E*C/8 = 16384 threads
    int erow = idx & 63;
    int cb = (idx >> 6) & 7;
    int cc = (idx >> 9) & 3;
    int etile = idx >> 11;
    int e = etile * 64 + erow;
    int c0 = cc * 64 + cb * 8;
    const float* src = mw + (size_t)e * C_ + c0;
    ushort4 h0, l0, h1, l1;
    float v;
    v = src[0]; h0.x = f2bf(v); l0.x = f2bf(v - bf2f(h0.x));
    v = src[1]; h0.y = f2bf(v); l0.y = f2bf(v - bf2f(h0.y));
    v = src[2]; h0.z = f2bf(v); l0.z = f2bf(v - bf2f(h0.z));
    v = src[3]; h0.w = f2bf(v); l0.w = f2bf(v - bf2f(h0.w));
    v = src[4]; h1.x = f2bf(v); l1.x = f2bf(v - bf2f(h1.x));
    v = src[5]; h1.y = f2bf(v); l1.y = f2bf(v - bf2f(h1.y));
    v = src[6]; h1.z = f2bf(v); l1.z = f2bf(v - bf2f(h1.z));
    v = src[7]; h1.w = f2bf(v); l1.w = f2bf(v - bf2f(h1.w));
    *(ushort4*)(mwh + (size_t)idx * 8) = h0;
    *(ushort4*)(mwh + (size_t)idx * 8 + 4) = h1;
    *(ushort4*)(mwl + (size_t)idx * 8) = l0;
    *(ushort4*)(mwl + (size_t)idx * 8 + 4) = l1;
}

// transpose + rn-scale + split into TILED layout
__launch_bounds__(256)
__global__ void k_split_x(const float* __restrict__ x, const float* __restrict__ rn,
                          ushort* __restrict__ xh, ushort* __restrict__ xl) {
    __shared__ float tile[64][76];
    __shared__ float rnv[64];
    int tid = threadIdx.x;
    int ttile = blockIdx.x, cc = blockIdx.y, b = blockIdx.z;
    int t0 = ttile * 64, c0 = cc * 64;
    if (tid < 64) rnv[tid] = rn[b * T_ + t0 + tid];
    const float* xb = x + (size_t)b * CT_;
#pragma unroll
    for (int q = 0; q < 4; ++q) {
        int idx = tid + q * 256;
        int cr = idx >> 4, t4 = (idx & 15) * 4;
        float4 v = *(const float4*)(xb + (size_t)(c0 + cr) * T_ + t0 + t4);
        *(float4*)&tile[cr][t4] = v;
    }
    __syncthreads();
    size_t obase = (((size_t)b * 128 + ttile) * 4 + cc) * 4096;
#pragma unroll
    for (int q = 0; q < 4; ++q) {
        int idx = tid + q * 256;
        int tr = idx >> 4, c4 = (idx & 15) * 4;
        float s = rnv[tr];
        float v0 = tile[c4 + 0][tr] * s;
        float v1 = tile[c4 + 1][tr] * s;
        float v2 = tile[c4 + 2][tr] * s;
        float v3 = tile[c4 + 3][tr] * s;
        ushort4 h, l;
        h.x = f2bf(v0); l.x = f2bf(v0 - bf2f(h.x));
        h.y = f2bf(v1); l.y = f2bf(v1 - bf2f(h.y));
        h.z = f2bf(v2); l.z = f2bf(v2 - bf2f(h.z));
        h.w = f2bf(v3); l.w = f2bf(v3 - bf2f(h.w));
        int cb = c4 >> 3, half = (c4 >> 2) & 1;
        size_t ro = obase + (size_t)cb * 512 + tr * 8 + half * 4;
        *(ushort4*)(xh + ro) = h;
        *(ushort4*)(xl + ro) = l;
    }
}

// gather subsampled, rn-scaled x; first 32K threads also zero gh
__global__ void k_gather(const float* __restrict__ x, const float* __restrict__ rn,
                         float* __restrict__ xs, int* __restrict__ gh) {
    int gid = blockIdx.x * 256 + threadIdx.x;   // B*C*SCOLS threads = 262144
    if (gid < B_ * NB1_) gh[gid] = 0;
    int s = gid & (SCOLS_ - 1);
    int c = (gid >> 7) & (C_ - 1);
    int b = gid >> 15;
    int t = s * SUBS_;
    xs[gid] = x[(size_t)b * CT_ + (size_t)c * T_ + t] * rn[b * T_ + t];
}

// tiled f32 GEMM on compact gathered buffer (small: ~270 MFLOP)
__launch_bounds__(256)
__global__ void k_msub2(const float* __restrict__ xs, const float* __restrict__ mw,
                        const float* __restrict__ mb, float* __restrict__ msub) {
    __shared__ float As[64][68];
    __shared__ float Bs[64][68];
    int tid = threadIdx.x;
    int tx = tid & 15, ty = tid >> 4;
    int s0 = blockIdx.x * 64, e0 = blockIdx.y * 64, b = blockIdx.z;
    const float* xb = xs + (size_t)b * C_ * SCOLS_;
    float acc[4][4] = {};
    for (int c0 = 0; c0 < C_; c0 += 64) {
#pragma unroll
        for (int r = 0; r < 4; ++r) {
            int i = (tid >> 4) + r * 16;
            int kq = (tid & 15) * 4;
            float4 av = *(const float4*)(mw + (size_t)(e0 + i) * C_ + c0 + kq);
            As[kq + 0][i] = av.x; As[kq + 1][i] = av.y;
            As[kq + 2][i] = av.z; As[kq + 3][i] = av.w;
        }
#pragma unroll
        for (int r = 0; r < 4; ++r) {
            int k = (tid >> 4) + r * 16;
            int jq = (tid & 15) * 4;
            *(float4*)(&Bs[k][jq]) =
                *(const float4*)(xb + (size_t)(c0 + k) * SCOLS_ + s0 + jq);
        }
        __syncthreads();
#pragma unroll
        for (int k = 0; k < 64; ++k) {
            float4 a = *(const float4*)(&As[k][ty * 4]);
            float4 bq = *(const float4*)(&Bs[k][tx * 4]);
            float av[4] = {a.x, a.y, a.z, a.w};
            float bv[4] = {bq.x, bq.y, bq.z, bq.w};
#pragma unroll
            for (int ii = 0; ii < 4; ++ii)
#pragma unroll
                for (int jj = 0; jj < 4; ++jj)
                    acc[ii][jj] += av[ii] * bv[jj];
        }
        __syncthreads();
    }
#pragma unroll
    for (int ii = 0; ii < 4; ++ii) {
        float mbv = mb[e0 + ty * 4 + ii];
#pragma unroll
        for (int jj = 0; jj < 4; ++jj) {
            int e = e0 + ty * 4 + ii, s = s0 + tx * 4 + jj;
            msub[(size_t)b * SUBN_ + e * SCOLS_ + s] = acc[ii][jj] + mbv;
        }
    }
}

// parallel histogram of msub: 64 blocks (8 per batch) -> global gh[b][NB1]
__launch_bounds__(256)
__global__ void k_tau_hist(const float* __restrict__ msub, int* __restrict__ gh) {
    __shared__ int h[NB1_];
    int tid = threadIdx.x;
    int b = blockIdx.x >> 3, part = blockIdx.x & (TAUP_ - 1);
    for (int i = tid; i < NB1_; i += 256) h[i] = 0;
    __syncthreads();
    const float* mp = msub + (size_t)b * SUBN_ + part * (SUBN_ / TAUP_);
    for (int j = tid; j < SUBN_ / TAUP_; j += 256) {
        float v = mp[j];
        int bin = (int)((v + 1.0f) * ((float)NB1_ * 0.5f));
        bin = bin < 0 ? 0 : (bin > NB1_ - 1 ? NB1_ - 1 : bin);
        atomicAdd(&h[bin], 1);
    }
    __syncthreads();
    int* ghb = gh + b * NB1_;
    for (int i = tid; i < NB1_; i += 256)
        if (h[i]) atomicAdd(&ghb[i], h[i]);   // fire-and-forget, low contention
}

// per-batch conservative threshold tau0 from global histogram rank-64
__global__ void k_tau2(const int* __restrict__ gh, float* __restrict__ tau0) {
    __shared__ int part[256];
    int b = blockIdx.x, tid = threadIdx.x;
    const int* h = gh + b * NB1_;
    int ps = 0;
    for (int j = 0; j < 16; ++j) ps += h[tid * 16 + j];
    part[tid] = ps;
    __syncthreads();
    if (tid == 0) {
        int cum = 0, bf = 0;
        for (int i = 255; i >= 0; --i) {
            if (cum + part[i] >= RANK_) {
                int cum2 = cum;
                for (int j = 15; j >= 0; --j) {
                    cum2 += h[i * 16 + j];
                    if (cum2 >= RANK_) { bf = i * 16 + j; break; }
                }
                break;
            }
            cum += part[i];
        }
        tau0[b] = (float)bf * (2.0f / (float)NB1_) - 1.0f;  // bin lower edge
    }
}

// ---------------- fast main GEMM: plain bf16, half staging, 1/3 MFMA --------
__launch_bounds__(256)
__global__ void k_gemm128(const ushort* __restrict__ mwh, const ushort* __restrict__ xh,
                          const float* __restrict__ mb, const float* __restrict__ tau0,
                          float* __restrict__ zpart, int* __restrict__ cntB,
                          float* __restrict__ cvalB, int* __restrict__ cidxB,
                          int* __restrict__ ovc, float* __restrict__ ovv,
                          int* __restrict__ ovi) {
    __shared__ ushort S[4][4096];   // Wh0,Wh1,Xh0,Xh1 (8KB each)
    __shared__ float red[4];
    __shared__ float sval[BCAP_];
    __shared__ int sidx[BCAP_];
    __shared__ int scnt;
    int tid = threadIdx.x, lane = tid & 63, w = tid >> 6;
    int f = blockIdx.x;
    int xcd = f & 7, slot = f >> 3;          // XCD grouping: b == xcd
    int eblk = slot & 3, xt = slot >> 2;     // 4 e-blocks adjacent per x-tile
    int xtile = xcd * 64 + xt;               // 0..511 = b*64 + tt
    int b = xtile >> 6, tt = xtile & 63;
    int e0 = eblk * 128, t0 = tt * 128;
    if (tid == 0) scnt = 0;

    const ushort* base;
    if (w < 2) base = mwh + (size_t)(eblk * 2 + (w & 1)) * 16384;
    else       base = xh + ((size_t)b * 128 + tt * 2 + (w & 1)) * 16384;
    const ushort* gsrc = base + lane * 8;

    f32x4 acc[4][4];
#pragma unroll
    for (int m = 0; m < 4; ++m)
#pragma unroll
        for (int n = 0; n < 4; ++n)
            acc[m][n] = (f32x4){0.f, 0.f, 0.f, 0.f};

    int a15 = lane & 15;
    int khalf = lane >> 4;                   // 0..3
    int wr = w >> 1, wc = w & 1;             // wave's 64x64 quadrant

    for (int cc = 0; cc < 4; ++cc) {
#pragma unroll
        for (int i = 0; i < 8; ++i)
            gl16(gsrc + cc * 4096 + i * 512, &S[w][0] + i * 512);
        __syncthreads();
#pragma unroll
        for (int ks = 0; ks < 2; ++ks) {
            int cb16 = ks * 4 + khalf;
            bf16x8 ah[4], bh[4];
#pragma unroll
            for (int m = 0; m < 4; ++m) {
                int aoff = (cb16 * 64 + m * 16 + a15) * 16;
                ah[m] = *(const bf16x8*)((const char*)&S[wr][0] + aoff);
            }
#pragma unroll
            for (int n = 0; n < 4; ++n) {
                int boff = (cb16 * 64 + n * 16 + a15) * 16;
                bh[n] = *(const bf16x8*)((const char*)&S[2 + wc][0] + boff);
            }
#pragma unroll
            for (int m = 0; m < 4; ++m)
#pragma unroll
                for (int n = 0; n < 4; ++n)
                    acc[m][n] = __builtin_amdgcn_mfma_f32_16x16x32_bf16(ah[m], bh[n], acc[m][n], 0, 0, 0);
        }
        __syncthreads();
    }

    // epilogue: C/D layout col(t)=lane&15, row(e)=(lane>>4)*4+reg
    float tau = tau0[b] - TAUM_;
    float zs = 0.f;
    int erow0 = e0 + wr * 64 + (lane >> 4) * 4;
#pragma unroll
    for (int m = 0; m < 4; ++m)
#pragma unroll
        for (int r = 0; r < 4; ++r) {
            int e = erow0 + m * 16 + r;
            float mbe = mb[e];
#pragma unroll
            for (int n = 0; n < 4; ++n) {
                int t = t0 + wc * 64 + n * 16 + a15;
                float v = acc[m][n][r] + mbe;
                zs += __expf(v);
                if (v >= tau) {
                    int pos = atomicAdd(&scnt, 1);       // LDS atomic (fast)
                    if (pos < BCAP_) {
                        sval[pos] = v;
                        sidx[pos] = e * T_ + t;
                    } else {                             // rare overflow spill
                        int q2 = atomicAdd(&ovc[b], 1);
                        if (q2 < OCAP_) {
                            ovv[b * OCAP_ + q2] = v;
                            ovi[b * OCAP_ + q2] = e * T_ + t;
                        }
                    }
                }
            }
        }
#pragma unroll
    for (int off = 32; off; off >>= 1) zs += __shfl_xor(zs, off, 64);
    if (lane == 0) red[w] = zs;
    __syncthreads();
    // flush: plain stores only
    int nc = scnt < BCAP_ ? scnt : BCAP_;
    for (int j = tid; j < nc; j += 256) {
        cvalB[(size_t)f * BCAP_ + j] = sval[j];
        cidxB[(size_t)f * BCAP_ + j] = sidx[j];
    }
    if (tid == 0) {
        cntB[f] = nc;
        zpart[f] = (red[0] + red[1]) + (red[2] + red[3]);
    }
}

// recompute exact m (f32, split pairs) for every collected candidate
__launch_bounds__(256)
__global__ void k_exact(const ushort* __restrict__ mwh, const ushort* __restrict__ mwl,
                        const ushort* __restrict__ xh, const ushort* __restrict__ xl,
                        const float* __restrict__ mb, const int* __restrict__ cntB,
                        const int* __restrict__ cidxB, float* __restrict__ cvalB,
                        const int* __restrict__ ovc, const int* __restrict__ ovi,
                        float* __restrict__ ovv) {
    int f = blockIdx.x;
    int wv = threadIdx.x >> 6, lane = threadIdx.x & 63;
    int cc = lane >> 4, cb = (lane >> 1) & 7, half = lane & 1;
    int n, b;
    const int* ip;
    float* vp;
    if (f < NBLK_) {
        b = f & 7;
        n = cntB[f]; if (n > BCAP_) n = BCAP_;
        ip = cidxB + (size_t)f * BCAP_;
        vp = cvalB + (size_t)f * BCAP_;
    } else {
        b = f - NBLK_;
        n = ovc[b]; if (n > OCAP_) n = OCAP_;
        ip = ovi + (size_t)b * OCAP_;
        vp = ovv + (size_t)b * OCAP_;
    }
    for (int j = wv; j < n; j += 4) {
        int idx = ip[j];
        int e = idx >> 13, t = idx & (T_ - 1);
        size_t xro = ((((size_t)b * 128 + (t >> 6)) * 4 + cc) * 8 + cb) * 512
                   + (size_t)(t & 63) * 8 + half * 4;
        size_t wro = (((size_t)(e >> 6) * 4 + cc) * 8 + cb) * 512
                   + (size_t)(e & 63) * 8 + half * 4;
        ushort4 hx = *(const ushort4*)(xh + xro);
        ushort4 lx = *(const ushort4*)(xl + xro);
        ushort4 hw = *(const ushort4*)(mwh + wro);
        ushort4 lw = *(const ushort4*)(mwl + wro);
        float a = (bf2f(hw.x) + bf2f(lw.x)) * (bf2f(hx.x) + bf2f(lx.x))
                + (bf2f(hw.y) + bf2f(lw.y)) * (bf2f(hx.y) + bf2f(lx.y))
                + (bf2f(hw.z) + bf2f(lw.z)) * (bf2f(hx.z) + bf2f(lx.z))
                + (bf2f(hw.w) + bf2f(lw.w)) * (bf2f(hx.w) + bf2f(lx.w));
#pragma unroll
        for (int off = 32; off; off >>= 1) a += __shfl_xor(a, off, 64);
        if (lane == 0) vp[j] = a + mb[e];
    }
}

// fused compact + exact top-K selection (one block per batch).
__launch_bounds__(256)
__global__ void k_selectc(const float* __restrict__ zpart, const int* __restrict__ cntB,
                          const float* __restrict__ cvalB, const int* __restrict__ cidxB,
                          const int* __restrict__ ovc, const float* __restrict__ ovv,
                          const int* __restrict__ ovi, float* __restrict__ cval,
                          int* __restrict__ cidx, int* __restrict__ sel_e,
                          int* __restrict__ sel_t, float* __restrict__ sel_sp) {
    __shared__ int pre[256];
    __shared__ float zsh[256];
    __shared__ int h[NB2_];
    __shared__ int part[256];
    __shared__ float bl_v[1024];
    __shared__ int bl_i[1024];
    __shared__ int nb, bstar, nabove, outcnt, ntot;
    int b = blockIdx.x, tid = threadIdx.x;
    // ---- compact + histogram phase ----
    int f = b + 8 * tid;                     // region id (b == f&7 decode)
    int c = cntB[f];
    pre[tid] = c;
    zsh[tid] = zpart[f];
    for (int i = tid; i < NB2_; i += 256) h[i] = 0;
    if (tid == 0) { nb = 0; outcnt = 0; bstar = 0; nabove = 0; }
    __syncthreads();
    for (int d = 1; d < 256; d <<= 1) {      // inclusive prefix scan
        int v = (tid >= d) ? pre[tid - d] : 0;
        __syncthreads();
        pre[tid] += v;
        __syncthreads();
    }
    int start = pre[tid] - c;
    int total = pre[255];
    for (int j = 0; j < c; ++j) {
        int d = start + j;
        if (d < CAP_) {
            float v = cvalB[(size_t)f * BCAP_ + j];
            cval[b * CAP_ + d] = v;
            cidx[b * CAP_ + d] = cidxB[(size_t)f * BCAP_ + j];
            int bin = (int)(v * ((float)NB2_ * 2.0f));
            bin = bin < 0 ? 0 : (bin > NB2_ - 1 ? NB2_ - 1 : bin);
            atomicAdd(&h[bin], 1);
        }
    }
    __syncthreads();
    for (int d = 128; d; d >>= 1) {          // Z reduction
        if (tid < d) zsh[tid] += zsh[tid + d];
        __syncthreads();
    }
    int no = ovc[b]; if (no > OCAP_) no = OCAP_;
    for (int j = tid; j < no; j += 256) {
        int d = total + j;
        if (d < CAP_) {
            float v = ovv[b * OCAP_ + j];
            cval[b * CAP_ + d] = v;
            cidx[b * CAP_ + d] = ovi[b * OCAP_ + j];
            int bin = (int)(v * ((float)NB2_ * 2.0f));
            bin = bin < 0 ? 0 : (bin > NB2_ - 1 ? NB2_ - 1 : bin);
            atomicAdd(&h[bin], 1);
        }
    }
    if (tid == 0) {
        int tot = total + no;
        ntot = tot < CAP_ ? tot : CAP_;
    }
    __syncthreads();
    // ---- boundary-bin search: suffix scan over 16-bin group sums ----
    int ps = 0;
#pragma unroll
    for (int j = 0; j < 16; ++j) ps += h[tid * 16 + j];
    part[tid] = ps;
    __syncthreads();
    for (int d = 1; d < 256; d <<= 1) {      // inclusive suffix scan
        int v = (tid + d < 256) ? part[tid + d] : 0;
        __syncthreads();
        part[tid] += v;
        __syncthreads();
    }
    if (part[tid] >= K_ && (tid == 255 || part[tid + 1] < K_)) {
        int cum2 = (tid == 255) ? 0 : part[tid + 1];
        for (int j = 15; j >= 0; --j) {
            cum2 += h[tid * 16 + j];
            if (cum2 >= K_) { bstar = tid * 16 + j; nabove = cum2 - h[tid * 16 + j]; break; }
        }
    }
    __syncthreads();
    // ---- combined pass: write >bs outputs, collect boundary bin ----
    int n = ntot;
    int bs = bstar;
    float rZ = 1.0f / zsh[0];
    const float* vp = cval + b * CAP_;
    const int* ip = cidx + b * CAP_;
    for (int j = tid; j < n; j += 256) {
        float v = vp[j];
        int bin = (int)(v * ((float)NB2_ * 2.0f));
        bin = bin < 0 ? 0 : (bin > NB2_ - 1 ? NB2_ - 1 : bin);
        if (bin > bs) {
            int q = atomicAdd(&outcnt, 1);
            int idx = ip[j];
            sel_e[b * K_ + q] = idx / T_;
            sel_t[b * K_ + q] = idx % T_;
            sel_sp[b * K_ + q] = __expf(v) * rZ;
        } else if (bin == bs) {
            int q = atomicAdd(&nb, 1);
            if (q < 1024) { bl_v[q] = v; bl_i[q] = ip[j]; }
        }
    }
    __syncthreads();
    // ---- parallel rank selection within the boundary bin ----
    int m = nb; if (m > 1024) m = 1024;
    int need = K_ - nabove;
    for (int j = tid; j < m; j += 256) {
        float v = bl_v[j]; int id = bl_i[j];
        int r = 0;
        for (int i = 0; i < m; ++i) {
            float vi = bl_v[i]; int ii = bl_i[i];
            r += (vi > v || (vi == v && ii < id)) ? 1 : 0;
        }
        if (r < need) {
            int slot = nabove + r;
            sel_e[b * K_ + slot] = id / T_;
            sel_t[b * K_ + slot] = id % T_;
            sel_sp[b * K_ + slot] = __expf(v) * rZ;
        }
    }
    // pathological fallback: fewer boundary items than needed -> zero entries
    for (int q = m + tid; q < need; q += 256) {
        int slot = nabove + q;
        sel_e[b * K_ + slot] = 0; sel_t[b * K_ + slot] = 0;
        sel_sp[b * K_ + slot] = 0.f;
    }
}

// up at selected positions via tiled split-x
__global__ void k_upg2(const ushort* __restrict__ xh, const ushort* __restrict__ xl,
                       const float* __restrict__ nrm, const float* __restrict__ uw,
                       const float* __restrict__ ub, const int* __restrict__ sel_e,
                       const int* __restrict__ sel_t, const float* __restrict__ sel_sp,
                       float* __restrict__ gval) {
    int gid = blockIdx.x * 256 + threadIdx.x;   // B*K waves
    int w = gid >> 6, lane = gid & 63;
    int b = w >> 9, i = w & (K_ - 1);
    int e = sel_e[b * K_ + i], t = sel_t[b * K_ + i];
    int ttile = t >> 6, trow = t & 63;
    int cc = lane >> 4, cb = (lane >> 1) & 7, half = lane & 1;
    size_t ro = ((((size_t)b * 128 + ttile) * 4 + cc) * 8 + cb) * 512
              + (size_t)trow * 8 + half * 4;          // c = lane*4 .. +4
    ushort4 h = *(const ushort4*)(xh + ro);
    ushort4 l = *(const ushort4*)(xl + ro);
    float4 wv = *(const float4*)(uw + (size_t)e * C_ + lane * 4);
    float acc = (bf2f(h.x) + bf2f(l.x)) * wv.x + (bf2f(h.y) + bf2f(l.y)) * wv.y
              + (bf2f(h.z) + bf2f(l.z)) * wv.z + (bf2f(h.w) + bf2f(l.w)) * wv.w;
#pragma unroll
    for (int off = 32; off; off >>= 1) acc += __shfl_down(acc, off, 64);
    if (lane == 0)
        gval[b * K_ + i] = sel_sp[b * K_ + i] * (acc * nrm[b * T_ + t] + ub[e]);
}

// fused base/S1/Q + BN stats: one block per channel c, 8 batches inside
__launch_bounds__(256)
__global__ void k_bsqbn(const float* __restrict__ sw, const float* __restrict__ sb,
                        const float* __restrict__ db, const float* __restrict__ dw,
                        const int* __restrict__ sel_e, const float* __restrict__ gval,
                        const float* __restrict__ bnw, const float* __restrict__ bnb,
                        float* __restrict__ scalec, float* __restrict__ obase) {
    __shared__ float barr[8], s1arr[8], qarr[8];
    int c = blockIdx.x;
    int w = threadIdx.x >> 6, lane = threadIdx.x & 63;
#pragma unroll
    for (int rep = 0; rep < 2; ++rep) {
        int b = w + rep * 4;
        float p = 0.f, s = 0.f, q = 0.f;
        for (int i = lane; i < K_; i += 64) {
            int e = sel_e[b * K_ + i];
            float g = gval[b * K_ + i];
            p += g * sw[(size_t)c * E_ + e];
            float wv = dw[(size_t)c * E_ + e] * g;
            s += wv; q += wv * wv;
        }
#pragma unroll
        for (int off = 32; off; off >>= 1) {
            p += __shfl_xor(p, off, 64);
            s += __shfl_xor(s, off, 64);
            q += __shfl_xor(q, off, 64);
        }
        if (lane == 0) {
            barr[b] = p + sb[c] + db[c];
            s1arr[b] = s; qarr[b] = q;
        }
    }
    __syncthreads();
    if (threadIdx.x == 0) {
        float msum = 0.f;
        for (int b = 0; b < B_; ++b) msum += (float)T_ * barr[b] + s1arr[b];
        float mean = msum / (float)(B_ * T_);
        float vs = 0.f;
        for (int b = 0; b < B_; ++b) {
            float d = barr[b] - mean;
            vs += (float)T_ * d * d + 2.0f * d * s1arr[b] + qarr[b];
        }
        float var = vs / (float)(B_ * T_);
        float sc = bnw[c] * rsqrtf(var + 1e-5f);
        scalec[c] = sc;
        for (int b = 0; b < B_; ++b)
            obase[b * C_ + c] = (barr[b] - mean) * sc + bnb[c];
    }
}

// spike slot assignment: one slot per distinct (b,t); duplicates share winner
__global__ void k_spk1(const int* __restrict__ sel_t, int* __restrict__ map,
                       int* __restrict__ pri) {
    int gid = blockIdx.x * 256 + threadIdx.x;   // B*K threads
    int b = gid >> 9;
    int t = sel_t[gid];
    int old = atomicCAS(&map[b * T_ + t], -1, gid & (K_ - 1));
    pri[gid] = (old == -1) ? (gid & (K_ - 1)) : old;
}

// spike accumulation into compact L2-resident spk[b][slot][c]
__global__ void k_spk2(const float* __restrict__ dw, const float* __restrict__ scalec,
                       const int* __restrict__ sel_e, const int* __restrict__ pri,
                       const float* __restrict__ gval, float* __restrict__ spk) {
    int gid = blockIdx.x * 256 + threadIdx.x;   // B*K*64 threads
    int s = gid >> 6, cq = (gid & 63) * 4;
    int b = s >> 9;
    int e = sel_e[s];
    float g = gval[s];
    int p = pri[s];
    float* dst = spk + ((size_t)(b * K_ + p)) * C_ + cq;
#pragma unroll
    for (int q = 0; q < 4; ++q) {
        int c = cq + q;
        atomicAdd(dst + q, scalec[c] * dw[(size_t)c * E_ + e] * g);
    }
}

// fill output: column-constant base + spike columns from compact spk
__global__ void k_fill2(const float* __restrict__ obase, const int* __restrict__ map,
                        const float* __restrict__ spk, float* __restrict__ out) {
    size_t gid = (size_t)blockIdx.x * 256 + threadIdx.x;
    size_t flat = gid * 4;
    int b = (int)(flat / CT_);
    int c = (int)(flat / T_) & (C_ - 1);
    int t0 = (int)(flat & (T_ - 1));
    float v = obase[b * C_ + c];
    float4 o = {v, v, v, v};
    int4 mp = *(const int4*)(map + b * T_ + t0);
    if (mp.x >= 0) o.x += spk[((size_t)(b * K_ + mp.x)) * C_ + c];
    if (mp.y >= 0) o.y += spk[((size_t)(b * K_ + mp.y)) * C_ + c];
    if (mp.z >= 0) o.z += spk[((size_t)(b * K_ + mp.z)) * C_ + c];
    if (mp.w >= 0) o.w += spk[((size_t)(b * K_ + mp.w)) * C_ + c];
    *(float4*)(out + flat) = o;
}

extern "C" void kernel_launch(void* const* d_in, const int* in_sizes, int n_in,
                              void* d_out, int out_size, void* d_ws, size_t ws_size,
                              hipStream_t stream) {
    const float* x = (const float*)d_in[0];
    const float* up_w = (const float*)d_in[1];
    const float* up_b = (const float*)d_in[2];
    const float* mask_w = (const float*)d_in[3];
    const float* mask_b = (const float*)d_in[4];
    const float* sum_w = (const float*)d_in[5];
    const float* sum_b = (const float*)d_in[6];
    const float* down_w = (const float*)d_in[7];
    const float* down_b = (const float*)d_in[8];
    const float* bn_w = (const float*)d_in[9];
    const float* bn_b = (const float*)d_in[10];
    float* out = (float*)d_out;

    // workspace layout (float units)
    float* ws = (float*)d_ws;
    size_t o = 0;
    float* rn = ws + o;   o += (size_t)B_ * T_;
    float* nrm = ws + o;  o += (size_t)B_ * T_;
    float* xs = ws + o;   o += (size_t)B_ * C_ * SCOLS_;
    float* msub = ws + o; o += (size_t)B_ * SUBN_;
    float* tau0 = ws + o; o += B_;
    int* gh = (int*)(ws + o);    o += (size_t)B_ * NB1_;
    float* cval = ws + o; o += (size_t)B_ * CAP_;
    int* cidx = (int*)(ws + o);  o += (size_t)B_ * CAP_;
    int* sel_e = (int*)(ws + o); o += (size_t)B_ * K_;
    int* sel_t = (int*)(ws + o); o += (size_t)B_ * K_;
    float* sel_sp = ws + o; o += (size_t)B_ * K_;
    float* gval = ws + o;   o += (size_t)B_ * K_;
    float* scalec = ws + o; o += C_;
    float* obase = ws + o;  o += (size_t)B_ * C_ + 8;
    // no-atomic collection buffers
    float* zpart = ws + o;  o += NBLK_;
    int* cntB = (int*)(ws + o); o += NBLK_;
    float* cvalB = ws + o;  o += (size_t)NBLK_ * BCAP_;
    int* cidxB = (int*)(ws + o); o += (size_t)NBLK_ * BCAP_;
    int* ovc = (int*)(ws + o); o += B_;
    float* ovv = ws + o;    o += (size_t)B_ * OCAP_;
    int* ovi = (int*)(ws + o); o += (size_t)B_ * OCAP_;
    // spike buffers
    int* map = (int*)(ws + o);  o += (size_t)B_ * T_;
    int* pri = (int*)(ws + o);  o += (size_t)B_ * K_;
    float* spk = ws + o;        o += (size_t)B_ * K_ * C_;
    // big split buffers last
    ushort* mwh = (ushort*)(ws + o); o += (size_t)E_ * C_ / 2;
    ushort* mwl = (ushort*)(ws + o); o += (size_t)E_ * C_ / 2;
    ushort* xh = (ushort*)(ws + o);  o += (size_t)B_ * T_ * C_ / 2;
    ushort* xl = (ushort*)(ws + o);  o += (size_t)B_ * T_ * C_ / 2;
    (void)ws_size;

    k_rn<<<(B_ * T_) / 64, 256, 0, stream>>>(x, rn, nrm, ovc, map, spk);
    k_gather<<<(B_ * C_ * SCOLS_) / 256, 256, 0, stream>>>(x, rn, xs, gh);
    k_msub2<<<dim3(SCOLS_ / 64, E_ / 64, B_), 256, 0, stream>>>(xs, mask_w, mask_b, msub);
    k_tau_hist<<<B_ * TAUP_, 256, 0, stream>>>(msub, gh);
    k_tau2<<<B_, 256, 0, stream>>>(gh, tau0);
    k_split_w<<<(E_ * C_ / 8) / 256, 256, 0, stream>>>(mask_w, mwh, mwl);
    k_split_x<<<dim3(T_ / 64, C_ / 64, B_), 256, 0, stream>>>(x, rn, xh, xl);
    k_gemm128<<<NBLK_, 256, 0, stream>>>(mwh, xh, mask_b, tau0,
                                         zpart, cntB, cvalB, cidxB,
                                         ovc, ovv, ovi);
    k_exact<<<NBLK_ + B_, 256, 0, stream>>>(mwh, mwl, xh, xl, mask_b,
                                            cntB, cidxB, cvalB, ovc, ovi, ovv);
    k_selectc<<<B_, 256, 0, stream>>>(zpart, cntB, cvalB, cidxB,
                                      ovc, ovv, ovi, cval, cidx,
                                      sel_e, sel_t, sel_sp);
    k_spk1<<<(B_ * K_) / 256, 256, 0, stream>>>(sel_t, map, pri);
    k_upg2<<<(B_ * K_ * 64) / 256, 256, 0, stream>>>(xh, xl, nrm, up_w, up_b,
                                                     sel_e, sel_t, sel_sp, gval);
    k_bsqbn<<<C_, 256, 0, stream>>>(sum_w, sum_b, down_b, down_w, sel_e, gval,
                                    bn_w, bn_b, scalec, obase);
    k_spk2<<<(B_ * K_ * 64) / 256, 256, 0, stream>>>(down_w, scalec, sel_e, pri,
                                                     gval, spk);
    k_fill2<<<(B_ * CT_ / 4) / 256, 256, 0, stream>>>(obase, map, spk, out);
}

// Round 16
// 212.166 us; speedup vs baseline: 1.3065x; 1.1016x over previous
//
#include <hip/hip_runtime.h>
#include <hip/hip_bf16.h>

// Problem constants (fixed by the reference)
#define B_ 8
#define C_ 256
#define E_ 512
#define T_ 8192
#define K_ 512
#define CT_ (C_*T_)
#define BCAP_ 512           // per-block LDS candidate capacity
#define OCAP_ 1024          // per-batch overflow capacity
#define NBLK_ 2048          // k_gemm128 grid
#define SUBS_ 64            // t-subsample stride
#define SCOLS_ (T_/SUBS_)   // 128
#define SUBN_ (E_*SCOLS_)   // 65536 subsample points per batch
#define RANK_ 64            // subsample rank -> expected full count ~4096
#define NB1_ 4096           // subsample histogram bins over [-1,1)
#define NB2_ 4096           // selection histogram bins over [0,0.5)
#define TAUP_ 8             // histogram partial blocks per batch
#define TAUM_ 0.004f        // bf16-m error margin (~40 sigma) for collection

typedef __attribute__((ext_vector_type(8))) short bf16x8;
typedef __attribute__((ext_vector_type(4))) float f32x4;

__device__ __forceinline__ ushort f2bf(float f) {
    __hip_bfloat16 h = __float2bfloat16(f);
    return *reinterpret_cast<ushort*>(&h);
}
__device__ __forceinline__ float bf2f(ushort u) {
    __hip_bfloat16 h = *reinterpret_cast<__hip_bfloat16*>(&u);
    return __bfloat162float(h);
}

// async global->LDS, 16B per lane; LDS dest = wave-uniform base + lane*16
__device__ __forceinline__ void gl16(const void* g, void* l) {
    __builtin_amdgcn_global_load_lds(
        (const __attribute__((address_space(1))) void*)g,
        (__attribute__((address_space(3))) void*)l, 16, 0, 0);
}

// Tiled operand layout (ushort units):
//   W tiles:  [etile(8)][cc(4)][cb(8)][erow(64)][8]   (16384 per etile)
//   X tiles:  [b*128+ttile][cc(4)][cb(8)][trow(64)][8] (16384 per ttile)

// rn/nrm, 4x wave-parallel over channels; also inits ovc/map/spk
// grid: B*T/64 = 1024 blocks x 256 threads
__launch_bounds__(256)
__global__ void k_rn(const float* __restrict__ x, float* __restrict__ rn,
                     float* __restrict__ nrm, int* __restrict__ ovc,
                     int* __restrict__ map, float* __restrict__ spk) {
    __shared__ float partial[4][64];
    int tid = threadIdx.x, lane = tid & 63, w = tid >> 6;
    int bid = blockIdx.x;
    int gid = bid * 256 + tid;                  // 0 .. 262143
    if (gid < B_) ovc[gid] = 0;
    if (gid < B_ * T_) map[gid] = -1;
    ((float4*)spk)[gid] = (float4){0.f, 0.f, 0.f, 0.f};  // B*K*C/4 = 262144
    int b = bid >> 7;
    int t = (bid & 127) * 64 + lane;
    const float* xp = x + (size_t)b * CT_ + (size_t)(w * 64) * T_ + t;
    float s0 = 0.f, s1 = 0.f, s2 = 0.f, s3 = 0.f;
#pragma unroll 4
    for (int c = 0; c < 64; c += 4) {
        float a0 = xp[(size_t)c * T_];
        float a1 = xp[(size_t)(c + 1) * T_];
        float a2 = xp[(size_t)(c + 2) * T_];
        float a3 = xp[(size_t)(c + 3) * T_];
        s0 += a0 * a0; s1 += a1 * a1; s2 += a2 * a2; s3 += a3 * a3;
    }
    partial[w][lane] = (s0 + s1) + (s2 + s3);
    __syncthreads();
    if (w == 0) {
        float s = (partial[0][lane] + partial[1][lane])
                + (partial[2][lane] + partial[3][lane]);
        float n = sqrtf(s) + 1e-8f;
        nrm[b * T_ + t] = n;
        rn[b * T_ + t] = 1.0f / n;
    }
}

// split mask_w into bf16 hi/lo, TILED layout (coalesced 16B writes)
__global__ void k_split_w(const float* __restrict__ mw, ushort* __restrict__ mwh,
                          ushort* __restrict__ mwl) {
    int idx = blockIdx.x * 256 + threadIdx.x;   // E*C/8 = 16384 threads
    int erow = idx & 63;
    int cb = (idx >> 6) & 7;
    int cc = (idx >> 9) & 3;
    int etile = idx >> 11;
    int e = etile * 64 + erow;
    int c0 = cc * 64 + cb * 8;
    const float* src = mw + (size_t)e * C_ + c0;
    ushort4 h0, l0, h1, l1;
    float v;
    v = src[0]; h0.x = f2bf(v); l0.x = f2bf(v - bf2f(h0.x));
    v = src[1]; h0.y = f2bf(v); l0.y = f2bf(v - bf2f(h0.y));
    v = src[2]; h0.z = f2bf(v); l0.z = f2bf(v - bf2f(h0.z));
    v = src[3]; h0.w = f2bf(v); l0.w = f2bf(v - bf2f(h0.w));
    v = src[4]; h1.x = f2bf(v); l1.x = f2bf(v - bf2f(h1.x));
    v = src[5]; h1.y = f2bf(v); l1.y = f2bf(v - bf2f(h1.y));
    v = src[6]; h1.z = f2bf(v); l1.z = f2bf(v - bf2f(h1.z));
    v = src[7]; h1.w = f2bf(v); l1.w = f2bf(v - bf2f(h1.w));
    *(ushort4*)(mwh + (size_t)idx * 8) = h0;
    *(ushort4*)(mwh + (size_t)idx * 8 + 4) = h1;
    *(ushort4*)(mwl + (size_t)idx * 8) = l0;
    *(ushort4*)(mwl + (size_t)idx * 8 + 4) = l1;
}

// transpose + rn-scale + split into TILED layout
__launch_bounds__(256)
__global__ void k_split_x(const float* __restrict__ x, const float* __restrict__ rn,
                          ushort* __restrict__ xh, ushort* __restrict__ xl) {
    __shared__ float tile[64][76];
    __shared__ float rnv[64];
    int tid = threadIdx.x;
    int ttile = blockIdx.x, cc = blockIdx.y, b = blockIdx.z;
    int t0 = ttile * 64, c0 = cc * 64;
    if (tid < 64) rnv[tid] = rn[b * T_ + t0 + tid];
    const float* xb = x + (size_t)b * CT_;
#pragma unroll
    for (int q = 0; q < 4; ++q) {
        int idx = tid + q * 256;
        int cr = idx >> 4, t4 = (idx & 15) * 4;
        float4 v = *(const float4*)(xb + (size_t)(c0 + cr) * T_ + t0 + t4);
        *(float4*)&tile[cr][t4] = v;
    }
    __syncthreads();
    size_t obase = (((size_t)b * 128 + ttile) * 4 + cc) * 4096;
#pragma unroll
    for (int q = 0; q < 4; ++q) {
        int idx = tid + q * 256;
        int tr = idx >> 4, c4 = (idx & 15) * 4;
        float s = rnv[tr];
        float v0 = tile[c4 + 0][tr] * s;
        float v1 = tile[c4 + 1][tr] * s;
        float v2 = tile[c4 + 2][tr] * s;
        float v3 = tile[c4 + 3][tr] * s;
        ushort4 h, l;
        h.x = f2bf(v0); l.x = f2bf(v0 - bf2f(h.x));
        h.y = f2bf(v1); l.y = f2bf(v1 - bf2f(h.y));
        h.z = f2bf(v2); l.z = f2bf(v2 - bf2f(h.z));
        h.w = f2bf(v3); l.w = f2bf(v3 - bf2f(h.w));
        int cb = c4 >> 3, half = (c4 >> 2) & 1;
        size_t ro = obase + (size_t)cb * 512 + tr * 8 + half * 4;
        *(ushort4*)(xh + ro) = h;
        *(ushort4*)(xl + ro) = l;
    }
}

// gather subsampled, rn-scaled x; first 32K threads also zero gh
__global__ void k_gather(const float* __restrict__ x, const float* __restrict__ rn,
                         float* __restrict__ xs, int* __restrict__ gh) {
    int gid = blockIdx.x * 256 + threadIdx.x;   // B*C*SCOLS threads = 262144
    if (gid < B_ * NB1_) gh[gid] = 0;
    int s = gid & (SCOLS_ - 1);
    int c = (gid >> 7) & (C_ - 1);
    int b = gid >> 15;
    int t = s * SUBS_;
    xs[gid] = x[(size_t)b * CT_ + (size_t)c * T_ + t] * rn[b * T_ + t];
}

// tiled f32 GEMM on compact gathered buffer (small: ~270 MFLOP)
__launch_bounds__(256)
__global__ void k_msub2(const float* __restrict__ xs, const float* __restrict__ mw,
                        const float* __restrict__ mb, float* __restrict__ msub) {
    __shared__ float As[64][68];
    __shared__ float Bs[64][68];
    int tid = threadIdx.x;
    int tx = tid & 15, ty = tid >> 4;
    int s0 = blockIdx.x * 64, e0 = blockIdx.y * 64, b = blockIdx.z;
    const float* xb = xs + (size_t)b * C_ * SCOLS_;
    float acc[4][4] = {};
    for (int c0 = 0; c0 < C_; c0 += 64) {
#pragma unroll
        for (int r = 0; r < 4; ++r) {
            int i = (tid >> 4) + r * 16;
            int kq = (tid & 15) * 4;
            float4 av = *(const float4*)(mw + (size_t)(e0 + i) * C_ + c0 + kq);
            As[kq + 0][i] = av.x; As[kq + 1][i] = av.y;
            As[kq + 2][i] = av.z; As[kq + 3][i] = av.w;
        }
#pragma unroll
        for (int r = 0; r < 4; ++r) {
            int k = (tid >> 4) + r * 16;
            int jq = (tid & 15) * 4;
            *(float4*)(&Bs[k][jq]) =
                *(const float4*)(xb + (size_t)(c0 + k) * SCOLS_ + s0 + jq);
        }
        __syncthreads();
#pragma unroll
        for (int k = 0; k < 64; ++k) {
            float4 a = *(const float4*)(&As[k][ty * 4]);
            float4 bq = *(const float4*)(&Bs[k][tx * 4]);
            float av[4] = {a.x, a.y, a.z, a.w};
            float bv[4] = {bq.x, bq.y, bq.z, bq.w};
#pragma unroll
            for (int ii = 0; ii < 4; ++ii)
#pragma unroll
                for (int jj = 0; jj < 4; ++jj)
                    acc[ii][jj] += av[ii] * bv[jj];
        }
        __syncthreads();
    }
#pragma unroll
    for (int ii = 0; ii < 4; ++ii) {
        float mbv = mb[e0 + ty * 4 + ii];
#pragma unroll
        for (int jj = 0; jj < 4; ++jj) {
            int e = e0 + ty * 4 + ii, s = s0 + tx * 4 + jj;
            msub[(size_t)b * SUBN_ + e * SCOLS_ + s] = acc[ii][jj] + mbv;
        }
    }
}

// parallel histogram of msub: 64 blocks (8 per batch) -> global gh[b][NB1]
__launch_bounds__(256)
__global__ void k_tau_hist(const float* __restrict__ msub, int* __restrict__ gh) {
    __shared__ int h[NB1_];
    int tid = threadIdx.x;
    int b = blockIdx.x >> 3, part = blockIdx.x & (TAUP_ - 1);
    for (int i = tid; i < NB1_; i += 256) h[i] = 0;
    __syncthreads();
    const float* mp = msub + (size_t)b * SUBN_ + part * (SUBN_ / TAUP_);
    for (int j = tid; j < SUBN_ / TAUP_; j += 256) {
        float v = mp[j];
        int bin = (int)((v + 1.0f) * ((float)NB1_ * 0.5f));
        bin = bin < 0 ? 0 : (bin > NB1_ - 1 ? NB1_ - 1 : bin);
        atomicAdd(&h[bin], 1);
    }
    __syncthreads();
    int* ghb = gh + b * NB1_;
    for (int i = tid; i < NB1_; i += 256)
        if (h[i]) atomicAdd(&ghb[i], h[i]);   // fire-and-forget, low contention
}

// per-batch conservative threshold tau0 from global histogram rank-64
__global__ void k_tau2(const int* __restrict__ gh, float* __restrict__ tau0) {
    __shared__ int part[256];
    int b = blockIdx.x, tid = threadIdx.x;
    const int* h = gh + b * NB1_;
    int ps = 0;
    for (int j = 0; j < 16; ++j) ps += h[tid * 16 + j];
    part[tid] = ps;
    __syncthreads();
    if (tid == 0) {
        int cum = 0, bf = 0;
        for (int i = 255; i >= 0; --i) {
            if (cum + part[i] >= RANK_) {
                int cum2 = cum;
                for (int j = 15; j >= 0; --j) {
                    cum2 += h[i * 16 + j];
                    if (cum2 >= RANK_) { bf = i * 16 + j; break; }
                }
                break;
            }
            cum += part[i];
        }
        tau0[b] = (float)bf * (2.0f / (float)NB1_) - 1.0f;  // bin lower edge
    }
}

// ---------------- fast main GEMM: plain bf16, half staging, 1/3 MFMA --------
__launch_bounds__(256)
__global__ void k_gemm128(const ushort* __restrict__ mwh, const ushort* __restrict__ xh,
                          const float* __restrict__ mb, const float* __restrict__ tau0,
                          float* __restrict__ zpart, int* __restrict__ cntB,
                          float* __restrict__ cvalB, int* __restrict__ cidxB,
                          int* __restrict__ ovc, float* __restrict__ ovv,
                          int* __restrict__ ovi) {
    __shared__ ushort S[4][4096];   // Wh0,Wh1,Xh0,Xh1 (8KB each)
    __shared__ float red[4];
    __shared__ float sval[BCAP_];
    __shared__ int sidx[BCAP_];
    __shared__ int scnt;
    int tid = threadIdx.x, lane = tid & 63, w = tid >> 6;
    int f = blockIdx.x;
    int xcd = f & 7, slot = f >> 3;          // XCD grouping: b == xcd
    int eblk = slot & 3, xt = slot >> 2;     // 4 e-blocks adjacent per x-tile
    int xtile = xcd * 64 + xt;               // 0..511 = b*64 + tt
    int b = xtile >> 6, tt = xtile & 63;
    int e0 = eblk * 128, t0 = tt * 128;
    if (tid == 0) scnt = 0;

    const ushort* base;
    if (w < 2) base = mwh + (size_t)(eblk * 2 + (w & 1)) * 16384;
    else       base = xh + ((size_t)b * 128 + tt * 2 + (w & 1)) * 16384;
    const ushort* gsrc = base + lane * 8;

    f32x4 acc[4][4];
#pragma unroll
    for (int m = 0; m < 4; ++m)
#pragma unroll
        for (int n = 0; n < 4; ++n)
            acc[m][n] = (f32x4){0.f, 0.f, 0.f, 0.f};

    int a15 = lane & 15;
    int khalf = lane >> 4;                   // 0..3
    int wr = w >> 1, wc = w & 1;             // wave's 64x64 quadrant

    for (int cc = 0; cc < 4; ++cc) {
#pragma unroll
        for (int i = 0; i < 8; ++i)
            gl16(gsrc + cc * 4096 + i * 512, &S[w][0] + i * 512);
        __syncthreads();
#pragma unroll
        for (int ks = 0; ks < 2; ++ks) {
            int cb16 = ks * 4 + khalf;
            bf16x8 ah[4], bh[4];
#pragma unroll
            for (int m = 0; m < 4; ++m) {
                int aoff = (cb16 * 64 + m * 16 + a15) * 16;
                ah[m] = *(const bf16x8*)((const char*)&S[wr][0] + aoff);
            }
#pragma unroll
            for (int n = 0; n < 4; ++n) {
                int boff = (cb16 * 64 + n * 16 + a15) * 16;
                bh[n] = *(const bf16x8*)((const char*)&S[2 + wc][0] + boff);
            }
#pragma unroll
            for (int m = 0; m < 4; ++m)
#pragma unroll
                for (int n = 0; n < 4; ++n)
                    acc[m][n] = __builtin_amdgcn_mfma_f32_16x16x32_bf16(ah[m], bh[n], acc[m][n], 0, 0, 0);
        }
        __syncthreads();
    }

    // epilogue: C/D layout col(t)=lane&15, row(e)=(lane>>4)*4+reg
    float tau = tau0[b] - TAUM_;
    float zs = 0.f;
    int erow0 = e0 + wr * 64 + (lane >> 4) * 4;
#pragma unroll
    for (int m = 0; m < 4; ++m)
#pragma unroll
        for (int r = 0; r < 4; ++r) {
            int e = erow0 + m * 16 + r;
            float mbe = mb[e];
#pragma unroll
            for (int n = 0; n < 4; ++n) {
                int t = t0 + wc * 64 + n * 16 + a15;
                float v = acc[m][n][r] + mbe;
                zs += __expf(v);
                if (v >= tau) {
                    int pos = atomicAdd(&scnt, 1);       // LDS atomic (fast)
                    if (pos < BCAP_) {
                        sval[pos] = v;
                        sidx[pos] = e * T_ + t;
                    } else {                             // rare overflow spill
                        int q2 = atomicAdd(&ovc[b], 1);
                        if (q2 < OCAP_) {
                            ovv[b * OCAP_ + q2] = v;
                            ovi[b * OCAP_ + q2] = e * T_ + t;
                        }
                    }
                }
            }
        }
#pragma unroll
    for (int off = 32; off; off >>= 1) zs += __shfl_xor(zs, off, 64);
    if (lane == 0) red[w] = zs;
    __syncthreads();
    // flush: plain stores only
    int nc = scnt < BCAP_ ? scnt : BCAP_;
    for (int j = tid; j < nc; j += 256) {
        cvalB[(size_t)f * BCAP_ + j] = sval[j];
        cidxB[(size_t)f * BCAP_ + j] = sidx[j];
    }
    if (tid == 0) {
        cntB[f] = nc;
        zpart[f] = (red[0] + red[1]) + (red[2] + red[3]);
    }
}

// recompute exact m (f32, split pairs) for every collected candidate
__launch_bounds__(256)
__global__ void k_exact(const ushort* __restrict__ mwh, const ushort* __restrict__ mwl,
                        const ushort* __restrict__ xh, const ushort* __restrict__ xl,
                        const float* __restrict__ mb, const int* __restrict__ cntB,
                        const int* __restrict__ cidxB, float* __restrict__ cvalB,
                        const int* __restrict__ ovc, const int* __restrict__ ovi,
                        float* __restrict__ ovv) {
    int f = blockIdx.x;
    int wv = threadIdx.x >> 6, lane = threadIdx.x & 63;
    int cc = lane >> 4, cb = (lane >> 1) & 7, half = lane & 1;
    int n, b;
    const int* ip;
    float* vp;
    if (f < NBLK_) {
        b = f & 7;
        n = cntB[f]; if (n > BCAP_) n = BCAP_;
        ip = cidxB + (size_t)f * BCAP_;
        vp = cvalB + (size_t)f * BCAP_;
    } else {
        b = f - NBLK_;
        n = ovc[b]; if (n > OCAP_) n = OCAP_;
        ip = ovi + (size_t)b * OCAP_;
        vp = ovv + (size_t)b * OCAP_;
    }
    for (int j = wv; j < n; j += 4) {
        int idx = ip[j];
        int e = idx >> 13, t = idx & (T_ - 1);
        size_t xro = ((((size_t)b * 128 + (t >> 6)) * 4 + cc) * 8 + cb) * 512
                   + (size_t)(t & 63) * 8 + half * 4;
        size_t wro = (((size_t)(e >> 6) * 4 + cc) * 8 + cb) * 512
                   + (size_t)(e & 63) * 8 + half * 4;
        ushort4 hx = *(const ushort4*)(xh + xro);
        ushort4 lx = *(const ushort4*)(xl + xro);
        ushort4 hw = *(const ushort4*)(mwh + wro);
        ushort4 lw = *(const ushort4*)(mwl + wro);
        float a = (bf2f(hw.x) + bf2f(lw.x)) * (bf2f(hx.x) + bf2f(lx.x))
                + (bf2f(hw.y) + bf2f(lw.y)) * (bf2f(hx.y) + bf2f(lx.y))
                + (bf2f(hw.z) + bf2f(lw.z)) * (bf2f(hx.z) + bf2f(lx.z))
                + (bf2f(hw.w) + bf2f(lw.w)) * (bf2f(hx.w) + bf2f(lx.w));
#pragma unroll
        for (int off = 32; off; off >>= 1) a += __shfl_xor(a, off, 64);
        if (lane == 0) vp[j] = a + mb[e];
    }
}

// top-K selection straight from per-block regions (no compaction).
// 1024 threads: 4 sub-threads per region; two L2-resident sweeps.
__launch_bounds__(1024)
__global__ void k_selectc(const float* __restrict__ zpart, const int* __restrict__ cntB,
                          const float* __restrict__ cvalB, const int* __restrict__ cidxB,
                          const int* __restrict__ ovc, const float* __restrict__ ovv,
                          const int* __restrict__ ovi, int* __restrict__ sel_e,
                          int* __restrict__ sel_t, float* __restrict__ sel_sp) {
    __shared__ float zsh[256];
    __shared__ int h[NB2_];
    __shared__ int part[256];
    __shared__ float bl_v[1024];
    __shared__ int bl_i[1024];
    __shared__ int nb, bstar, nabove, outcnt;
    int b = blockIdx.x, tid = threadIdx.x;
    int rid = tid & 255, sub = tid >> 8;     // 4 subthreads per region
    int f = b + 8 * rid;
    int c = cntB[f];                          // all 4 subs read same (cached)
    for (int i = tid; i < NB2_; i += 1024) h[i] = 0;
    if (tid < 256) zsh[tid] = zpart[b + 8 * tid];
    if (tid == 0) { nb = 0; outcnt = 0; bstar = 0; nabove = 0; }
    __syncthreads();
    // ---- pass 1: histogram from regions (+ overflow) ----
    const float* rv = cvalB + (size_t)f * BCAP_;
    for (int j = sub; j < c; j += 4) {
        float v = rv[j];
        int bin = (int)(v * ((float)NB2_ * 2.0f));
        bin = bin < 0 ? 0 : (bin > NB2_ - 1 ? NB2_ - 1 : bin);
        atomicAdd(&h[bin], 1);
    }
    int no = ovc[b]; if (no > OCAP_) no = OCAP_;
    for (int j = tid; j < no; j += 1024) {
        float v = ovv[b * OCAP_ + j];
        int bin = (int)(v * ((float)NB2_ * 2.0f));
        bin = bin < 0 ? 0 : (bin > NB2_ - 1 ? NB2_ - 1 : bin);
        atomicAdd(&h[bin], 1);
    }
    __syncthreads();
    // Z reduction (first 256 threads)
    for (int d = 128; d; d >>= 1) {
        if (tid < d) zsh[tid] += zsh[tid + d];
        __syncthreads();
    }
    // ---- boundary-bin search: suffix scan over 16-bin group sums ----
    if (tid < 256) {
        int ps = 0;
#pragma unroll
        for (int j = 0; j < 16; ++j) ps += h[tid * 16 + j];
        part[tid] = ps;
    }
    __syncthreads();
    for (int d = 1; d < 256; d <<= 1) {      // inclusive suffix scan
        int v = 0;
        if (tid < 256) v = (tid + d < 256) ? part[tid + d] : 0;
        __syncthreads();
        if (tid < 256) part[tid] += v;
        __syncthreads();
    }
    if (tid < 256 && part[tid] >= K_ && (tid == 255 || part[tid + 1] < K_)) {
        int cum2 = (tid == 255) ? 0 : part[tid + 1];
        for (int j = 15; j >= 0; --j) {
            cum2 += h[tid * 16 + j];
            if (cum2 >= K_) { bstar = tid * 16 + j; nabove = cum2 - h[tid * 16 + j]; break; }
        }
    }
    __syncthreads();
    // ---- pass 2: write >bs outputs, collect boundary bin ----
    int bs = bstar;
    float rZ = 1.0f / zsh[0];
    const int* ri = cidxB + (size_t)f * BCAP_;
    for (int j = sub; j < c; j += 4) {
        float v = rv[j];
        int bin = (int)(v * ((float)NB2_ * 2.0f));
        bin = bin < 0 ? 0 : (bin > NB2_ - 1 ? NB2_ - 1 : bin);
        if (bin > bs) {
            int q = atomicAdd(&outcnt, 1);
            int idx = ri[j];
            sel_e[b * K_ + q] = idx / T_;
            sel_t[b * K_ + q] = idx % T_;
            sel_sp[b * K_ + q] = __expf(v) * rZ;
        } else if (bin == bs) {
            int q = atomicAdd(&nb, 1);
            if (q < 1024) { bl_v[q] = v; bl_i[q] = ri[j]; }
        }
    }
    for (int j = tid; j < no; j += 1024) {
        float v = ovv[b * OCAP_ + j];
        int bin = (int)(v * ((float)NB2_ * 2.0f));
        bin = bin < 0 ? 0 : (bin > NB2_ - 1 ? NB2_ - 1 : bin);
        if (bin > bs) {
            int q = atomicAdd(&outcnt, 1);
            int idx = ovi[b * OCAP_ + j];
            sel_e[b * K_ + q] = idx / T_;
            sel_t[b * K_ + q] = idx % T_;
            sel_sp[b * K_ + q] = __expf(v) * rZ;
        } else if (bin == bs) {
            int q = atomicAdd(&nb, 1);
            if (q < 1024) { bl_v[q] = v; bl_i[q] = ovi[b * OCAP_ + j]; }
        }
    }
    __syncthreads();
    // ---- parallel rank selection within the boundary bin ----
    int m = nb; if (m > 1024) m = 1024;
    int need = K_ - nabove;
    for (int j = tid; j < m; j += 1024) {
        float v = bl_v[j]; int id = bl_i[j];
        int r = 0;
        for (int i = 0; i < m; ++i) {
            float vi = bl_v[i]; int ii = bl_i[i];
            r += (vi > v || (vi == v && ii < id)) ? 1 : 0;
        }
        if (r < need) {
            int slot = nabove + r;
            sel_e[b * K_ + slot] = id / T_;
            sel_t[b * K_ + slot] = id % T_;
            sel_sp[b * K_ + slot] = __expf(v) * rZ;
        }
    }
    // pathological fallback: fewer boundary items than needed -> zero entries
    for (int q = m + tid; q < need; q += 1024) {
        int slot = nabove + q;
        sel_e[b * K_ + slot] = 0; sel_t[b * K_ + slot] = 0;
        sel_sp[b * K_ + slot] = 0.f;
    }
}

// up at selected positions via tiled split-x
__global__ void k_upg2(const ushort* __restrict__ xh, const ushort* __restrict__ xl,
                       const float* __restrict__ nrm, const float* __restrict__ uw,
                       const float* __restrict__ ub, const int* __restrict__ sel_e,
                       const int* __restrict__ sel_t, const float* __restrict__ sel_sp,
                       float* __restrict__ gval) {
    int gid = blockIdx.x * 256 + threadIdx.x;   // B*K waves
    int w = gid >> 6, lane = gid & 63;
    int b = w >> 9, i = w & (K_ - 1);
    int e = sel_e[b * K_ + i], t = sel_t[b * K_ + i];
    int ttile = t >> 6, trow = t & 63;
    int cc = lane >> 4, cb = (lane >> 1) & 7, half = lane & 1;
    size_t ro = ((((size_t)b * 128 + ttile) * 4 + cc) * 8 + cb) * 512
              + (size_t)trow * 8 + half * 4;          // c = lane*4 .. +4
    ushort4 h = *(const ushort4*)(xh + ro);
    ushort4 l = *(const ushort4*)(xl + ro);
    float4 wv = *(const float4*)(uw + (size_t)e * C_ + lane * 4);
    float acc = (bf2f(h.x) + bf2f(l.x)) * wv.x + (bf2f(h.y) + bf2f(l.y)) * wv.y
              + (bf2f(h.z) + bf2f(l.z)) * wv.z + (bf2f(h.w) + bf2f(l.w)) * wv.w;
#pragma unroll
    for (int off = 32; off; off >>= 1) acc += __shfl_down(acc, off, 64);
    if (lane == 0)
        gval[b * K_ + i] = sel_sp[b * K_ + i] * (acc * nrm[b * T_ + t] + ub[e]);
}

// fused base/S1/Q + BN stats: one block per channel c, 8 batches inside
__launch_bounds__(256)
__global__ void k_bsqbn(const float* __restrict__ sw, const float* __restrict__ sb,
                        const float* __restrict__ db, const float* __restrict__ dw,
                        const int* __restrict__ sel_e, const float* __restrict__ gval,
                        const float* __restrict__ bnw, const float* __restrict__ bnb,
                        float* __restrict__ scalec, float* __restrict__ obase) {
    __shared__ float barr[8], s1arr[8], qarr[8];
    int c = blockIdx.x;
    int w = threadIdx.x >> 6, lane = threadIdx.x & 63;
#pragma unroll
    for (int rep = 0; rep < 2; ++rep) {
        int b = w + rep * 4;
        float p = 0.f, s = 0.f, q = 0.f;
        for (int i = lane; i < K_; i += 64) {
            int e = sel_e[b * K_ + i];
            float g = gval[b * K_ + i];
            p += g * sw[(size_t)c * E_ + e];
            float wv = dw[(size_t)c * E_ + e] * g;
            s += wv; q += wv * wv;
        }
#pragma unroll
        for (int off = 32; off; off >>= 1) {
            p += __shfl_xor(p, off, 64);
            s += __shfl_xor(s, off, 64);
            q += __shfl_xor(q, off, 64);
        }
        if (lane == 0) {
            barr[b] = p + sb[c] + db[c];
            s1arr[b] = s; qarr[b] = q;
        }
    }
    __syncthreads();
    if (threadIdx.x == 0) {
        float msum = 0.f;
        for (int b = 0; b < B_; ++b) msum += (float)T_ * barr[b] + s1arr[b];
        float mean = msum / (float)(B_ * T_);
        float vs = 0.f;
        for (int b = 0; b < B_; ++b) {
            float d = barr[b] - mean;
            vs += (float)T_ * d * d + 2.0f * d * s1arr[b] + qarr[b];
        }
        float var = vs / (float)(B_ * T_);
        float sc = bnw[c] * rsqrtf(var + 1e-5f);
        scalec[c] = sc;
        for (int b = 0; b < B_; ++b)
            obase[b * C_ + c] = (barr[b] - mean) * sc + bnb[c];
    }
}

// spike slot assignment: one slot per distinct (b,t); duplicates share winner
__global__ void k_spk1(const int* __restrict__ sel_t, int* __restrict__ map,
                       int* __restrict__ pri) {
    int gid = blockIdx.x * 256 + threadIdx.x;   // B*K threads
    int b = gid >> 9;
    int t = sel_t[gid];
    int old = atomicCAS(&map[b * T_ + t], -1, gid & (K_ - 1));
    pri[gid] = (old == -1) ? (gid & (K_ - 1)) : old;
}

// spike accumulation into compact L2-resident spk[b][slot][c]
__global__ void k_spk2(const float* __restrict__ dw, const float* __restrict__ scalec,
                       const int* __restrict__ sel_e, const int* __restrict__ pri,
                       const float* __restrict__ gval, float* __restrict__ spk) {
    int gid = blockIdx.x * 256 + threadIdx.x;   // B*K*64 threads
    int s = gid >> 6, cq = (gid & 63) * 4;
    int b = s >> 9;
    int e = sel_e[s];
    float g = gval[s];
    int p = pri[s];
    float* dst = spk + ((size_t)(b * K_ + p)) * C_ + cq;
#pragma unroll
    for (int q = 0; q < 4; ++q) {
        int c = cq + q;
        atomicAdd(dst + q, scalec[c] * dw[(size_t)c * E_ + e] * g);
    }
}

// fill output: column-constant base + spike columns from compact spk
__global__ void k_fill2(const float* __restrict__ obase, const int* __restrict__ map,
                        const float* __restrict__ spk, float* __restrict__ out) {
    size_t gid = (size_t)blockIdx.x * 256 + threadIdx.x;
    size_t flat = gid * 4;
    int b = (int)(flat / CT_);
    int c = (int)(flat / T_) & (C_ - 1);
    int t0 = (int)(flat & (T_ - 1));
    float v = obase[b * C_ + c];
    float4 o = {v, v, v, v};
    int4 mp = *(const int4*)(map + b * T_ + t0);
    if (mp.x >= 0) o.x += spk[((size_t)(b * K_ + mp.x)) * C_ + c];
    if (mp.y >= 0) o.y += spk[((size_t)(b * K_ + mp.y)) * C_ + c];
    if (mp.z >= 0) o.z += spk[((size_t)(b * K_ + mp.z)) * C_ + c];
    if (mp.w >= 0) o.w += spk[((size_t)(b * K_ + mp.w)) * C_ + c];
    *(float4*)(out + flat) = o;
}

extern "C" void kernel_launch(void* const* d_in, const int* in_sizes, int n_in,
                              void* d_out, int out_size, void* d_ws, size_t ws_size,
                              hipStream_t stream) {
    const float* x = (const float*)d_in[0];
    const float* up_w = (const float*)d_in[1];
    const float* up_b = (const float*)d_in[2];
    const float* mask_w = (const float*)d_in[3];
    const float* mask_b = (const float*)d_in[4];
    const float* sum_w = (const float*)d_in[5];
    const float* sum_b = (const float*)d_in[6];
    const float* down_w = (const float*)d_in[7];
    const float* down_b = (const float*)d_in[8];
    const float* bn_w = (const float*)d_in[9];
    const float* bn_b = (const float*)d_in[10];
    float* out = (float*)d_out;

    // workspace layout (float units)
    float* ws = (float*)d_ws;
    size_t o = 0;
    float* rn = ws + o;   o += (size_t)B_ * T_;
    float* nrm = ws + o;  o += (size_t)B_ * T_;
    float* xs = ws + o;   o += (size_t)B_ * C_ * SCOLS_;
    float* msub = ws + o; o += (size_t)B_ * SUBN_;
    float* tau0 = ws + o; o += B_;
    int* gh = (int*)(ws + o);    o += (size_t)B_ * NB1_;
    int* sel_e = (int*)(ws + o); o += (size_t)B_ * K_;
    int* sel_t = (int*)(ws + o); o += (size_t)B_ * K_;
    float* sel_sp = ws + o; o += (size_t)B_ * K_;
    float* gval = ws + o;   o += (size_t)B_ * K_;
    float* scalec = ws + o; o += C_;
    float* obase = ws + o;  o += (size_t)B_ * C_ + 8;
    // no-atomic collection buffers
    float* zpart = ws + o;  o += NBLK_;
    int* cntB = (int*)(ws + o); o += NBLK_;
    float* cvalB = ws + o;  o += (size_t)NBLK_ * BCAP_;
    int* cidxB = (int*)(ws + o); o += (size_t)NBLK_ * BCAP_;
    int* ovc = (int*)(ws + o); o += B_;
    float* ovv = ws + o;    o += (size_t)B_ * OCAP_;
    int* ovi = (int*)(ws + o); o += (size_t)B_ * OCAP_;
    // spike buffers
    int* map = (int*)(ws + o);  o += (size_t)B_ * T_;
    int* pri = (int*)(ws + o);  o += (size_t)B_ * K_;
    float* spk = ws + o;        o += (size_t)B_ * K_ * C_;
    // big split buffers last
    ushort* mwh = (ushort*)(ws + o); o += (size_t)E_ * C_ / 2;
    ushort* mwl = (ushort*)(ws + o); o += (size_t)E_ * C_ / 2;
    ushort* xh = (ushort*)(ws + o);  o += (size_t)B_ * T_ * C_ / 2;
    ushort* xl = (ushort*)(ws + o);  o += (size_t)B_ * T_ * C_ / 2;
    (void)ws_size;

    k_rn<<<(B_ * T_) / 64, 256, 0, stream>>>(x, rn, nrm, ovc, map, spk);
    k_gather<<<(B_ * C_ * SCOLS_) / 256, 256, 0, stream>>>(x, rn, xs, gh);
    k_msub2<<<dim3(SCOLS_ / 64, E_ / 64, B_), 256, 0, stream>>>(xs, mask_w, mask_b, msub);
    k_tau_hist<<<B_ * TAUP_, 256, 0, stream>>>(msub, gh);
    k_tau2<<<B_, 256, 0, stream>>>(gh, tau0);
    k_split_w<<<(E_ * C_ / 8) / 256, 256, 0, stream>>>(mask_w, mwh, mwl);
    k_split_x<<<dim3(T_ / 64, C_ / 64, B_), 256, 0, stream>>>(x, rn, xh, xl);
    k_gemm128<<<NBLK_, 256, 0, stream>>>(mwh, xh, mask_b, tau0,
                                         zpart, cntB, cvalB, cidxB,
                                         ovc, ovv, ovi);
    k_exact<<<NBLK_ + B_, 256, 0, stream>>>(mwh, mwl, xh, xl, mask_b,
                                            cntB, cidxB, cvalB, ovc, ovi, ovv);
    k_selectc<<<B_, 1024, 0, stream>>>(zpart, cntB, cvalB, cidxB,
                                       ovc, ovv, ovi, sel_e, sel_t, sel_sp);
    k_spk1<<<(B_ * K_) / 256, 256, 0, stream>>>(sel_t, map, pri);
    k_upg2<<<(B_ * K_ * 64) / 256, 256, 0, stream>>>(xh, xl, nrm, up_w, up_b,
                                                     sel_e, sel_t, sel_sp, gval);
    k_bsqbn<<<C_, 256, 0, stream>>>(sum_w, sum_b, down_b, down_w, sel_e, gval,
                                    bn_w, bn_b, scalec, obase);
    k_spk2<<<(B_ * K_ * 64) / 256, 256, 0, stream>>>(down_w, scalec, sel_e, pri,
                                                     gval, spk);
    k_fill2<<<(B_ * CT_ / 4) / 256, 256, 0, stream>>>(obase, map, spk, out);
}

// Round 17
// 209.931 us; speedup vs baseline: 1.3204x; 1.0106x over previous
//
#include <hip/hip_runtime.h>
#include <hip/hip_bf16.h>

// Problem constants (fixed by the reference)
#define B_ 8
#define C_ 256
#define E_ 512
#define T_ 8192
#define K_ 512
#define CT_ (C_*T_)
#define BCAP_ 512           // per-block LDS candidate capacity
#define OCAP_ 1024          // per-batch overflow capacity
#define NBLK_ 2048          // k_gemm128 grid
#define SUBS_ 64            // t-subsample stride
#define SCOLS_ (T_/SUBS_)   // 128
#define SUBN_ (E_*SCOLS_)   // 65536 subsample points per batch
#define RANK_ 64            // subsample rank -> expected full count ~4096
#define NB1_ 4096           // subsample histogram bins over [-1,1)
#define NB2_ 4096           // selection histogram bins over [0,0.5)
#define TAUP_ 8             // histogram partial blocks per batch
#define TAUM_ 0.004f        // bf16-m error margin (~40 sigma) for collection

typedef __attribute__((ext_vector_type(8))) short bf16x8;
typedef __attribute__((ext_vector_type(4))) float f32x4;

__device__ __forceinline__ ushort f2bf(float f) {
    __hip_bfloat16 h = __float2bfloat16(f);
    return *reinterpret_cast<ushort*>(&h);
}
__device__ __forceinline__ float bf2f(ushort u) {
    __hip_bfloat16 h = *reinterpret_cast<__hip_bfloat16*>(&u);
    return __bfloat162float(h);
}

// async global->LDS, 16B per lane; LDS dest = wave-uniform base + lane*16
__device__ __forceinline__ void gl16(const void* g, void* l) {
    __builtin_amdgcn_global_load_lds(
        (const __attribute__((address_space(1))) void*)g,
        (__attribute__((address_space(3))) void*)l, 16, 0, 0);
}

// Tiled operand layout (ushort units):
//   W tiles:  [etile(8)][cc(4)][cb(8)][erow(64)][8]   (16384 per etile)
//   X tiles:  [b*128+ttile][cc(4)][cb(8)][trow(64)][8] (16384 per ttile)

// rn/nrm, 4x wave-parallel over channels; fused: xs gather (this block's t0
// column), gh zeroing, ovc/map/spk init.  grid: B*T/64 = 1024 blocks x 256
__launch_bounds__(256)
__global__ void k_rn(const float* __restrict__ x, float* __restrict__ rn,
                     float* __restrict__ nrm, int* __restrict__ ovc,
                     int* __restrict__ map, float* __restrict__ spk,
                     float* __restrict__ xs, int* __restrict__ gh) {
    __shared__ float partial[4][64];
    __shared__ float xcol[256];
    __shared__ float rn0;
    int tid = threadIdx.x, lane = tid & 63, w = tid >> 6;
    int bid = blockIdx.x;
    int gid = bid * 256 + tid;                  // 0 .. 262143
    if (gid < B_) ovc[gid] = 0;
    if (gid < B_ * T_) map[gid] = -1;
    if (gid < B_ * NB1_) gh[gid] = 0;
    ((float4*)spk)[gid] = (float4){0.f, 0.f, 0.f, 0.f};  // B*K*C/4 = 262144
    int b = bid >> 7;
    int s = bid & 127;                          // xs column id (t0 = s*64)
    int t = s * 64 + lane;
    const float* xp = x + (size_t)b * CT_ + (size_t)(w * 64) * T_ + t;
    float s0 = 0.f, s1 = 0.f, s2 = 0.f, s3 = 0.f;
#pragma unroll 4
    for (int c = 0; c < 64; c += 4) {
        float a0 = xp[(size_t)c * T_];
        float a1 = xp[(size_t)(c + 1) * T_];
        float a2 = xp[(size_t)(c + 2) * T_];
        float a3 = xp[(size_t)(c + 3) * T_];
        if (lane == 0) {                        // stash t0 column for xs
            xcol[w * 64 + c] = a0;
            xcol[w * 64 + c + 1] = a1;
            xcol[w * 64 + c + 2] = a2;
            xcol[w * 64 + c + 3] = a3;
        }
        s0 += a0 * a0; s1 += a1 * a1; s2 += a2 * a2; s3 += a3 * a3;
    }
    partial[w][lane] = (s0 + s1) + (s2 + s3);
    __syncthreads();
    if (w == 0) {
        float sx = (partial[0][lane] + partial[1][lane])
                 + (partial[2][lane] + partial[3][lane]);
        float n = sqrtf(sx) + 1e-8f;
        nrm[b * T_ + t] = n;
        float r = 1.0f / n;
        rn[b * T_ + t] = r;
        if (lane == 0) rn0 = r;
    }
    __syncthreads();
    xs[b * (C_ * SCOLS_) + tid * SCOLS_ + s] = xcol[tid] * rn0;
}

// transpose + rn-scale + split into TILED layout; (ttile==0,cc==0) blocks
// also split mask_w (fused k_split_w, 1/8 per batch-index block)
__launch_bounds__(256)
__global__ void k_split_x(const float* __restrict__ x, const float* __restrict__ rn,
                          ushort* __restrict__ xh, ushort* __restrict__ xl,
                          const float* __restrict__ mw, ushort* __restrict__ mwh,
                          ushort* __restrict__ mwl) {
    __shared__ float tile[64][76];
    __shared__ float rnv[64];
    int tid = threadIdx.x;
    int ttile = blockIdx.x, cc = blockIdx.y, b = blockIdx.z;
    int t0 = ttile * 64, c0 = cc * 64;
    if (tid < 64) rnv[tid] = rn[b * T_ + t0 + tid];
    const float* xb = x + (size_t)b * CT_;
#pragma unroll
    for (int q = 0; q < 4; ++q) {
        int idx = tid + q * 256;
        int cr = idx >> 4, t4 = (idx & 15) * 4;
        float4 v = *(const float4*)(xb + (size_t)(c0 + cr) * T_ + t0 + t4);
        *(float4*)&tile[cr][t4] = v;
    }
    __syncthreads();
    size_t obase = (((size_t)b * 128 + ttile) * 4 + cc) * 4096;
#pragma unroll
    for (int q = 0; q < 4; ++q) {
        int idx = tid + q * 256;
        int tr = idx >> 4, c4 = (idx & 15) * 4;
        float sc = rnv[tr];
        float v0 = tile[c4 + 0][tr] * sc;
        float v1 = tile[c4 + 1][tr] * sc;
        float v2 = tile[c4 + 2][tr] * sc;
        float v3 = tile[c4 + 3][tr] * sc;
        ushort4 h, l;
        h.x = f2bf(v0); l.x = f2bf(v0 - bf2f(h.x));
        h.y = f2bf(v1); l.y = f2bf(v1 - bf2f(h.y));
        h.z = f2bf(v2); l.z = f2bf(v2 - bf2f(h.z));
        h.w = f2bf(v3); l.w = f2bf(v3 - bf2f(h.w));
        int cb = c4 >> 3, half = (c4 >> 2) & 1;
        size_t ro = obase + (size_t)cb * 512 + tr * 8 + half * 4;
        *(ushort4*)(xh + ro) = h;
        *(ushort4*)(xl + ro) = l;
    }
    // fused split_w: 8 blocks (ttile==0, cc==0), each 2048 items of 8 floats
    if (ttile == 0 && cc == 0) {
        for (int r = 0; r < 8; ++r) {
            int idx = b * 2048 + r * 256 + tid;
            int erow = idx & 63;
            int cbw = (idx >> 6) & 7;
            int ccw = (idx >> 9) & 3;
            int etile = idx >> 11;
            int e = etile * 64 + erow;
            int c0w = ccw * 64 + cbw * 8;
            const float* src = mw + (size_t)e * C_ + c0w;
            ushort4 h0, l0, h1, l1;
            float v;
            v = src[0]; h0.x = f2bf(v); l0.x = f2bf(v - bf2f(h0.x));
            v = src[1]; h0.y = f2bf(v); l0.y = f2bf(v - bf2f(h0.y));
            v = src[2]; h0.z = f2bf(v); l0.z = f2bf(v - bf2f(h0.z));
            v = src[3]; h0.w = f2bf(v); l0.w = f2bf(v - bf2f(h0.w));
            v = src[4]; h1.x = f2bf(v); l1.x = f2bf(v - bf2f(h1.x));
            v = src[5]; h1.y = f2bf(v); l1.y = f2bf(v - bf2f(h1.y));
            v = src[6]; h1.z = f2bf(v); l1.z = f2bf(v - bf2f(h1.z));
            v = src[7]; h1.w = f2bf(v); l1.w = f2bf(v - bf2f(h1.w));
            *(ushort4*)(mwh + (size_t)idx * 8) = h0;
            *(ushort4*)(mwh + (size_t)idx * 8 + 4) = h1;
            *(ushort4*)(mwl + (size_t)idx * 8) = l0;
            *(ushort4*)(mwl + (size_t)idx * 8 + 4) = l1;
        }
    }
}

// tiled f32 GEMM on compact gathered buffer (small: ~270 MFLOP)
__launch_bounds__(256)
__global__ void k_msub2(const float* __restrict__ xs, const float* __restrict__ mw,
                        const float* __restrict__ mb, float* __restrict__ msub) {
    __shared__ float As[64][68];
    __shared__ float Bs[64][68];
    int tid = threadIdx.x;
    int tx = tid & 15, ty = tid >> 4;
    int s0 = blockIdx.x * 64, e0 = blockIdx.y * 64, b = blockIdx.z;
    const float* xb = xs + (size_t)b * C_ * SCOLS_;
    float acc[4][4] = {};
    for (int c0 = 0; c0 < C_; c0 += 64) {
#pragma unroll
        for (int r = 0; r < 4; ++r) {
            int i = (tid >> 4) + r * 16;
            int kq = (tid & 15) * 4;
            float4 av = *(const float4*)(mw + (size_t)(e0 + i) * C_ + c0 + kq);
            As[kq + 0][i] = av.x; As[kq + 1][i] = av.y;
            As[kq + 2][i] = av.z; As[kq + 3][i] = av.w;
        }
#pragma unroll
        for (int r = 0; r < 4; ++r) {
            int k = (tid >> 4) + r * 16;
            int jq = (tid & 15) * 4;
            *(float4*)(&Bs[k][jq]) =
                *(const float4*)(xb + (size_t)(c0 + k) * SCOLS_ + s0 + jq);
        }
        __syncthreads();
#pragma unroll
        for (int k = 0; k < 64; ++k) {
            float4 a = *(const float4*)(&As[k][ty * 4]);
            float4 bq = *(const float4*)(&Bs[k][tx * 4]);
            float av[4] = {a.x, a.y, a.z, a.w};
            float bv[4] = {bq.x, bq.y, bq.z, bq.w};
#pragma unroll
            for (int ii = 0; ii < 4; ++ii)
#pragma unroll
                for (int jj = 0; jj < 4; ++jj)
                    acc[ii][jj] += av[ii] * bv[jj];
        }
        __syncthreads();
    }
#pragma unroll
    for (int ii = 0; ii < 4; ++ii) {
        float mbv = mb[e0 + ty * 4 + ii];
#pragma unroll
        for (int jj = 0; jj < 4; ++jj) {
            int e = e0 + ty * 4 + ii, s = s0 + tx * 4 + jj;
            msub[(size_t)b * SUBN_ + e * SCOLS_ + s] = acc[ii][jj] + mbv;
        }
    }
}

// parallel histogram of msub: 64 blocks (8 per batch) -> global gh[b][NB1]
__launch_bounds__(256)
__global__ void k_tau_hist(const float* __restrict__ msub, int* __restrict__ gh) {
    __shared__ int h[NB1_];
    int tid = threadIdx.x;
    int b = blockIdx.x >> 3, part = blockIdx.x & (TAUP_ - 1);
    for (int i = tid; i < NB1_; i += 256) h[i] = 0;
    __syncthreads();
    const float* mp = msub + (size_t)b * SUBN_ + part * (SUBN_ / TAUP_);
    for (int j = tid; j < SUBN_ / TAUP_; j += 256) {
        float v = mp[j];
        int bin = (int)((v + 1.0f) * ((float)NB1_ * 0.5f));
        bin = bin < 0 ? 0 : (bin > NB1_ - 1 ? NB1_ - 1 : bin);
        atomicAdd(&h[bin], 1);
    }
    __syncthreads();
    int* ghb = gh + b * NB1_;
    for (int i = tid; i < NB1_; i += 256)
        if (h[i]) atomicAdd(&ghb[i], h[i]);   // fire-and-forget, low contention
}

// per-batch conservative threshold tau0 from global histogram rank-64
__global__ void k_tau2(const int* __restrict__ gh, float* __restrict__ tau0) {
    __shared__ int part[256];
    int b = blockIdx.x, tid = threadIdx.x;
    const int* h = gh + b * NB1_;
    int ps = 0;
    for (int j = 0; j < 16; ++j) ps += h[tid * 16 + j];
    part[tid] = ps;
    __syncthreads();
    if (tid == 0) {
        int cum = 0, bf = 0;
        for (int i = 255; i >= 0; --i) {
            if (cum + part[i] >= RANK_) {
                int cum2 = cum;
                for (int j = 15; j >= 0; --j) {
                    cum2 += h[i * 16 + j];
                    if (cum2 >= RANK_) { bf = i * 16 + j; break; }
                }
                break;
            }
            cum += part[i];
        }
        tau0[b] = (float)bf * (2.0f / (float)NB1_) - 1.0f;  // bin lower edge
    }
}

// ---------------- fast main GEMM: plain bf16, half staging, 1/3 MFMA --------
__launch_bounds__(256)
__global__ void k_gemm128(const ushort* __restrict__ mwh, const ushort* __restrict__ xh,
                          const float* __restrict__ mb, const float* __restrict__ tau0,
                          float* __restrict__ zpart, int* __restrict__ cntB,
                          float* __restrict__ cvalB, int* __restrict__ cidxB,
                          int* __restrict__ ovc, float* __restrict__ ovv,
                          int* __restrict__ ovi) {
    __shared__ ushort S[4][4096];   // Wh0,Wh1,Xh0,Xh1 (8KB each)
    __shared__ float red[4];
    __shared__ float sval[BCAP_];
    __shared__ int sidx[BCAP_];
    __shared__ int scnt;
    int tid = threadIdx.x, lane = tid & 63, w = tid >> 6;
    int f = blockIdx.x;
    int xcd = f & 7, slot = f >> 3;          // XCD grouping: b == xcd
    int eblk = slot & 3, xt = slot >> 2;     // 4 e-blocks adjacent per x-tile
    int xtile = xcd * 64 + xt;               // 0..511 = b*64 + tt
    int b = xtile >> 6, tt = xtile & 63;
    int e0 = eblk * 128, t0 = tt * 128;
    if (tid == 0) scnt = 0;

    const ushort* base;
    if (w < 2) base = mwh + (size_t)(eblk * 2 + (w & 1)) * 16384;
    else       base = xh + ((size_t)b * 128 + tt * 2 + (w & 1)) * 16384;
    const ushort* gsrc = base + lane * 8;

    f32x4 acc[4][4];
#pragma unroll
    for (int m = 0; m < 4; ++m)
#pragma unroll
        for (int n = 0; n < 4; ++n)
            acc[m][n] = (f32x4){0.f, 0.f, 0.f, 0.f};

    int a15 = lane & 15;
    int khalf = lane >> 4;                   // 0..3
    int wr = w >> 1, wc = w & 1;             // wave's 64x64 quadrant

    for (int cc = 0; cc < 4; ++cc) {
#pragma unroll
        for (int i = 0; i < 8; ++i)
            gl16(gsrc + cc * 4096 + i * 512, &S[w][0] + i * 512);
        __syncthreads();
#pragma unroll
        for (int ks = 0; ks < 2; ++ks) {
            int cb16 = ks * 4 + khalf;
            bf16x8 ah[4], bh[4];
#pragma unroll
            for (int m = 0; m < 4; ++m) {
                int aoff = (cb16 * 64 + m * 16 + a15) * 16;
                ah[m] = *(const bf16x8*)((const char*)&S[wr][0] + aoff);
            }
#pragma unroll
            for (int n = 0; n < 4; ++n) {
                int boff = (cb16 * 64 + n * 16 + a15) * 16;
                bh[n] = *(const bf16x8*)((const char*)&S[2 + wc][0] + boff);
            }
#pragma unroll
            for (int m = 0; m < 4; ++m)
#pragma unroll
                for (int n = 0; n < 4; ++n)
                    acc[m][n] = __builtin_amdgcn_mfma_f32_16x16x32_bf16(ah[m], bh[n], acc[m][n], 0, 0, 0);
        }
        __syncthreads();
    }

    // epilogue: C/D layout col(t)=lane&15, row(e)=(lane>>4)*4+reg
    float tau = tau0[b] - TAUM_;
    float zs = 0.f;
    int erow0 = e0 + wr * 64 + (lane >> 4) * 4;
#pragma unroll
    for (int m = 0; m < 4; ++m)
#pragma unroll
        for (int r = 0; r < 4; ++r) {
            int e = erow0 + m * 16 + r;
            float mbe = mb[e];
#pragma unroll
            for (int n = 0; n < 4; ++n) {
                int t = t0 + wc * 64 + n * 16 + a15;
                float v = acc[m][n][r] + mbe;
                zs += __expf(v);
                if (v >= tau) {
                    int pos = atomicAdd(&scnt, 1);       // LDS atomic (fast)
                    if (pos < BCAP_) {
                        sval[pos] = v;
                        sidx[pos] = e * T_ + t;
                    } else {                             // rare overflow spill
                        int q2 = atomicAdd(&ovc[b], 1);
                        if (q2 < OCAP_) {
                            ovv[b * OCAP_ + q2] = v;
                            ovi[b * OCAP_ + q2] = e * T_ + t;
                        }
                    }
                }
            }
        }
#pragma unroll
    for (int off = 32; off; off >>= 1) zs += __shfl_xor(zs, off, 64);
    if (lane == 0) red[w] = zs;
    __syncthreads();
    // flush: plain stores only
    int nc = scnt < BCAP_ ? scnt : BCAP_;
    for (int j = tid; j < nc; j += 256) {
        cvalB[(size_t)f * BCAP_ + j] = sval[j];
        cidxB[(size_t)f * BCAP_ + j] = sidx[j];
    }
    if (tid == 0) {
        cntB[f] = nc;
        zpart[f] = (red[0] + red[1]) + (red[2] + red[3]);
    }
}

// recompute exact m (f32, split pairs) for every collected candidate
__launch_bounds__(256)
__global__ void k_exact(const ushort* __restrict__ mwh, const ushort* __restrict__ mwl,
                        const ushort* __restrict__ xh, const ushort* __restrict__ xl,
                        const float* __restrict__ mb, const int* __restrict__ cntB,
                        const int* __restrict__ cidxB, float* __restrict__ cvalB,
                        const int* __restrict__ ovc, const int* __restrict__ ovi,
                        float* __restrict__ ovv) {
    int f = blockIdx.x;
    int wv = threadIdx.x >> 6, lane = threadIdx.x & 63;
    int cc = lane >> 4, cb = (lane >> 1) & 7, half = lane & 1;
    int n, b;
    const int* ip;
    float* vp;
    if (f < NBLK_) {
        b = f & 7;
        n = cntB[f]; if (n > BCAP_) n = BCAP_;
        ip = cidxB + (size_t)f * BCAP_;
        vp = cvalB + (size_t)f * BCAP_;
    } else {
        b = f - NBLK_;
        n = ovc[b]; if (n > OCAP_) n = OCAP_;
        ip = ovi + (size_t)b * OCAP_;
        vp = ovv + (size_t)b * OCAP_;
    }
    for (int j = wv; j < n; j += 4) {
        int idx = ip[j];
        int e = idx >> 13, t = idx & (T_ - 1);
        size_t xro = ((((size_t)b * 128 + (t >> 6)) * 4 + cc) * 8 + cb) * 512
                   + (size_t)(t & 63) * 8 + half * 4;
        size_t wro = (((size_t)(e >> 6) * 4 + cc) * 8 + cb) * 512
                   + (size_t)(e & 63) * 8 + half * 4;
        ushort4 hx = *(const ushort4*)(xh + xro);
        ushort4 lx = *(const ushort4*)(xl + xro);
        ushort4 hw = *(const ushort4*)(mwh + wro);
        ushort4 lw = *(const ushort4*)(mwl + wro);
        float a = (bf2f(hw.x) + bf2f(lw.x)) * (bf2f(hx.x) + bf2f(lx.x))
                + (bf2f(hw.y) + bf2f(lw.y)) * (bf2f(hx.y) + bf2f(lx.y))
                + (bf2f(hw.z) + bf2f(lw.z)) * (bf2f(hx.z) + bf2f(lx.z))
                + (bf2f(hw.w) + bf2f(lw.w)) * (bf2f(hx.w) + bf2f(lx.w));
#pragma unroll
        for (int off = 32; off; off >>= 1) a += __shfl_xor(a, off, 64);
        if (lane == 0) vp[j] = a + mb[e];
    }
}

// top-K selection straight from per-block regions (no compaction).
// 1024 threads: 4 sub-threads per region; two L2-resident sweeps.
__launch_bounds__(1024)
__global__ void k_selectc(const float* __restrict__ zpart, const int* __restrict__ cntB,
                          const float* __restrict__ cvalB, const int* __restrict__ cidxB,
                          const int* __restrict__ ovc, const float* __restrict__ ovv,
                          const int* __restrict__ ovi, int* __restrict__ sel_e,
                          int* __restrict__ sel_t, float* __restrict__ sel_sp) {
    __shared__ float zsh[256];
    __shared__ int h[NB2_];
    __shared__ int part[256];
    __shared__ float bl_v[1024];
    __shared__ int bl_i[1024];
    __shared__ int nb, bstar, nabove, outcnt;
    int b = blockIdx.x, tid = threadIdx.x;
    int rid = tid & 255, sub = tid >> 8;     // 4 subthreads per region
    int f = b + 8 * rid;
    int c = cntB[f];                          // all 4 subs read same (cached)
    for (int i = tid; i < NB2_; i += 1024) h[i] = 0;
    if (tid < 256) zsh[tid] = zpart[b + 8 * tid];
    if (tid == 0) { nb = 0; outcnt = 0; bstar = 0; nabove = 0; }
    __syncthreads();
    // ---- pass 1: histogram from regions (+ overflow) ----
    const float* rv = cvalB + (size_t)f * BCAP_;
    for (int j = sub; j < c; j += 4) {
        float v = rv[j];
        int bin = (int)(v * ((float)NB2_ * 2.0f));
        bin = bin < 0 ? 0 : (bin > NB2_ - 1 ? NB2_ - 1 : bin);
        atomicAdd(&h[bin], 1);
    }
    int no = ovc[b]; if (no > OCAP_) no = OCAP_;
    for (int j = tid; j < no; j += 1024) {
        float v = ovv[b * OCAP_ + j];
        int bin = (int)(v * ((float)NB2_ * 2.0f));
        bin = bin < 0 ? 0 : (bin > NB2_ - 1 ? NB2_ - 1 : bin);
        atomicAdd(&h[bin], 1);
    }
    __syncthreads();
    // Z reduction (first 256 threads)
    for (int d = 128; d; d >>= 1) {
        if (tid < d) zsh[tid] += zsh[tid + d];
        __syncthreads();
    }
    // ---- boundary-bin search: suffix scan over 16-bin group sums ----
    if (tid < 256) {
        int ps = 0;
#pragma unroll
        for (int j = 0; j < 16; ++j) ps += h[tid * 16 + j];
        part[tid] = ps;
    }
    __syncthreads();
    for (int d = 1; d < 256; d <<= 1) {      // inclusive suffix scan
        int v = 0;
        if (tid < 256) v = (tid + d < 256) ? part[tid + d] : 0;
        __syncthreads();
        if (tid < 256) part[tid] += v;
        __syncthreads();
    }
    if (tid < 256 && part[tid] >= K_ && (tid == 255 || part[tid + 1] < K_)) {
        int cum2 = (tid == 255) ? 0 : part[tid + 1];
        for (int j = 15; j >= 0; --j) {
            cum2 += h[tid * 16 + j];
            if (cum2 >= K_) { bstar = tid * 16 + j; nabove = cum2 - h[tid * 16 + j]; break; }
        }
    }
    __syncthreads();
    // ---- pass 2: write >bs outputs, collect boundary bin ----
    int bs = bstar;
    float rZ = 1.0f / zsh[0];
    const int* ri = cidxB + (size_t)f * BCAP_;
    for (int j = sub; j < c; j += 4) {
        float v = rv[j];
        int bin = (int)(v * ((float)NB2_ * 2.0f));
        bin = bin < 0 ? 0 : (bin > NB2_ - 1 ? NB2_ - 1 : bin);
        if (bin > bs) {
            int q = atomicAdd(&outcnt, 1);
            int idx = ri[j];
            sel_e[b * K_ + q] = idx / T_;
            sel_t[b * K_ + q] = idx % T_;
            sel_sp[b * K_ + q] = __expf(v) * rZ;
        } else if (bin == bs) {
            int q = atomicAdd(&nb, 1);
            if (q < 1024) { bl_v[q] = v; bl_i[q] = ri[j]; }
        }
    }
    for (int j = tid; j < no; j += 1024) {
        float v = ovv[b * OCAP_ + j];
        int bin = (int)(v * ((float)NB2_ * 2.0f));
        bin = bin < 0 ? 0 : (bin > NB2_ - 1 ? NB2_ - 1 : bin);
        if (bin > bs) {
            int q = atomicAdd(&outcnt, 1);
            int idx = ovi[b * OCAP_ + j];
            sel_e[b * K_ + q] = idx / T_;
            sel_t[b * K_ + q] = idx % T_;
            sel_sp[b * K_ + q] = __expf(v) * rZ;
        } else if (bin == bs) {
            int q = atomicAdd(&nb, 1);
            if (q < 1024) { bl_v[q] = v; bl_i[q] = ovi[b * OCAP_ + j]; }
        }
    }
    __syncthreads();
    // ---- parallel rank selection within the boundary bin ----
    int m = nb; if (m > 1024) m = 1024;
    int need = K_ - nabove;
    for (int j = tid; j < m; j += 1024) {
        float v = bl_v[j]; int id = bl_i[j];
        int r = 0;
        for (int i = 0; i < m; ++i) {
            float vi = bl_v[i]; int ii = bl_i[i];
            r += (vi > v || (vi == v && ii < id)) ? 1 : 0;
        }
        if (r < need) {
            int slot = nabove + r;
            sel_e[b * K_ + slot] = id / T_;
            sel_t[b * K_ + slot] = id % T_;
            sel_sp[b * K_ + slot] = __expf(v) * rZ;
        }
    }
    // pathological fallback: fewer boundary items than needed -> zero entries
    for (int q = m + tid; q < need; q += 1024) {
        int slot = nabove + q;
        sel_e[b * K_ + slot] = 0; sel_t[b * K_ + slot] = 0;
        sel_sp[b * K_ + slot] = 0.f;
    }
}

// up at selected positions via tiled split-x; fused spk slot assignment
__global__ void k_upg2(const ushort* __restrict__ xh, const ushort* __restrict__ xl,
                       const float* __restrict__ nrm, const float* __restrict__ uw,
                       const float* __restrict__ ub, const int* __restrict__ sel_e,
                       const int* __restrict__ sel_t, const float* __restrict__ sel_sp,
                       float* __restrict__ gval, int* __restrict__ map,
                       int* __restrict__ pri) {
    int gid = blockIdx.x * 256 + threadIdx.x;   // B*K waves
    int w = gid >> 6, lane = gid & 63;
    int b = w >> 9, i = w & (K_ - 1);
    int e = sel_e[b * K_ + i], t = sel_t[b * K_ + i];
    if (lane == 0) {                             // fused k_spk1
        int old = atomicCAS(&map[b * T_ + t], -1, i);
        pri[b * K_ + i] = (old == -1) ? i : old;
    }
    int ttile = t >> 6, trow = t & 63;
    int cc = lane >> 4, cb = (lane >> 1) & 7, half = lane & 1;
    size_t ro = ((((size_t)b * 128 + ttile) * 4 + cc) * 8 + cb) * 512
              + (size_t)trow * 8 + half * 4;          // c = lane*4 .. +4
    ushort4 h = *(const ushort4*)(xh + ro);
    ushort4 l = *(const ushort4*)(xl + ro);
    float4 wv = *(const float4*)(uw + (size_t)e * C_ + lane * 4);
    float acc = (bf2f(h.x) + bf2f(l.x)) * wv.x + (bf2f(h.y) + bf2f(l.y)) * wv.y
              + (bf2f(h.z) + bf2f(l.z)) * wv.z + (bf2f(h.w) + bf2f(l.w)) * wv.w;
#pragma unroll
    for (int off = 32; off; off >>= 1) acc += __shfl_down(acc, off, 64);
    if (lane == 0)
        gval[b * K_ + i] = sel_sp[b * K_ + i] * (acc * nrm[b * T_ + t] + ub[e]);
}

// fused base/S1/Q + BN stats: one block per channel c, 8 batches inside
__launch_bounds__(256)
__global__ void k_bsqbn(const float* __restrict__ sw, const float* __restrict__ sb,
                        const float* __restrict__ db, const float* __restrict__ dw,
                        const int* __restrict__ sel_e, const float* __restrict__ gval,
                        const float* __restrict__ bnw, const float* __restrict__ bnb,
                        float* __restrict__ scalec, float* __restrict__ obase) {
    __shared__ float barr[8], s1arr[8], qarr[8];
    int c = blockIdx.x;
    int w = threadIdx.x >> 6, lane = threadIdx.x & 63;
#pragma unroll
    for (int rep = 0; rep < 2; ++rep) {
        int b = w + rep * 4;
        float p = 0.f, s = 0.f, q = 0.f;
        for (int i = lane; i < K_; i += 64) {
            int e = sel_e[b * K_ + i];
            float g = gval[b * K_ + i];
            p += g * sw[(size_t)c * E_ + e];
            float wv = dw[(size_t)c * E_ + e] * g;
            s += wv; q += wv * wv;
        }
#pragma unroll
        for (int off = 32; off; off >>= 1) {
            p += __shfl_xor(p, off, 64);
            s += __shfl_xor(s, off, 64);
            q += __shfl_xor(q, off, 64);
        }
        if (lane == 0) {
            barr[b] = p + sb[c] + db[c];
            s1arr[b] = s; qarr[b] = q;
        }
    }
    __syncthreads();
    if (threadIdx.x == 0) {
        float msum = 0.f;
        for (int b = 0; b < B_; ++b) msum += (float)T_ * barr[b] + s1arr[b];
        float mean = msum / (float)(B_ * T_);
        float vs = 0.f;
        for (int b = 0; b < B_; ++b) {
            float d = barr[b] - mean;
            vs += (float)T_ * d * d + 2.0f * d * s1arr[b] + qarr[b];
        }
        float var = vs / (float)(B_ * T_);
        float sc = bnw[c] * rsqrtf(var + 1e-5f);
        scalec[c] = sc;
        for (int b = 0; b < B_; ++b)
            obase[b * C_ + c] = (barr[b] - mean) * sc + bnb[c];
    }
}

// spike accumulation into compact L2-resident spk[b][slot][c]
__global__ void k_spk2(const float* __restrict__ dw, const float* __restrict__ scalec,
                       const int* __restrict__ sel_e, const int* __restrict__ pri,
                       const float* __restrict__ gval, float* __restrict__ spk) {
    int gid = blockIdx.x * 256 + threadIdx.x;   // B*K*64 threads
    int s = gid >> 6, cq = (gid & 63) * 4;
    int b = s >> 9;
    int e = sel_e[s];
    float g = gval[s];
    int p = pri[s];
    float* dst = spk + ((size_t)(b * K_ + p)) * C_ + cq;
#pragma unroll
    for (int q = 0; q < 4; ++q) {
        int c = cq + q;
        atomicAdd(dst + q, scalec[c] * dw[(size_t)c * E_ + e] * g);
    }
}

// fill output: column-constant base + spike columns from compact spk
__global__ void k_fill2(const float* __restrict__ obase, const int* __restrict__ map,
                        const float* __restrict__ spk, float* __restrict__ out) {
    size_t gid = (size_t)blockIdx.x * 256 + threadIdx.x;
    size_t flat = gid * 4;
    int b = (int)(flat / CT_);
    int c = (int)(flat / T_) & (C_ - 1);
    int t0 = (int)(flat & (T_ - 1));
    float v = obase[b * C_ + c];
    float4 o = {v, v, v, v};
    int4 mp = *(const int4*)(map + b * T_ + t0);
    if (mp.x >= 0) o.x += spk[((size_t)(b * K_ + mp.x)) * C_ + c];
    if (mp.y >= 0) o.y += spk[((size_t)(b * K_ + mp.y)) * C_ + c];
    if (mp.z >= 0) o.z += spk[((size_t)(b * K_ + mp.z)) * C_ + c];
    if (mp.w >= 0) o.w += spk[((size_t)(b * K_ + mp.w)) * C_ + c];
    *(float4*)(out + flat) = o;
}

extern "C" void kernel_launch(void* const* d_in, const int* in_sizes, int n_in,
                              void* d_out, int out_size, void* d_ws, size_t ws_size,
                              hipStream_t stream) {
    const float* x = (const float*)d_in[0];
    const float* up_w = (const float*)d_in[1];
    const float* up_b = (const float*)d_in[2];
    const float* mask_w = (const float*)d_in[3];
    const float* mask_b = (const float*)d_in[4];
    const float* sum_w = (const float*)d_in[5];
    const float* sum_b = (const float*)d_in[6];
    const float* down_w = (const float*)d_in[7];
    const float* down_b = (const float*)d_in[8];
    const float* bn_w = (const float*)d_in[9];
    const float* bn_b = (const float*)d_in[10];
    float* out = (float*)d_out;

    // workspace layout (float units)
    float* ws = (float*)d_ws;
    size_t o = 0;
    float* rn = ws + o;   o += (size_t)B_ * T_;
    float* nrm = ws + o;  o += (size_t)B_ * T_;
    float* xs = ws + o;   o += (size_t)B_ * C_ * SCOLS_;
    float* msub = ws + o; o += (size_t)B_ * SUBN_;
    float* tau0 = ws + o; o += B_;
    int* gh = (int*)(ws + o);    o += (size_t)B_ * NB1_;
    int* sel_e = (int*)(ws + o); o += (size_t)B_ * K_;
    int* sel_t = (int*)(ws + o); o += (size_t)B_ * K_;
    float* sel_sp = ws + o; o += (size_t)B_ * K_;
    float* gval = ws + o;   o += (size_t)B_ * K_;
    float* scalec = ws + o; o += C_;
    float* obase = ws + o;  o += (size_t)B_ * C_ + 8;
    // no-atomic collection buffers
    float* zpart = ws + o;  o += NBLK_;
    int* cntB = (int*)(ws + o); o += NBLK_;
    float* cvalB = ws + o;  o += (size_t)NBLK_ * BCAP_;
    int* cidxB = (int*)(ws + o); o += (size_t)NBLK_ * BCAP_;
    int* ovc = (int*)(ws + o); o += B_;
    float* ovv = ws + o;    o += (size_t)B_ * OCAP_;
    int* ovi = (int*)(ws + o); o += (size_t)B_ * OCAP_;
    // spike buffers
    int* map = (int*)(ws + o);  o += (size_t)B_ * T_;
    int* pri = (int*)(ws + o);  o += (size_t)B_ * K_;
    float* spk = ws + o;        o += (size_t)B_ * K_ * C_;
    // big split buffers last
    ushort* mwh = (ushort*)(ws + o); o += (size_t)E_ * C_ / 2;
    ushort* mwl = (ushort*)(ws + o); o += (size_t)E_ * C_ / 2;
    ushort* xh = (ushort*)(ws + o);  o += (size_t)B_ * T_ * C_ / 2;
    ushort* xl = (ushort*)(ws + o);  o += (size_t)B_ * T_ * C_ / 2;
    (void)ws_size;

    k_rn<<<(B_ * T_) / 64, 256, 0, stream>>>(x, rn, nrm, ovc, map, spk, xs, gh);
    k_msub2<<<dim3(SCOLS_ / 64, E_ / 64, B_), 256, 0, stream>>>(xs, mask_w, mask_b, msub);
    k_tau_hist<<<B_ * TAUP_, 256, 0, stream>>>(msub, gh);
    k_tau2<<<B_, 256, 0, stream>>>(gh, tau0);
    k_split_x<<<dim3(T_ / 64, C_ / 64, B_), 256, 0, stream>>>(x, rn, xh, xl,
                                                              mask_w, mwh, mwl);
    k_gemm128<<<NBLK_, 256, 0, stream>>>(mwh, xh, mask_b, tau0,
                                         zpart, cntB, cvalB, cidxB,
                                         ovc, ovv, ovi);
    k_exact<<<NBLK_ + B_, 256, 0, stream>>>(mwh, mwl, xh, xl, mask_b,
                                            cntB, cidxB, cvalB, ovc, ovi, ovv);
    k_selectc<<<B_, 1024, 0, stream>>>(zpart, cntB, cvalB, cidxB,
                                       ovc, ovv, ovi, sel_e, sel_t, sel_sp);
    k_upg2<<<(B_ * K_ * 64) / 256, 256, 0, stream>>>(xh, xl, nrm, up_w, up_b,
                                                     sel_e, sel_t, sel_sp, gval,
                                                     map, pri);
    k_bsqbn<<<C_, 256, 0, stream>>>(sum_w, sum_b, down_b, down_w, sel_e, gval,
                                    bn_w, bn_b, scalec, obase);
    k_spk2<<<(B_ * K_ * 64) / 256, 256, 0, stream>>>(down_w, scalec, sel_e, pri,
                                                     gval, spk);
    k_fill2<<<(B_ * CT_ / 4) / 256, 256, 0, stream>>>(obase, map, spk, out);
}

// Round 18
// 195.762 us; speedup vs baseline: 1.4159x; 1.0724x over previous
//
#include <hip/hip_runtime.h>
#include <hip/hip_bf16.h>

// Problem constants (fixed by the reference)
#define B_ 8
#define C_ 256
#define E_ 512
#define T_ 8192
#define K_ 512
#define CT_ (C_*T_)
#define BCAP_ 512           // per-block LDS candidate capacity
#define OCAP_ 1024          // per-batch overflow capacity
#define NBLK_ 2048          // k_gemm128 grid
#define SUBS_ 64            // t-subsample stride
#define SCOLS_ (T_/SUBS_)   // 128
#define SUBN_ (E_*SCOLS_)   // 65536 subsample points per batch
#define RANK_ 64            // subsample rank -> expected full count ~4096
#define NB1_ 4096           // subsample histogram bins over [-1,1)
#define NB2_ 4096           // selection histogram bins over [0,0.5)
#define TAUP_ 8             // histogram partial blocks per batch
#define TAUM_ 0.004f        // bf16-m error margin (~40 sigma) for collection

typedef __attribute__((ext_vector_type(8))) short bf16x8;
typedef __attribute__((ext_vector_type(4))) float f32x4;

__device__ __forceinline__ ushort f2bf(float f) {
    __hip_bfloat16 h = __float2bfloat16(f);
    return *reinterpret_cast<ushort*>(&h);
}
__device__ __forceinline__ float bf2f(ushort u) {
    __hip_bfloat16 h = *reinterpret_cast<__hip_bfloat16*>(&u);
    return __bfloat162float(h);
}

// async global->LDS, 16B per lane; LDS dest = wave-uniform base + lane*16
__device__ __forceinline__ void gl16(const void* g, void* l) {
    __builtin_amdgcn_global_load_lds(
        (const __attribute__((address_space(1))) void*)g,
        (__attribute__((address_space(3))) void*)l, 16, 0, 0);
}

// Tiled operand layout (ushort units):
//   W tiles:  [etile(8)][cc(4)][cb(8)][erow(64)][8]   (16384 per etile)
//   X tiles:  [b*128+ttile][cc(4)][cb(8)][trow(64)][8] (16384 per ttile)

// FUSED: norms + transpose/rn-scale/split + xs gather + weight split + inits.
// x read exactly ONCE.  grid: B*128 = 1024 blocks x 256 threads, ~71KB LDS.
__launch_bounds__(256)
__global__ void k_rnsplit(const float* __restrict__ x, float* __restrict__ rn,
                          float* __restrict__ nrm, ushort* __restrict__ xh,
                          ushort* __restrict__ xl, float* __restrict__ xs,
                          const float* __restrict__ mw, ushort* __restrict__ mwh,
                          ushort* __restrict__ mwl, int* __restrict__ ovc,
                          int* __restrict__ map, float* __restrict__ spk,
                          int* __restrict__ gh) {
    __shared__ float tile[4][64][68];   // [cc][c-in-chunk][t]  (~69.6 KB)
    __shared__ float partial[4][64];
    __shared__ float rnv[64];
    int tid = threadIdx.x;
    int bid = blockIdx.x;
    int b = bid >> 7, ttile = bid & 127;
    int t0 = ttile * 64;
    int gid = bid * 256 + tid;                  // 0 .. 262143
    // init duties (same gid space as before)
    if (gid < B_) ovc[gid] = 0;
    if (gid < B_ * T_) map[gid] = -1;
    if (gid < B_ * NB1_) gh[gid] = 0;
    ((float4*)spk)[gid] = (float4){0.f, 0.f, 0.f, 0.f};  // B*K*C/4 = 262144
    const float* xb = x + (size_t)b * CT_;
    // load all 4 channel-chunks of this t-window into LDS (coalesced)
#pragma unroll
    for (int cc = 0; cc < 4; ++cc) {
#pragma unroll
        for (int q = 0; q < 4; ++q) {
            int idx = tid + q * 256;
            int cr = idx >> 4, t4 = (idx & 15) * 4;
            float4 v = *(const float4*)(xb + (size_t)(cc * 64 + cr) * T_ + t0 + t4);
            *(float4*)&tile[cc][cr][t4] = v;
        }
    }
    __syncthreads();
    // norms: 4 threads per t, each sums one 64-channel chunk from LDS
    {
        int t = tid & 63, cq = tid >> 6;
        float s0 = 0.f, s1 = 0.f, s2 = 0.f, s3 = 0.f;
#pragma unroll 4
        for (int c = 0; c < 64; c += 4) {
            float a0 = tile[cq][c][t];
            float a1 = tile[cq][c + 1][t];
            float a2 = tile[cq][c + 2][t];
            float a3 = tile[cq][c + 3][t];
            s0 += a0 * a0; s1 += a1 * a1; s2 += a2 * a2; s3 += a3 * a3;
        }
        partial[cq][t] = (s0 + s1) + (s2 + s3);
    }
    __syncthreads();
    if (tid < 64) {
        float s = (partial[0][tid] + partial[1][tid])
                + (partial[2][tid] + partial[3][tid]);
        float n = sqrtf(s) + 1e-8f;
        nrm[b * T_ + t0 + tid] = n;
        float r = 1.0f / n;
        rn[b * T_ + t0 + tid] = r;
        rnv[tid] = r;
    }
    __syncthreads();
    // xs column (t = t0 is this block's subsample point): c == tid
    xs[b * (C_ * SCOLS_) + tid * SCOLS_ + ttile] = tile[tid >> 6][tid & 63][0] * rnv[0];
    // split all 4 chunks from the SAME LDS copy (transpose reads)
#pragma unroll
    for (int cc = 0; cc < 4; ++cc) {
        size_t obase = (((size_t)b * 128 + ttile) * 4 + cc) * 4096;
#pragma unroll
        for (int q = 0; q < 4; ++q) {
            int idx = tid + q * 256;
            int tr = idx >> 4, c4 = (idx & 15) * 4;
            float sc = rnv[tr];
            float v0 = tile[cc][c4 + 0][tr] * sc;
            float v1 = tile[cc][c4 + 1][tr] * sc;
            float v2 = tile[cc][c4 + 2][tr] * sc;
            float v3 = tile[cc][c4 + 3][tr] * sc;
            ushort4 h, l;
            h.x = f2bf(v0); l.x = f2bf(v0 - bf2f(h.x));
            h.y = f2bf(v1); l.y = f2bf(v1 - bf2f(h.y));
            h.z = f2bf(v2); l.z = f2bf(v2 - bf2f(h.z));
            h.w = f2bf(v3); l.w = f2bf(v3 - bf2f(h.w));
            int cb = c4 >> 3, half = (c4 >> 2) & 1;
            size_t ro = obase + (size_t)cb * 512 + tr * 8 + half * 4;
            *(ushort4*)(xh + ro) = h;
            *(ushort4*)(xl + ro) = l;
        }
    }
    // fused split_w: 8 blocks (ttile==0), each 2048 items of 8 floats
    if (ttile == 0) {
        for (int r = 0; r < 8; ++r) {
            int idx = b * 2048 + r * 256 + tid;
            int erow = idx & 63;
            int cbw = (idx >> 6) & 7;
            int ccw = (idx >> 9) & 3;
            int etile = idx >> 11;
            int e = etile * 64 + erow;
            int c0w = ccw * 64 + cbw * 8;
            const float* src = mw + (size_t)e * C_ + c0w;
            ushort4 h0, l0, h1, l1;
            float v;
            v = src[0]; h0.x = f2bf(v); l0.x = f2bf(v - bf2f(h0.x));
            v = src[1]; h0.y = f2bf(v); l0.y = f2bf(v - bf2f(h0.y));
            v = src[2]; h0.z = f2bf(v); l0.z = f2bf(v - bf2f(h0.z));
            v = src[3]; h0.w = f2bf(v); l0.w = f2bf(v - bf2f(h0.w));
            v = src[4]; h1.x = f2bf(v); l1.x = f2bf(v - bf2f(h1.x));
            v = src[5]; h1.y = f2bf(v); l1.y = f2bf(v - bf2f(h1.y));
            v = src[6]; h1.z = f2bf(v); l1.z = f2bf(v - bf2f(h1.z));
            v = src[7]; h1.w = f2bf(v); l1.w = f2bf(v - bf2f(h1.w));
            *(ushort4*)(mwh + (size_t)idx * 8) = h0;
            *(ushort4*)(mwh + (size_t)idx * 8 + 4) = h1;
            *(ushort4*)(mwl + (size_t)idx * 8) = l0;
            *(ushort4*)(mwl + (size_t)idx * 8 + 4) = l1;
        }
    }
}

// tiled f32 GEMM on compact gathered buffer (small: ~270 MFLOP)
__launch_bounds__(256)
__global__ void k_msub2(const float* __restrict__ xs, const float* __restrict__ mw,
                        const float* __restrict__ mb, float* __restrict__ msub) {
    __shared__ float As[64][68];
    __shared__ float Bs[64][68];
    int tid = threadIdx.x;
    int tx = tid & 15, ty = tid >> 4;
    int s0 = blockIdx.x * 64, e0 = blockIdx.y * 64, b = blockIdx.z;
    const float* xb = xs + (size_t)b * C_ * SCOLS_;
    float acc[4][4] = {};
    for (int c0 = 0; c0 < C_; c0 += 64) {
#pragma unroll
        for (int r = 0; r < 4; ++r) {
            int i = (tid >> 4) + r * 16;
            int kq = (tid & 15) * 4;
            float4 av = *(const float4*)(mw + (size_t)(e0 + i) * C_ + c0 + kq);
            As[kq + 0][i] = av.x; As[kq + 1][i] = av.y;
            As[kq + 2][i] = av.z; As[kq + 3][i] = av.w;
        }
#pragma unroll
        for (int r = 0; r < 4; ++r) {
            int k = (tid >> 4) + r * 16;
            int jq = (tid & 15) * 4;
            *(float4*)(&Bs[k][jq]) =
                *(const float4*)(xb + (size_t)(c0 + k) * SCOLS_ + s0 + jq);
        }
        __syncthreads();
#pragma unroll
        for (int k = 0; k < 64; ++k) {
            float4 a = *(const float4*)(&As[k][ty * 4]);
            float4 bq = *(const float4*)(&Bs[k][tx * 4]);
            float av[4] = {a.x, a.y, a.z, a.w};
            float bv[4] = {bq.x, bq.y, bq.z, bq.w};
#pragma unroll
            for (int ii = 0; ii < 4; ++ii)
#pragma unroll
                for (int jj = 0; jj < 4; ++jj)
                    acc[ii][jj] += av[ii] * bv[jj];
        }
        __syncthreads();
    }
#pragma unroll
    for (int ii = 0; ii < 4; ++ii) {
        float mbv = mb[e0 + ty * 4 + ii];
#pragma unroll
        for (int jj = 0; jj < 4; ++jj) {
            int e = e0 + ty * 4 + ii, s = s0 + tx * 4 + jj;
            msub[(size_t)b * SUBN_ + e * SCOLS_ + s] = acc[ii][jj] + mbv;
        }
    }
}

// parallel histogram of msub: 64 blocks (8 per batch) -> global gh[b][NB1]
__launch_bounds__(256)
__global__ void k_tau_hist(const float* __restrict__ msub, int* __restrict__ gh) {
    __shared__ int h[NB1_];
    int tid = threadIdx.x;
    int b = blockIdx.x >> 3, part = blockIdx.x & (TAUP_ - 1);
    for (int i = tid; i < NB1_; i += 256) h[i] = 0;
    __syncthreads();
    const float* mp = msub + (size_t)b * SUBN_ + part * (SUBN_ / TAUP_);
    for (int j = tid; j < SUBN_ / TAUP_; j += 256) {
        float v = mp[j];
        int bin = (int)((v + 1.0f) * ((float)NB1_ * 0.5f));
        bin = bin < 0 ? 0 : (bin > NB1_ - 1 ? NB1_ - 1 : bin);
        atomicAdd(&h[bin], 1);
    }
    __syncthreads();
    int* ghb = gh + b * NB1_;
    for (int i = tid; i < NB1_; i += 256)
        if (h[i]) atomicAdd(&ghb[i], h[i]);   // fire-and-forget, low contention
}

// per-batch conservative threshold tau0 from global histogram rank-64
__global__ void k_tau2(const int* __restrict__ gh, float* __restrict__ tau0) {
    __shared__ int part[256];
    int b = blockIdx.x, tid = threadIdx.x;
    const int* h = gh + b * NB1_;
    int ps = 0;
    for (int j = 0; j < 16; ++j) ps += h[tid * 16 + j];
    part[tid] = ps;
    __syncthreads();
    if (tid == 0) {
        int cum = 0, bf = 0;
        for (int i = 255; i >= 0; --i) {
            if (cum + part[i] >= RANK_) {
                int cum2 = cum;
                for (int j = 15; j >= 0; --j) {
                    cum2 += h[i * 16 + j];
                    if (cum2 >= RANK_) { bf = i * 16 + j; break; }
                }
                break;
            }
            cum += part[i];
        }
        tau0[b] = (float)bf * (2.0f / (float)NB1_) - 1.0f;  // bin lower edge
    }
}

// ---------------- fast main GEMM: plain bf16, half staging, 1/3 MFMA --------
__launch_bounds__(256)
__global__ void k_gemm128(const ushort* __restrict__ mwh, const ushort* __restrict__ xh,
                          const float* __restrict__ mb, const float* __restrict__ tau0,
                          float* __restrict__ zpart, int* __restrict__ cntB,
                          float* __restrict__ cvalB, int* __restrict__ cidxB,
                          int* __restrict__ ovc, float* __restrict__ ovv,
                          int* __restrict__ ovi) {
    __shared__ ushort S[4][4096];   // Wh0,Wh1,Xh0,Xh1 (8KB each)
    __shared__ float red[4];
    __shared__ float sval[BCAP_];
    __shared__ int sidx[BCAP_];
    __shared__ int scnt;
    int tid = threadIdx.x, lane = tid & 63, w = tid >> 6;
    int f = blockIdx.x;
    int xcd = f & 7, slot = f >> 3;          // XCD grouping: b == xcd
    int eblk = slot & 3, xt = slot >> 2;     // 4 e-blocks adjacent per x-tile
    int xtile = xcd * 64 + xt;               // 0..511 = b*64 + tt
    int b = xtile >> 6, tt = xtile & 63;
    int e0 = eblk * 128, t0 = tt * 128;
    if (tid == 0) scnt = 0;

    const ushort* base;
    if (w < 2) base = mwh + (size_t)(eblk * 2 + (w & 1)) * 16384;
    else       base = xh + ((size_t)b * 128 + tt * 2 + (w & 1)) * 16384;
    const ushort* gsrc = base + lane * 8;

    f32x4 acc[4][4];
#pragma unroll
    for (int m = 0; m < 4; ++m)
#pragma unroll
        for (int n = 0; n < 4; ++n)
            acc[m][n] = (f32x4){0.f, 0.f, 0.f, 0.f};

    int a15 = lane & 15;
    int khalf = lane >> 4;                   // 0..3
    int wr = w >> 1, wc = w & 1;             // wave's 64x64 quadrant

    for (int cc = 0; cc < 4; ++cc) {
#pragma unroll
        for (int i = 0; i < 8; ++i)
            gl16(gsrc + cc * 4096 + i * 512, &S[w][0] + i * 512);
        __syncthreads();
#pragma unroll
        for (int ks = 0; ks < 2; ++ks) {
            int cb16 = ks * 4 + khalf;
            bf16x8 ah[4], bh[4];
#pragma unroll
            for (int m = 0; m < 4; ++m) {
                int aoff = (cb16 * 64 + m * 16 + a15) * 16;
                ah[m] = *(const bf16x8*)((const char*)&S[wr][0] + aoff);
            }
#pragma unroll
            for (int n = 0; n < 4; ++n) {
                int boff = (cb16 * 64 + n * 16 + a15) * 16;
                bh[n] = *(const bf16x8*)((const char*)&S[2 + wc][0] + boff);
            }
#pragma unroll
            for (int m = 0; m < 4; ++m)
#pragma unroll
                for (int n = 0; n < 4; ++n)
                    acc[m][n] = __builtin_amdgcn_mfma_f32_16x16x32_bf16(ah[m], bh[n], acc[m][n], 0, 0, 0);
        }
        __syncthreads();
    }

    // epilogue: C/D layout col(t)=lane&15, row(e)=(lane>>4)*4+reg
    float tau = tau0[b] - TAUM_;
    float zs = 0.f;
    int erow0 = e0 + wr * 64 + (lane >> 4) * 4;
#pragma unroll
    for (int m = 0; m < 4; ++m)
#pragma unroll
        for (int r = 0; r < 4; ++r) {
            int e = erow0 + m * 16 + r;
            float mbe = mb[e];
#pragma unroll
            for (int n = 0; n < 4; ++n) {
                int t = t0 + wc * 64 + n * 16 + a15;
                float v = acc[m][n][r] + mbe;
                zs += __expf(v);
                if (v >= tau) {
                    int pos = atomicAdd(&scnt, 1);       // LDS atomic (fast)
                    if (pos < BCAP_) {
                        sval[pos] = v;
                        sidx[pos] = e * T_ + t;
                    } else {                             // rare overflow spill
                        int q2 = atomicAdd(&ovc[b], 1);
                        if (q2 < OCAP_) {
                            ovv[b * OCAP_ + q2] = v;
                            ovi[b * OCAP_ + q2] = e * T_ + t;
                        }
                    }
                }
            }
        }
#pragma unroll
    for (int off = 32; off; off >>= 1) zs += __shfl_xor(zs, off, 64);
    if (lane == 0) red[w] = zs;
    __syncthreads();
    // flush: plain stores only
    int nc = scnt < BCAP_ ? scnt : BCAP_;
    for (int j = tid; j < nc; j += 256) {
        cvalB[(size_t)f * BCAP_ + j] = sval[j];
        cidxB[(size_t)f * BCAP_ + j] = sidx[j];
    }
    if (tid == 0) {
        cntB[f] = nc;
        zpart[f] = (red[0] + red[1]) + (red[2] + red[3]);
    }
}

// recompute exact m (f32, split pairs) for every collected candidate
__launch_bounds__(256)
__global__ void k_exact(const ushort* __restrict__ mwh, const ushort* __restrict__ mwl,
                        const ushort* __restrict__ xh, const ushort* __restrict__ xl,
                        const float* __restrict__ mb, const int* __restrict__ cntB,
                        const int* __restrict__ cidxB, float* __restrict__ cvalB,
                        const int* __restrict__ ovc, const int* __restrict__ ovi,
                        float* __restrict__ ovv) {
    int f = blockIdx.x;
    int wv = threadIdx.x >> 6, lane = threadIdx.x & 63;
    int cc = lane >> 4, cb = (lane >> 1) & 7, half = lane & 1;
    int n, b;
    const int* ip;
    float* vp;
    if (f < NBLK_) {
        b = f & 7;
        n = cntB[f]; if (n > BCAP_) n = BCAP_;
        ip = cidxB + (size_t)f * BCAP_;
        vp = cvalB + (size_t)f * BCAP_;
    } else {
        b = f - NBLK_;
        n = ovc[b]; if (n > OCAP_) n = OCAP_;
        ip = ovi + (size_t)b * OCAP_;
        vp = ovv + (size_t)b * OCAP_;
    }
    for (int j = wv; j < n; j += 4) {
        int idx = ip[j];
        int e = idx >> 13, t = idx & (T_ - 1);
        size_t xro = ((((size_t)b * 128 + (t >> 6)) * 4 + cc) * 8 + cb) * 512
                   + (size_t)(t & 63) * 8 + half * 4;
        size_t wro = (((size_t)(e >> 6) * 4 + cc) * 8 + cb) * 512
                   + (size_t)(e & 63) * 8 + half * 4;
        ushort4 hx = *(const ushort4*)(xh + xro);
        ushort4 lx = *(const ushort4*)(xl + xro);
        ushort4 hw = *(const ushort4*)(mwh + wro);
        ushort4 lw = *(const ushort4*)(mwl + wro);
        float a = (bf2f(hw.x) + bf2f(lw.x)) * (bf2f(hx.x) + bf2f(lx.x))
                + (bf2f(hw.y) + bf2f(lw.y)) * (bf2f(hx.y) + bf2f(lx.y))
                + (bf2f(hw.z) + bf2f(lw.z)) * (bf2f(hx.z) + bf2f(lx.z))
                + (bf2f(hw.w) + bf2f(lw.w)) * (bf2f(hx.w) + bf2f(lx.w));
#pragma unroll
        for (int off = 32; off; off >>= 1) a += __shfl_xor(a, off, 64);
        if (lane == 0) vp[j] = a + mb[e];
    }
}

// top-K selection straight from per-block regions (no compaction).
// 1024 threads: 4 sub-threads per region; two L2-resident sweeps.
__launch_bounds__(1024)
__global__ void k_selectc(const float* __restrict__ zpart, const int* __restrict__ cntB,
                          const float* __restrict__ cvalB, const int* __restrict__ cidxB,
                          const int* __restrict__ ovc, const float* __restrict__ ovv,
                          const int* __restrict__ ovi, int* __restrict__ sel_e,
                          int* __restrict__ sel_t, float* __restrict__ sel_sp) {
    __shared__ float zsh[256];
    __shared__ int h[NB2_];
    __shared__ int part[256];
    __shared__ float bl_v[1024];
    __shared__ int bl_i[1024];
    __shared__ int nb, bstar, nabove, outcnt;
    int b = blockIdx.x, tid = threadIdx.x;
    int rid = tid & 255, sub = tid >> 8;     // 4 subthreads per region
    int f = b + 8 * rid;
    int c = cntB[f];                          // all 4 subs read same (cached)
    for (int i = tid; i < NB2_; i += 1024) h[i] = 0;
    if (tid < 256) zsh[tid] = zpart[b + 8 * tid];
    if (tid == 0) { nb = 0; outcnt = 0; bstar = 0; nabove = 0; }
    __syncthreads();
    // ---- pass 1: histogram from regions (+ overflow) ----
    const float* rv = cvalB + (size_t)f * BCAP_;
    for (int j = sub; j < c; j += 4) {
        float v = rv[j];
        int bin = (int)(v * ((float)NB2_ * 2.0f));
        bin = bin < 0 ? 0 : (bin > NB2_ - 1 ? NB2_ - 1 : bin);
        atomicAdd(&h[bin], 1);
    }
    int no = ovc[b]; if (no > OCAP_) no = OCAP_;
    for (int j = tid; j < no; j += 1024) {
        float v = ovv[b * OCAP_ + j];
        int bin = (int)(v * ((float)NB2_ * 2.0f));
        bin = bin < 0 ? 0 : (bin > NB2_ - 1 ? NB2_ - 1 : bin);
        atomicAdd(&h[bin], 1);
    }
    __syncthreads();
    // Z reduction (first 256 threads)
    for (int d = 128; d; d >>= 1) {
        if (tid < d) zsh[tid] += zsh[tid + d];
        __syncthreads();
    }
    // ---- boundary-bin search: suffix scan over 16-bin group sums ----
    if (tid < 256) {
        int ps = 0;
#pragma unroll
        for (int j = 0; j < 16; ++j) ps += h[tid * 16 + j];
        part[tid] = ps;
    }
    __syncthreads();
    for (int d = 1; d < 256; d <<= 1) {      // inclusive suffix scan
        int v = 0;
        if (tid < 256) v = (tid + d < 256) ? part[tid + d] : 0;
        __syncthreads();
        if (tid < 256) part[tid] += v;
        __syncthreads();
    }
    if (tid < 256 && part[tid] >= K_ && (tid == 255 || part[tid + 1] < K_)) {
        int cum2 = (tid == 255) ? 0 : part[tid + 1];
        for (int j = 15; j >= 0; --j) {
            cum2 += h[tid * 16 + j];
            if (cum2 >= K_) { bstar = tid * 16 + j; nabove = cum2 - h[tid * 16 + j]; break; }
        }
    }
    __syncthreads();
    // ---- pass 2: write >bs outputs, collect boundary bin ----
    int bs = bstar;
    float rZ = 1.0f / zsh[0];
    const int* ri = cidxB + (size_t)f * BCAP_;
    for (int j = sub; j < c; j += 4) {
        float v = rv[j];
        int bin = (int)(v * ((float)NB2_ * 2.0f));
        bin = bin < 0 ? 0 : (bin > NB2_ - 1 ? NB2_ - 1 : bin);
        if (bin > bs) {
            int q = atomicAdd(&outcnt, 1);
            int idx = ri[j];
            sel_e[b * K_ + q] = idx / T_;
            sel_t[b * K_ + q] = idx % T_;
            sel_sp[b * K_ + q] = __expf(v) * rZ;
        } else if (bin == bs) {
            int q = atomicAdd(&nb, 1);
            if (q < 1024) { bl_v[q] = v; bl_i[q] = ri[j]; }
        }
    }
    for (int j = tid; j < no; j += 1024) {
        float v = ovv[b * OCAP_ + j];
        int bin = (int)(v * ((float)NB2_ * 2.0f));
        bin = bin < 0 ? 0 : (bin > NB2_ - 1 ? NB2_ - 1 : bin);
        if (bin > bs) {
            int q = atomicAdd(&outcnt, 1);
            int idx = ovi[b * OCAP_ + j];
            sel_e[b * K_ + q] = idx / T_;
            sel_t[b * K_ + q] = idx % T_;
            sel_sp[b * K_ + q] = __expf(v) * rZ;
        } else if (bin == bs) {
            int q = atomicAdd(&nb, 1);
            if (q < 1024) { bl_v[q] = v; bl_i[q] = ovi[b * OCAP_ + j]; }
        }
    }
    __syncthreads();
    // ---- parallel rank selection within the boundary bin ----
    int m = nb; if (m > 1024) m = 1024;
    int need = K_ - nabove;
    for (int j = tid; j < m; j += 1024) {
        float v = bl_v[j]; int id = bl_i[j];
        int r = 0;
        for (int i = 0; i < m; ++i) {
            float vi = bl_v[i]; int ii = bl_i[i];
            r += (vi > v || (vi == v && ii < id)) ? 1 : 0;
        }
        if (r < need) {
            int slot = nabove + r;
            sel_e[b * K_ + slot] = id / T_;
            sel_t[b * K_ + slot] = id % T_;
            sel_sp[b * K_ + slot] = __expf(v) * rZ;
        }
    }
    // pathological fallback: fewer boundary items than needed -> zero entries
    for (int q = m + tid; q < need; q += 1024) {
        int slot = nabove + q;
        sel_e[b * K_ + slot] = 0; sel_t[b * K_ + slot] = 0;
        sel_sp[b * K_ + slot] = 0.f;
    }
}

// up at selected positions via tiled split-x; fused spk slot assignment
__global__ void k_upg2(const ushort* __restrict__ xh, const ushort* __restrict__ xl,
                       const float* __restrict__ nrm, const float* __restrict__ uw,
                       const float* __restrict__ ub, const int* __restrict__ sel_e,
                       const int* __restrict__ sel_t, const float* __restrict__ sel_sp,
                       float* __restrict__ gval, int* __restrict__ map,
                       int* __restrict__ pri) {
    int gid = blockIdx.x * 256 + threadIdx.x;   // B*K waves
    int w = gid >> 6, lane = gid & 63;
    int b = w >> 9, i = w & (K_ - 1);
    int e = sel_e[b * K_ + i], t = sel_t[b * K_ + i];
    if (lane == 0) {                             // fused k_spk1
        int old = atomicCAS(&map[b * T_ + t], -1, i);
        pri[b * K_ + i] = (old == -1) ? i : old;
    }
    int ttile = t >> 6, trow = t & 63;
    int cc = lane >> 4, cb = (lane >> 1) & 7, half = lane & 1;
    size_t ro = ((((size_t)b * 128 + ttile) * 4 + cc) * 8 + cb) * 512
              + (size_t)trow * 8 + half * 4;          // c = lane*4 .. +4
    ushort4 h = *(const ushort4*)(xh + ro);
    ushort4 l = *(const ushort4*)(xl + ro);
    float4 wv = *(const float4*)(uw + (size_t)e * C_ + lane * 4);
    float acc = (bf2f(h.x) + bf2f(l.x)) * wv.x + (bf2f(h.y) + bf2f(l.y)) * wv.y
              + (bf2f(h.z) + bf2f(l.z)) * wv.z + (bf2f(h.w) + bf2f(l.w)) * wv.w;
#pragma unroll
    for (int off = 32; off; off >>= 1) acc += __shfl_down(acc, off, 64);
    if (lane == 0)
        gval[b * K_ + i] = sel_sp[b * K_ + i] * (acc * nrm[b * T_ + t] + ub[e]);
}

// fused base/S1/Q + BN stats: one block per channel c, 8 batches inside
__launch_bounds__(256)
__global__ void k_bsqbn(const float* __restrict__ sw, const float* __restrict__ sb,
                        const float* __restrict__ db, const float* __restrict__ dw,
                        const int* __restrict__ sel_e, const float* __restrict__ gval,
                        const float* __restrict__ bnw, const float* __restrict__ bnb,
                        float* __restrict__ scalec, float* __restrict__ obase) {
    __shared__ float barr[8], s1arr[8], qarr[8];
    int c = blockIdx.x;
    int w = threadIdx.x >> 6, lane = threadIdx.x & 63;
#pragma unroll
    for (int rep = 0; rep < 2; ++rep) {
        int b = w + rep * 4;
        float p = 0.f, s = 0.f, q = 0.f;
        for (int i = lane; i < K_; i += 64) {
            int e = sel_e[b * K_ + i];
            float g = gval[b * K_ + i];
            p += g * sw[(size_t)c * E_ + e];
            float wv = dw[(size_t)c * E_ + e] * g;
            s += wv; q += wv * wv;
        }
#pragma unroll
        for (int off = 32; off; off >>= 1) {
            p += __shfl_xor(p, off, 64);
            s += __shfl_xor(s, off, 64);
            q += __shfl_xor(q, off, 64);
        }
        if (lane == 0) {
            barr[b] = p + sb[c] + db[c];
            s1arr[b] = s; qarr[b] = q;
        }
    }
    __syncthreads();
    if (threadIdx.x == 0) {
        float msum = 0.f;
        for (int b = 0; b < B_; ++b) msum += (float)T_ * barr[b] + s1arr[b];
        float mean = msum / (float)(B_ * T_);
        float vs = 0.f;
        for (int b = 0; b < B_; ++b) {
            float d = barr[b] - mean;
            vs += (float)T_ * d * d + 2.0f * d * s1arr[b] + qarr[b];
        }
        float var = vs / (float)(B_ * T_);
        float sc = bnw[c] * rsqrtf(var + 1e-5f);
        scalec[c] = sc;
        for (int b = 0; b < B_; ++b)
            obase[b * C_ + c] = (barr[b] - mean) * sc + bnb[c];
    }
}

// spike accumulation into compact L2-resident spk[b][slot][c]
__global__ void k_spk2(const float* __restrict__ dw, const float* __restrict__ scalec,
                       const int* __restrict__ sel_e, const int* __restrict__ pri,
                       const float* __restrict__ gval, float* __restrict__ spk) {
    int gid = blockIdx.x * 256 + threadIdx.x;   // B*K*64 threads
    int s = gid >> 6, cq = (gid & 63) * 4;
    int b = s >> 9;
    int e = sel_e[s];
    float g = gval[s];
    int p = pri[s];
    float* dst = spk + ((size_t)(b * K_ + p)) * C_ + cq;
#pragma unroll
    for (int q = 0; q < 4; ++q) {
        int c = cq + q;
        atomicAdd(dst + q, scalec[c] * dw[(size_t)c * E_ + e] * g);
    }
}

// fill output: column-constant base + spike columns from compact spk
__global__ void k_fill2(const float* __restrict__ obase, const int* __restrict__ map,
                        const float* __restrict__ spk, float* __restrict__ out) {
    size_t gid = (size_t)blockIdx.x * 256 + threadIdx.x;
    size_t flat = gid * 4;
    int b = (int)(flat / CT_);
    int c = (int)(flat / T_) & (C_ - 1);
    int t0 = (int)(flat & (T_ - 1));
    float v = obase[b * C_ + c];
    float4 o = {v, v, v, v};
    int4 mp = *(const int4*)(map + b * T_ + t0);
    if (mp.x >= 0) o.x += spk[((size_t)(b * K_ + mp.x)) * C_ + c];
    if (mp.y >= 0) o.y += spk[((size_t)(b * K_ + mp.y)) * C_ + c];
    if (mp.z >= 0) o.z += spk[((size_t)(b * K_ + mp.z)) * C_ + c];
    if (mp.w >= 0) o.w += spk[((size_t)(b * K_ + mp.w)) * C_ + c];
    *(float4*)(out + flat) = o;
}

extern "C" void kernel_launch(void* const* d_in, const int* in_sizes, int n_in,
                              void* d_out, int out_size, void* d_ws, size_t ws_size,
                              hipStream_t stream) {
    const float* x = (const float*)d_in[0];
    const float* up_w = (const float*)d_in[1];
    const float* up_b = (const float*)d_in[2];
    const float* mask_w = (const float*)d_in[3];
    const float* mask_b = (const float*)d_in[4];
    const float* sum_w = (const float*)d_in[5];
    const float* sum_b = (const float*)d_in[6];
    const float* down_w = (const float*)d_in[7];
    const float* down_b = (const float*)d_in[8];
    const float* bn_w = (const float*)d_in[9];
    const float* bn_b = (const float*)d_in[10];
    float* out = (float*)d_out;

    // workspace layout (float units)
    float* ws = (float*)d_ws;
    size_t o = 0;
    float* rn = ws + o;   o += (size_t)B_ * T_;
    float* nrm = ws + o;  o += (size_t)B_ * T_;
    float* xs = ws + o;   o += (size_t)B_ * C_ * SCOLS_;
    float* msub = ws + o; o += (size_t)B_ * SUBN_;
    float* tau0 = ws + o; o += B_;
    int* gh = (int*)(ws + o);    o += (size_t)B_ * NB1_;
    int* sel_e = (int*)(ws + o); o += (size_t)B_ * K_;
    int* sel_t = (int*)(ws + o); o += (size_t)B_ * K_;
    float* sel_sp = ws + o; o += (size_t)B_ * K_;
    float* gval = ws + o;   o += (size_t)B_ * K_;
    float* scalec = ws + o; o += C_;
    float* obase = ws + o;  o += (size_t)B_ * C_ + 8;
    // no-atomic collection buffers
    float* zpart = ws + o;  o += NBLK_;
    int* cntB = (int*)(ws + o); o += NBLK_;
    float* cvalB = ws + o;  o += (size_t)NBLK_ * BCAP_;
    int* cidxB = (int*)(ws + o); o += (size_t)NBLK_ * BCAP_;
    int* ovc = (int*)(ws + o); o += B_;
    float* ovv = ws + o;    o += (size_t)B_ * OCAP_;
    int* ovi = (int*)(ws + o); o += (size_t)B_ * OCAP_;
    // spike buffers
    int* map = (int*)(ws + o);  o += (size_t)B_ * T_;
    int* pri = (int*)(ws + o);  o += (size_t)B_ * K_;
    float* spk = ws + o;        o += (size_t)B_ * K_ * C_;
    // big split buffers last
    ushort* mwh = (ushort*)(ws + o); o += (size_t)E_ * C_ / 2;
    ushort* mwl = (ushort*)(ws + o); o += (size_t)E_ * C_ / 2;
    ushort* xh = (ushort*)(ws + o);  o += (size_t)B_ * T_ * C_ / 2;
    ushort* xl = (ushort*)(ws + o);  o += (size_t)B_ * T_ * C_ / 2;
    (void)ws_size;

    k_rnsplit<<<B_ * 128, 256, 0, stream>>>(x, rn, nrm, xh, xl, xs,
                                            mask_w, mwh, mwl, ovc, map, spk, gh);
    k_msub2<<<dim3(SCOLS_ / 64, E_ / 64, B_), 256, 0, stream>>>(xs, mask_w, mask_b, msub);
    k_tau_hist<<<B_ * TAUP_, 256, 0, stream>>>(msub, gh);
    k_tau2<<<B_, 256, 0, stream>>>(gh, tau0);
    k_gemm128<<<NBLK_, 256, 0, stream>>>(mwh, xh, mask_b, tau0,
                                         zpart, cntB, cvalB, cidxB,
                                         ovc, ovv, ovi);
    k_exact<<<NBLK_ + B_, 256, 0, stream>>>(mwh, mwl, xh, xl, mask_b,
                                            cntB, cidxB, cvalB, ovc, ovi, ovv);
    k_selectc<<<B_, 1024, 0, stream>>>(zpart, cntB, cvalB, cidxB,
                                       ovc, ovv, ovi, sel_e, sel_t, sel_sp);
    k_upg2<<<(B_ * K_ * 64) / 256, 256, 0, stream>>>(xh, xl, nrm, up_w, up_b,
                                                     sel_e, sel_t, sel_sp, gval,
                                                     map, pri);
    k_bsqbn<<<C_, 256, 0, stream>>>(sum_w, sum_b, down_b, down_w, sel_e, gval,
                                    bn_w, bn_b, scalec, obase);
    k_spk2<<<(B_ * K_ * 64) / 256, 256, 0, stream>>>(down_w, scalec, sel_e, pri,
                                                     gval, spk);
    k_fill2<<<(B_ * CT_ / 4) / 256, 256, 0, stream>>>(obase, map, spk, out);
}

// Round 19
// 195.527 us; speedup vs baseline: 1.4176x; 1.0012x over previous
//
#include <hip/hip_runtime.h>
#include <hip/hip_bf16.h>

// Problem constants (fixed by the reference)
#define B_ 8
#define C_ 256
#define E_ 512
#define T_ 8192
#define K_ 512
#define CT_ (C_*T_)
#define BCAP_ 512           // per-block LDS candidate capacity
#define OCAP_ 1024          // per-batch overflow capacity
#define NBLK_ 2048          // k_gemm128 grid
#define SUBS_ 64            // t-subsample stride
#define SCOLS_ (T_/SUBS_)   // 128
#define SUBN_ (E_*SCOLS_)   // 65536 subsample points per batch
#define RANK_ 64            // subsample rank -> expected full count ~4096
#define NB1_ 4096           // subsample histogram bins over [-1,1)
#define NB2_ 4096           // selection histogram bins over [0,0.5)
#define TAUP_ 8             // histogram partial blocks per batch
#define TAUM_ 0.004f        // bf16-m error margin (~40 sigma) for collection

typedef __attribute__((ext_vector_type(8))) short bf16x8;
typedef __attribute__((ext_vector_type(4))) float f32x4;

__device__ __forceinline__ ushort f2bf(float f) {
    __hip_bfloat16 h = __float2bfloat16(f);
    return *reinterpret_cast<ushort*>(&h);
}
__device__ __forceinline__ float bf2f(ushort u) {
    __hip_bfloat16 h = *reinterpret_cast<__hip_bfloat16*>(&u);
    return __bfloat162float(h);
}

// async global->LDS, 16B per lane; LDS dest = wave-uniform base + lane*16
__device__ __forceinline__ void gl16(const void* g, void* l) {
    __builtin_amdgcn_global_load_lds(
        (const __attribute__((address_space(1))) void*)g,
        (__attribute__((address_space(3))) void*)l, 16, 0, 0);
}

// Tiled operand layout (ushort units):
//   W tiles:  [etile(8)][cc(4)][cb(8)][erow(64)][8]   (16384 per etile)
//   X tiles:  [b*128+ttile][cc(4)][cb(8)][trow(64)][8] (16384 per ttile)

// FUSED: norms + transpose/rn-scale/split + xs gather + weight split + inits.
// x read exactly ONCE.  32-t windows: grid B*256 = 2048 blocks x 256, ~38KB LDS
// (4 blocks/CU).  Split phase re-indexed so c4 is wave-uniform and tr = lane:
// conflict-free LDS reads + lane-contiguous global stores.
__launch_bounds__(256)
__global__ void k_rnsplit(const float* __restrict__ x, float* __restrict__ rn,
                          float* __restrict__ nrm, ushort* __restrict__ xh,
                          ushort* __restrict__ xl, float* __restrict__ xs,
                          const float* __restrict__ mw, ushort* __restrict__ mwh,
                          ushort* __restrict__ mwl, int* __restrict__ ovc,
                          int* __restrict__ map, float* __restrict__ spk,
                          int* __restrict__ gh) {
    __shared__ float tile[4][64][36];   // [cc][c-in-chunk][t]  (~36.9 KB)
    __shared__ float partial[8][32];
    __shared__ float rnv[32];
    int tid = threadIdx.x;
    int bid = blockIdx.x;
    int b = bid >> 8, tt32 = bid & 255;
    int t0 = tt32 * 32;
    int gid = bid * 256 + tid;                  // 0 .. 524287
    // init duties
    if (gid < B_) ovc[gid] = 0;
    if (gid < B_ * T_) map[gid] = -1;
    if (gid < B_ * NB1_) gh[gid] = 0;
    if (gid < (B_ * K_ * C_) / 4)
        ((float4*)spk)[gid] = (float4){0.f, 0.f, 0.f, 0.f};
    const float* xb = x + (size_t)b * CT_;
    // load all 4 channel-chunks of this 32-t window into LDS (128B/row)
#pragma unroll
    for (int cc = 0; cc < 4; ++cc) {
#pragma unroll
        for (int q = 0; q < 2; ++q) {
            int idx = tid + q * 256;
            int cr = idx >> 3, t4 = (idx & 7) * 4;
            float4 v = *(const float4*)(xb + (size_t)(cc * 64 + cr) * T_ + t0 + t4);
            *(float4*)&tile[cc][cr][t4] = v;
        }
    }
    __syncthreads();
    // norms: 8 threads per t, each sums one 32-channel sub-chunk from LDS
    {
        int t = tid & 31, cq = tid >> 5;        // cq 0..7
        int chunk = cq >> 1, coff = (cq & 1) * 32;
        float s0 = 0.f, s1 = 0.f, s2 = 0.f, s3 = 0.f;
#pragma unroll 4
        for (int c = 0; c < 32; c += 4) {
            float a0 = tile[chunk][coff + c][t];
            float a1 = tile[chunk][coff + c + 1][t];
            float a2 = tile[chunk][coff + c + 2][t];
            float a3 = tile[chunk][coff + c + 3][t];
            s0 += a0 * a0; s1 += a1 * a1; s2 += a2 * a2; s3 += a3 * a3;
        }
        partial[cq][t] = (s0 + s1) + (s2 + s3);
    }
    __syncthreads();
    if (tid < 32) {
        float s = ((partial[0][tid] + partial[1][tid])
                 + (partial[2][tid] + partial[3][tid]))
                + ((partial[4][tid] + partial[5][tid])
                 + (partial[6][tid] + partial[7][tid]));
        float n = sqrtf(s) + 1e-8f;
        nrm[b * T_ + t0 + tid] = n;
        float r = 1.0f / n;
        rn[b * T_ + t0 + tid] = r;
        rnv[tid] = r;
    }
    __syncthreads();
    // xs column: even windows start at a subsample point (t0 = (tt32/2)*64)
    if ((tt32 & 1) == 0) {
        int s = tt32 >> 1;
        xs[b * (C_ * SCOLS_) + tid * SCOLS_ + s] =
            tile[tid >> 6][tid & 63][0] * rnv[0];
    }
    // split: c4 wave-uniform, tr = lane-contiguous (conflict-free reads)
    int tt64 = tt32 >> 1, off = (tt32 & 1) * 32;
#pragma unroll
    for (int cc = 0; cc < 4; ++cc) {
        size_t obase = (((size_t)b * 128 + tt64) * 4 + cc) * 4096;
#pragma unroll
        for (int q = 0; q < 2; ++q) {
            int idx = tid + q * 256;
            int tr = idx & 31;
            int cgrp = idx >> 5;                // 0..15, wave-uniform
            int c4 = cgrp * 4;
            float sc = rnv[tr];
            float v0 = tile[cc][c4 + 0][tr] * sc;
            float v1 = tile[cc][c4 + 1][tr] * sc;
            float v2 = tile[cc][c4 + 2][tr] * sc;
            float v3 = tile[cc][c4 + 3][tr] * sc;
            ushort4 h, l;
            h.x = f2bf(v0); l.x = f2bf(v0 - bf2f(h.x));
            h.y = f2bf(v1); l.y = f2bf(v1 - bf2f(h.y));
            h.z = f2bf(v2); l.z = f2bf(v2 - bf2f(h.z));
            h.w = f2bf(v3); l.w = f2bf(v3 - bf2f(h.w));
            int cb = cgrp >> 1, half = cgrp & 1;
            size_t ro = obase + (size_t)cb * 512 + (size_t)(off + tr) * 8 + half * 4;
            *(ushort4*)(xh + ro) = h;
            *(ushort4*)(xl + ro) = l;
        }
    }
    // fused split_w: 8 blocks (tt32==0), each 2048 items of 8 floats
    if (tt32 == 0) {
        for (int r = 0; r < 8; ++r) {
            int idx = b * 2048 + r * 256 + tid;
            int erow = idx & 63;
            int cbw = (idx >> 6) & 7;
            int ccw = (idx >> 9) & 3;
            int etile = idx >> 11;
            int e = etile * 64 + erow;
            int c0w = ccw * 64 + cbw * 8;
            const float* src = mw + (size_t)e * C_ + c0w;
            ushort4 h0, l0, h1, l1;
            float v;
            v = src[0]; h0.x = f2bf(v); l0.x = f2bf(v - bf2f(h0.x));
            v = src[1]; h0.y = f2bf(v); l0.y = f2bf(v - bf2f(h0.y));
            v = src[2]; h0.z = f2bf(v); l0.z = f2bf(v - bf2f(h0.z));
            v = src[3]; h0.w = f2bf(v); l0.w = f2bf(v - bf2f(h0.w));
            v = src[4]; h1.x = f2bf(v); l1.x = f2bf(v - bf2f(h1.x));
            v = src[5]; h1.y = f2bf(v); l1.y = f2bf(v - bf2f(h1.y));
            v = src[6]; h1.z = f2bf(v); l1.z = f2bf(v - bf2f(h1.z));
            v = src[7]; h1.w = f2bf(v); l1.w = f2bf(v - bf2f(h1.w));
            *(ushort4*)(mwh + (size_t)idx * 8) = h0;
            *(ushort4*)(mwh + (size_t)idx * 8 + 4) = h1;
            *(ushort4*)(mwl + (size_t)idx * 8) = l0;
            *(ushort4*)(mwl + (size_t)idx * 8 + 4) = l1;
        }
    }
}

// tiled f32 GEMM on compact gathered buffer (small: ~270 MFLOP)
__launch_bounds__(256)
__global__ void k_msub2(const float* __restrict__ xs, const float* __restrict__ mw,
                        const float* __restrict__ mb, float* __restrict__ msub) {
    __shared__ float As[64][68];
    __shared__ float Bs[64][68];
    int tid = threadIdx.x;
    int tx = tid & 15, ty = tid >> 4;
    int s0 = blockIdx.x * 64, e0 = blockIdx.y * 64, b = blockIdx.z;
    const float* xb = xs + (size_t)b * C_ * SCOLS_;
    float acc[4][4] = {};
    for (int c0 = 0; c0 < C_; c0 += 64) {
#pragma unroll
        for (int r = 0; r < 4; ++r) {
            int i = (tid >> 4) + r * 16;
            int kq = (tid & 15) * 4;
            float4 av = *(const float4*)(mw + (size_t)(e0 + i) * C_ + c0 + kq);
            As[kq + 0][i] = av.x; As[kq + 1][i] = av.y;
            As[kq + 2][i] = av.z; As[kq + 3][i] = av.w;
        }
#pragma unroll
        for (int r = 0; r < 4; ++r) {
            int k = (tid >> 4) + r * 16;
            int jq = (tid & 15) * 4;
            *(float4*)(&Bs[k][jq]) =
                *(const float4*)(xb + (size_t)(c0 + k) * SCOLS_ + s0 + jq);
        }
        __syncthreads();
#pragma unroll
        for (int k = 0; k < 64; ++k) {
            float4 a = *(const float4*)(&As[k][ty * 4]);
            float4 bq = *(const float4*)(&Bs[k][tx * 4]);
            float av[4] = {a.x, a.y, a.z, a.w};
            float bv[4] = {bq.x, bq.y, bq.z, bq.w};
#pragma unroll
            for (int ii = 0; ii < 4; ++ii)
#pragma unroll
                for (int jj = 0; jj < 4; ++jj)
                    acc[ii][jj] += av[ii] * bv[jj];
        }
        __syncthreads();
    }
#pragma unroll
    for (int ii = 0; ii < 4; ++ii) {
        float mbv = mb[e0 + ty * 4 + ii];
#pragma unroll
        for (int jj = 0; jj < 4; ++jj) {
            int e = e0 + ty * 4 + ii, s = s0 + tx * 4 + jj;
            msub[(size_t)b * SUBN_ + e * SCOLS_ + s] = acc[ii][jj] + mbv;
        }
    }
}

// parallel histogram of msub: 64 blocks (8 per batch) -> global gh[b][NB1]
__launch_bounds__(256)
__global__ void k_tau_hist(const float* __restrict__ msub, int* __restrict__ gh) {
    __shared__ int h[NB1_];
    int tid = threadIdx.x;
    int b = blockIdx.x >> 3, part = blockIdx.x & (TAUP_ - 1);
    for (int i = tid; i < NB1_; i += 256) h[i] = 0;
    __syncthreads();
    const float* mp = msub + (size_t)b * SUBN_ + part * (SUBN_ / TAUP_);
    for (int j = tid; j < SUBN_ / TAUP_; j += 256) {
        float v = mp[j];
        int bin = (int)((v + 1.0f) * ((float)NB1_ * 0.5f));
        bin = bin < 0 ? 0 : (bin > NB1_ - 1 ? NB1_ - 1 : bin);
        atomicAdd(&h[bin], 1);
    }
    __syncthreads();
    int* ghb = gh + b * NB1_;
    for (int i = tid; i < NB1_; i += 256)
        if (h[i]) atomicAdd(&ghb[i], h[i]);   // fire-and-forget, low contention
}

// per-batch conservative threshold tau0 from global histogram rank-64
__global__ void k_tau2(const int* __restrict__ gh, float* __restrict__ tau0) {
    __shared__ int part[256];
    int b = blockIdx.x, tid = threadIdx.x;
    const int* h = gh + b * NB1_;
    int ps = 0;
    for (int j = 0; j < 16; ++j) ps += h[tid * 16 + j];
    part[tid] = ps;
    __syncthreads();
    if (tid == 0) {
        int cum = 0, bf = 0;
        for (int i = 255; i >= 0; --i) {
            if (cum + part[i] >= RANK_) {
                int cum2 = cum;
                for (int j = 15; j >= 0; --j) {
                    cum2 += h[i * 16 + j];
                    if (cum2 >= RANK_) { bf = i * 16 + j; break; }
                }
                break;
            }
            cum += part[i];
        }
        tau0[b] = (float)bf * (2.0f / (float)NB1_) - 1.0f;  // bin lower edge
    }
}

// ---------------- fast main GEMM: plain bf16, half staging, 1/3 MFMA --------
__launch_bounds__(256)
__global__ void k_gemm128(const ushort* __restrict__ mwh, const ushort* __restrict__ xh,
                          const float* __restrict__ mb, const float* __restrict__ tau0,
                          float* __restrict__ zpart, int* __restrict__ cntB,
                          float* __restrict__ cvalB, int* __restrict__ cidxB,
                          int* __restrict__ ovc, float* __restrict__ ovv,
                          int* __restrict__ ovi) {
    __shared__ ushort S[4][4096];   // Wh0,Wh1,Xh0,Xh1 (8KB each)
    __shared__ float red[4];
    __shared__ float sval[BCAP_];
    __shared__ int sidx[BCAP_];
    __shared__ int scnt;
    int tid = threadIdx.x, lane = tid & 63, w = tid >> 6;
    int f = blockIdx.x;
    int xcd = f & 7, slot = f >> 3;          // XCD grouping: b == xcd
    int eblk = slot & 3, xt = slot >> 2;     // 4 e-blocks adjacent per x-tile
    int xtile = xcd * 64 + xt;               // 0..511 = b*64 + tt
    int b = xtile >> 6, tt = xtile & 63;
    int e0 = eblk * 128, t0 = tt * 128;
    if (tid == 0) scnt = 0;

    const ushort* base;
    if (w < 2) base = mwh + (size_t)(eblk * 2 + (w & 1)) * 16384;
    else       base = xh + ((size_t)b * 128 + tt * 2 + (w & 1)) * 16384;
    const ushort* gsrc = base + lane * 8;

    f32x4 acc[4][4];
#pragma unroll
    for (int m = 0; m < 4; ++m)
#pragma unroll
        for (int n = 0; n < 4; ++n)
            acc[m][n] = (f32x4){0.f, 0.f, 0.f, 0.f};

    int a15 = lane & 15;
    int khalf = lane >> 4;                   // 0..3
    int wr = w >> 1, wc = w & 1;             // wave's 64x64 quadrant

    for (int cc = 0; cc < 4; ++cc) {
#pragma unroll
        for (int i = 0; i < 8; ++i)
            gl16(gsrc + cc * 4096 + i * 512, &S[w][0] + i * 512);
        __syncthreads();
#pragma unroll
        for (int ks = 0; ks < 2; ++ks) {
            int cb16 = ks * 4 + khalf;
            bf16x8 ah[4], bh[4];
#pragma unroll
            for (int m = 0; m < 4; ++m) {
                int aoff = (cb16 * 64 + m * 16 + a15) * 16;
                ah[m] = *(const bf16x8*)((const char*)&S[wr][0] + aoff);
            }
#pragma unroll
            for (int n = 0; n < 4; ++n) {
                int boff = (cb16 * 64 + n * 16 + a15) * 16;
                bh[n] = *(const bf16x8*)((const char*)&S[2 + wc][0] + boff);
            }
#pragma unroll
            for (int m = 0; m < 4; ++m)
#pragma unroll
                for (int n = 0; n < 4; ++n)
                    acc[m][n] = __builtin_amdgcn_mfma_f32_16x16x32_bf16(ah[m], bh[n], acc[m][n], 0, 0, 0);
        }
        __syncthreads();
    }

    // epilogue: C/D layout col(t)=lane&15, row(e)=(lane>>4)*4+reg
    float tau = tau0[b] - TAUM_;
    float zs = 0.f;
    int erow0 = e0 + wr * 64 + (lane >> 4) * 4;
#pragma unroll
    for (int m = 0; m < 4; ++m)
#pragma unroll
        for (int r = 0; r < 4; ++r) {
            int e = erow0 + m * 16 + r;
            float mbe = mb[e];
#pragma unroll
            for (int n = 0; n < 4; ++n) {
                int t = t0 + wc * 64 + n * 16 + a15;
                float v = acc[m][n][r] + mbe;
                zs += __expf(v);
                if (v >= tau) {
                    int pos = atomicAdd(&scnt, 1);       // LDS atomic (fast)
                    if (pos < BCAP_) {
                        sval[pos] = v;
                        sidx[pos] = e * T_ + t;
                    } else {                             // rare overflow spill
                        int q2 = atomicAdd(&ovc[b], 1);
                        if (q2 < OCAP_) {
                            ovv[b * OCAP_ + q2] = v;
                            ovi[b * OCAP_ + q2] = e * T_ + t;
                        }
                    }
                }
            }
        }
#pragma unroll
    for (int off = 32; off; off >>= 1) zs += __shfl_xor(zs, off, 64);
    if (lane == 0) red[w] = zs;
    __syncthreads();
    // flush: plain stores only
    int nc = scnt < BCAP_ ? scnt : BCAP_;
    for (int j = tid; j < nc; j += 256) {
        cvalB[(size_t)f * BCAP_ + j] = sval[j];
        cidxB[(size_t)f * BCAP_ + j] = sidx[j];
    }
    if (tid == 0) {
        cntB[f] = nc;
        zpart[f] = (red[0] + red[1]) + (red[2] + red[3]);
    }
}

// recompute exact m (f32, split pairs) for every collected candidate
__launch_bounds__(256)
__global__ void k_exact(const ushort* __restrict__ mwh, const ushort* __restrict__ mwl,
                        const ushort* __restrict__ xh, const ushort* __restrict__ xl,
                        const float* __restrict__ mb, const int* __restrict__ cntB,
                        const int* __restrict__ cidxB, float* __restrict__ cvalB,
                        const int* __restrict__ ovc, const int* __restrict__ ovi,
                        float* __restrict__ ovv) {
    int f = blockIdx.x;
    int wv = threadIdx.x >> 6, lane = threadIdx.x & 63;
    int cc = lane >> 4, cb = (lane >> 1) & 7, half = lane & 1;
    int n, b;
    const int* ip;
    float* vp;
    if (f < NBLK_) {
        b = f & 7;
        n = cntB[f]; if (n > BCAP_) n = BCAP_;
        ip = cidxB + (size_t)f * BCAP_;
        vp = cvalB + (size_t)f * BCAP_;
    } else {
        b = f - NBLK_;
        n = ovc[b]; if (n > OCAP_) n = OCAP_;
        ip = ovi + (size_t)b * OCAP_;
        vp = ovv + (size_t)b * OCAP_;
    }
    for (int j = wv; j < n; j += 4) {
        int idx = ip[j];
        int e = idx >> 13, t = idx & (T_ - 1);
        size_t xro = ((((size_t)b * 128 + (t >> 6)) * 4 + cc) * 8 + cb) * 512
                   + (size_t)(t & 63) * 8 + half * 4;
        size_t wro = (((size_t)(e >> 6) * 4 + cc) * 8 + cb) * 512
                   + (size_t)(e & 63) * 8 + half * 4;
        ushort4 hx = *(const ushort4*)(xh + xro);
        ushort4 lx = *(const ushort4*)(xl + xro);
        ushort4 hw = *(const ushort4*)(mwh + wro);
        ushort4 lw = *(const ushort4*)(mwl + wro);
        float a = (bf2f(hw.x) + bf2f(lw.x)) * (bf2f(hx.x) + bf2f(lx.x))
                + (bf2f(hw.y) + bf2f(lw.y)) * (bf2f(hx.y) + bf2f(lx.y))
                + (bf2f(hw.z) + bf2f(lw.z)) * (bf2f(hx.z) + bf2f(lx.z))
                + (bf2f(hw.w) + bf2f(lw.w)) * (bf2f(hx.w) + bf2f(lx.w));
#pragma unroll
        for (int off = 32; off; off >>= 1) a += __shfl_xor(a, off, 64);
        if (lane == 0) vp[j] = a + mb[e];
    }
}

// top-K selection straight from per-block regions (no compaction).
// 1024 threads: 4 sub-threads per region; two L2-resident sweeps.
__launch_bounds__(1024)
__global__ void k_selectc(const float* __restrict__ zpart, const int* __restrict__ cntB,
                          const float* __restrict__ cvalB, const int* __restrict__ cidxB,
                          const int* __restrict__ ovc, const float* __restrict__ ovv,
                          const int* __restrict__ ovi, int* __restrict__ sel_e,
                          int* __restrict__ sel_t, float* __restrict__ sel_sp) {
    __shared__ float zsh[256];
    __shared__ int h[NB2_];
    __shared__ int part[256];
    __shared__ float bl_v[1024];
    __shared__ int bl_i[1024];
    __shared__ int nb, bstar, nabove, outcnt;
    int b = blockIdx.x, tid = threadIdx.x;
    int rid = tid & 255, sub = tid >> 8;     // 4 subthreads per region
    int f = b + 8 * rid;
    int c = cntB[f];                          // all 4 subs read same (cached)
    for (int i = tid; i < NB2_; i += 1024) h[i] = 0;
    if (tid < 256) zsh[tid] = zpart[b + 8 * tid];
    if (tid == 0) { nb = 0; outcnt = 0; bstar = 0; nabove = 0; }
    __syncthreads();
    // ---- pass 1: histogram from regions (+ overflow) ----
    const float* rv = cvalB + (size_t)f * BCAP_;
    for (int j = sub; j < c; j += 4) {
        float v = rv[j];
        int bin = (int)(v * ((float)NB2_ * 2.0f));
        bin = bin < 0 ? 0 : (bin > NB2_ - 1 ? NB2_ - 1 : bin);
        atomicAdd(&h[bin], 1);
    }
    int no = ovc[b]; if (no > OCAP_) no = OCAP_;
    for (int j = tid; j < no; j += 1024) {
        float v = ovv[b * OCAP_ + j];
        int bin = (int)(v * ((float)NB2_ * 2.0f));
        bin = bin < 0 ? 0 : (bin > NB2_ - 1 ? NB2_ - 1 : bin);
        atomicAdd(&h[bin], 1);
    }
    __syncthreads();
    // Z reduction (first 256 threads)
    for (int d = 128; d; d >>= 1) {
        if (tid < d) zsh[tid] += zsh[tid + d];
        __syncthreads();
    }
    // ---- boundary-bin search: suffix scan over 16-bin group sums ----
    if (tid < 256) {
        int ps = 0;
#pragma unroll
        for (int j = 0; j < 16; ++j) ps += h[tid * 16 + j];
        part[tid] = ps;
    }
    __syncthreads();
    for (int d = 1; d < 256; d <<= 1) {      // inclusive suffix scan
        int v = 0;
        if (tid < 256) v = (tid + d < 256) ? part[tid + d] : 0;
        __syncthreads();
        if (tid < 256) part[tid] += v;
        __syncthreads();
    }
    if (tid < 256 && part[tid] >= K_ && (tid == 255 || part[tid + 1] < K_)) {
        int cum2 = (tid == 255) ? 0 : part[tid + 1];
        for (int j = 15; j >= 0; --j) {
            cum2 += h[tid * 16 + j];
            if (cum2 >= K_) { bstar = tid * 16 + j; nabove = cum2 - h[tid * 16 + j]; break; }
        }
    }
    __syncthreads();
    // ---- pass 2: write >bs outputs, collect boundary bin ----
    int bs = bstar;
    float rZ = 1.0f / zsh[0];
    const int* ri = cidxB + (size_t)f * BCAP_;
    for (int j = sub; j < c; j += 4) {
        float v = rv[j];
        int bin = (int)(v * ((float)NB2_ * 2.0f));
        bin = bin < 0 ? 0 : (bin > NB2_ - 1 ? NB2_ - 1 : bin);
        if (bin > bs) {
            int q = atomicAdd(&outcnt, 1);
            int idx = ri[j];
            sel_e[b * K_ + q] = idx / T_;
            sel_t[b * K_ + q] = idx % T_;
            sel_sp[b * K_ + q] = __expf(v) * rZ;
        } else if (bin == bs) {
            int q = atomicAdd(&nb, 1);
            if (q < 1024) { bl_v[q] = v; bl_i[q] = ri[j]; }
        }
    }
    for (int j = tid; j < no; j += 1024) {
        float v = ovv[b * OCAP_ + j];
        int bin = (int)(v * ((float)NB2_ * 2.0f));
        bin = bin < 0 ? 0 : (bin > NB2_ - 1 ? NB2_ - 1 : bin);
        if (bin > bs) {
            int q = atomicAdd(&outcnt, 1);
            int idx = ovi[b * OCAP_ + j];
            sel_e[b * K_ + q] = idx / T_;
            sel_t[b * K_ + q] = idx % T_;
            sel_sp[b * K_ + q] = __expf(v) * rZ;
        } else if (bin == bs) {
            int q = atomicAdd(&nb, 1);
            if (q < 1024) { bl_v[q] = v; bl_i[q] = ovi[b * OCAP_ + j]; }
        }
    }
    __syncthreads();
    // ---- parallel rank selection within the boundary bin ----
    int m = nb; if (m > 1024) m = 1024;
    int need = K_ - nabove;
    for (int j = tid; j < m; j += 1024) {
        float v = bl_v[j]; int id = bl_i[j];
        int r = 0;
        for (int i = 0; i < m; ++i) {
            float vi = bl_v[i]; int ii = bl_i[i];
            r += (vi > v || (vi == v && ii < id)) ? 1 : 0;
        }
        if (r < need) {
            int slot = nabove + r;
            sel_e[b * K_ + slot] = id / T_;
            sel_t[b * K_ + slot] = id % T_;
            sel_sp[b * K_ + slot] = __expf(v) * rZ;
        }
    }
    // pathological fallback: fewer boundary items than needed -> zero entries
    for (int q = m + tid; q < need; q += 1024) {
        int slot = nabove + q;
        sel_e[b * K_ + slot] = 0; sel_t[b * K_ + slot] = 0;
        sel_sp[b * K_ + slot] = 0.f;
    }
}

// up at selected positions via tiled split-x; fused spk slot assignment
__global__ void k_upg2(const ushort* __restrict__ xh, const ushort* __restrict__ xl,
                       const float* __restrict__ nrm, const float* __restrict__ uw,
                       const float* __restrict__ ub, const int* __restrict__ sel_e,
                       const int* __restrict__ sel_t, const float* __restrict__ sel_sp,
                       float* __restrict__ gval, int* __restrict__ map,
                       int* __restrict__ pri) {
    int gid = blockIdx.x * 256 + threadIdx.x;   // B*K waves
    int w = gid >> 6, lane = gid & 63;
    int b = w >> 9, i = w & (K_ - 1);
    int e = sel_e[b * K_ + i], t = sel_t[b * K_ + i];
    if (lane == 0) {                             // fused k_spk1
        int old = atomicCAS(&map[b * T_ + t], -1, i);
        pri[b * K_ + i] = (old == -1) ? i : old;
    }
    int ttile = t >> 6, trow = t & 63;
    int cc = lane >> 4, cb = (lane >> 1) & 7, half = lane & 1;
    size_t ro = ((((size_t)b * 128 + ttile) * 4 + cc) * 8 + cb) * 512
              + (size_t)trow * 8 + half * 4;          // c = lane*4 .. +4
    ushort4 h = *(const ushort4*)(xh + ro);
    ushort4 l = *(const ushort4*)(xl + ro);
    float4 wv = *(const float4*)(uw + (size_t)e * C_ + lane * 4);
    float acc = (bf2f(h.x) + bf2f(l.x)) * wv.x + (bf2f(h.y) + bf2f(l.y)) * wv.y
              + (bf2f(h.z) + bf2f(l.z)) * wv.z + (bf2f(h.w) + bf2f(l.w)) * wv.w;
#pragma unroll
    for (int off = 32; off; off >>= 1) acc += __shfl_down(acc, off, 64);
    if (lane == 0)
        gval[b * K_ + i] = sel_sp[b * K_ + i] * (acc * nrm[b * T_ + t] + ub[e]);
}

// fused base/S1/Q + BN stats: one block per channel c, 8 batches inside
__launch_bounds__(256)
__global__ void k_bsqbn(const float* __restrict__ sw, const float* __restrict__ sb,
                        const float* __restrict__ db, const float* __restrict__ dw,
                        const int* __restrict__ sel_e, const float* __restrict__ gval,
                        const float* __restrict__ bnw, const float* __restrict__ bnb,
                        float* __restrict__ scalec, float* __restrict__ obase) {
    __shared__ float barr[8], s1arr[8], qarr[8];
    int c = blockIdx.x;
    int w = threadIdx.x >> 6, lane = threadIdx.x & 63;
#pragma unroll
    for (int rep = 0; rep < 2; ++rep) {
        int b = w + rep * 4;
        float p = 0.f, s = 0.f, q = 0.f;
        for (int i = lane; i < K_; i += 64) {
            int e = sel_e[b * K_ + i];
            float g = gval[b * K_ + i];
            p += g * sw[(size_t)c * E_ + e];
            float wv = dw[(size_t)c * E_ + e] * g;
            s += wv; q += wv * wv;
        }
#pragma unroll
        for (int off = 32; off; off >>= 1) {
            p += __shfl_xor(p, off, 64);
            s += __shfl_xor(s, off, 64);
            q += __shfl_xor(q, off, 64);
        }
        if (lane == 0) {
            barr[b] = p + sb[c] + db[c];
            s1arr[b] = s; qarr[b] = q;
        }
    }
    __syncthreads();
    if (threadIdx.x == 0) {
        float msum = 0.f;
        for (int b = 0; b < B_; ++b) msum += (float)T_ * barr[b] + s1arr[b];
        float mean = msum / (float)(B_ * T_);
        float vs = 0.f;
        for (int b = 0; b < B_; ++b) {
            float d = barr[b] - mean;
            vs += (float)T_ * d * d + 2.0f * d * s1arr[b] + qarr[b];
        }
        float var = vs / (float)(B_ * T_);
        float sc = bnw[c] * rsqrtf(var + 1e-5f);
        scalec[c] = sc;
        for (int b = 0; b < B_; ++b)
            obase[b * C_ + c] = (barr[b] - mean) * sc + bnb[c];
    }
}

// spike accumulation into compact L2-resident spk[b][slot][c]
__global__ void k_spk2(const float* __restrict__ dw, const float* __restrict__ scalec,
                       const int* __restrict__ sel_e, const int* __restrict__ pri,
                       const float* __restrict__ gval, float* __restrict__ spk) {
    int gid = blockIdx.x * 256 + threadIdx.x;   // B*K*64 threads
    int s = gid >> 6, cq = (gid & 63) * 4;
    int b = s >> 9;
    int e = sel_e[s];
    float g = gval[s];
    int p = pri[s];
    float* dst = spk + ((size_t)(b * K_ + p)) * C_ + cq;
#pragma unroll
    for (int q = 0; q < 4; ++q) {
        int c = cq + q;
        atomicAdd(dst + q, scalec[c] * dw[(size_t)c * E_ + e] * g);
    }
}

// fill output: column-constant base + spike columns from compact spk
__global__ void k_fill2(const float* __restrict__ obase, const int* __restrict__ map,
                        const float* __restrict__ spk, float* __restrict__ out) {
    size_t gid = (size_t)blockIdx.x * 256 + threadIdx.x;
    size_t flat = gid * 4;
    int b = (int)(flat / CT_);
    int c = (int)(flat / T_) & (C_ - 1);
    int t0 = (int)(flat & (T_ - 1));
    float v = obase[b * C_ + c];
    float4 o = {v, v, v, v};
    int4 mp = *(const int4*)(map + b * T_ + t0);
    if (mp.x >= 0) o.x += spk[((size_t)(b * K_ + mp.x)) * C_ + c];
    if (mp.y >= 0) o.y += spk[((size_t)(b * K_ + mp.y)) * C_ + c];
    if (mp.z >= 0) o.z += spk[((size_t)(b * K_ + mp.z)) * C_ + c];
    if (mp.w >= 0) o.w += spk[((size_t)(b * K_ + mp.w)) * C_ + c];
    *(float4*)(out + flat) = o;
}

extern "C" void kernel_launch(void* const* d_in, const int* in_sizes, int n_in,
                              void* d_out, int out_size, void* d_ws, size_t ws_size,
                              hipStream_t stream) {
    const float* x = (const float*)d_in[0];
    const float* up_w = (const float*)d_in[1];
    const float* up_b = (const float*)d_in[2];
    const float* mask_w = (const float*)d_in[3];
    const float* mask_b = (const float*)d_in[4];
    const float* sum_w = (const float*)d_in[5];
    const float* sum_b = (const float*)d_in[6];
    const float* down_w = (const float*)d_in[7];
    const float* down_b = (const float*)d_in[8];
    const float* bn_w = (const float*)d_in[9];
    const float* bn_b = (const float*)d_in[10];
    float* out = (float*)d_out;

    // workspace layout (float units)
    float* ws = (float*)d_ws;
    size_t o = 0;
    float* rn = ws + o;   o += (size_t)B_ * T_;
    float* nrm = ws + o;  o += (size_t)B_ * T_;
    float* xs = ws + o;   o += (size_t)B_ * C_ * SCOLS_;
    float* msub = ws + o; o += (size_t)B_ * SUBN_;
    float* tau0 = ws + o; o += B_;
    int* gh = (int*)(ws + o);    o += (size_t)B_ * NB1_;
    int* sel_e = (int*)(ws + o); o += (size_t)B_ * K_;
    int* sel_t = (int*)(ws + o); o += (size_t)B_ * K_;
    float* sel_sp = ws + o; o += (size_t)B_ * K_;
    float* gval = ws + o;   o += (size_t)B_ * K_;
    float* scalec = ws + o; o += C_;
    float* obase = ws + o;  o += (size_t)B_ * C_ + 8;
    // no-atomic collection buffers
    float* zpart = ws + o;  o += NBLK_;
    int* cntB = (int*)(ws + o); o += NBLK_;
    float* cvalB = ws + o;  o += (size_t)NBLK_ * BCAP_;
    int* cidxB = (int*)(ws + o); o += (size_t)NBLK_ * BCAP_;
    int* ovc = (int*)(ws + o); o += B_;
    float* ovv = ws + o;    o += (size_t)B_ * OCAP_;
    int* ovi = (int*)(ws + o); o += (size_t)B_ * OCAP_;
    // spike buffers
    int* map = (int*)(ws + o);  o += (size_t)B_ * T_;
    int* pri = (int*)(ws + o);  o += (size_t)B_ * K_;
    float* spk = ws + o;        o += (size_t)B_ * K_ * C_;
    // big split buffers last
    ushort* mwh = (ushort*)(ws + o); o += (size_t)E_ * C_ / 2;
    ushort* mwl = (ushort*)(ws + o); o += (size_t)E_ * C_ / 2;
    ushort* xh = (ushort*)(ws + o);  o += (size_t)B_ * T_ * C_ / 2;
    ushort* xl = (ushort*)(ws + o);  o += (size_t)B_ * T_ * C_ / 2;
    (void)ws_size;

    k_rnsplit<<<B_ * 256, 256, 0, stream>>>(x, rn, nrm, xh, xl, xs,
                                            mask_w, mwh, mwl, ovc, map, spk, gh);
    k_msub2<<<dim3(SCOLS_ / 64, E_ / 64, B_), 256, 0, stream>>>(xs, mask_w, mask_b, msub);
    k_tau_hist<<<B_ * TAUP_, 256, 0, stream>>>(msub, gh);
    k_tau2<<<B_, 256, 0, stream>>>(gh, tau0);
    k_gemm128<<<NBLK_, 256, 0, stream>>>(mwh, xh, mask_b, tau0,
                                         zpart, cntB, cvalB, cidxB,
                                         ovc, ovv, ovi);
    k_exact<<<NBLK_ + B_, 256, 0, stream>>>(mwh, mwl, xh, xl, mask_b,
                                            cntB, cidxB, cvalB, ovc, ovi, ovv);
    k_selectc<<<B_, 1024, 0, stream>>>(zpart, cntB, cvalB, cidxB,
                                       ovc, ovv, ovi, sel_e, sel_t, sel_sp);
    k_upg2<<<(B_ * K_ * 64) / 256, 256, 0, stream>>>(xh, xl, nrm, up_w, up_b,
                                                     sel_e, sel_t, sel_sp, gval,
                                                     map, pri);
    k_bsqbn<<<C_, 256, 0, stream>>>(sum_w, sum_b, down_b, down_w, sel_e, gval,
                                    bn_w, bn_b, scalec, obase);
    k_spk2<<<(B_ * K_ * 64) / 256, 256, 0, stream>>>(down_w, scalec, sel_e, pri,
                                                     gval, spk);
    k_fill2<<<(B_ * CT_ / 4) / 256, 256, 0, stream>>>(obase, map, spk, out);
}